// Round 2
// baseline (2830.516 us; speedup 1.0000x reference)
//
#include <hip/hip_runtime.h>
#include <math.h>

// WaveNet (4,256,16384), 20 layers. Round 6: same full fusion as round 5
// (20 layers + 3 block-local skip flushes in ONE persistent kernel), but
// launched as a PLAIN kernel with an explicit software grid barrier
// (agent-scope atomics + threadfence) instead of hipLaunchCooperativeKernel,
// which appears not to survive the harness's stream capture.
// Co-residency: 512 threads, launch_bounds(512,4) => <=128 VGPR => 16 waves/CU;
// LDS 55.8KB*2 = 111.6KB <= 160KB => exactly 2 blocks/CU * 256 CU = 512 blocks.

#define T_LEN   16384
#define NB      4
#define BT      (NB * T_LEN)     // 65536
#define NLAYERS 20
#define NBLK    512
#define SQH     0.70710678118654752440f

typedef _Float16 half8 __attribute__((ext_vector_type(8)));
typedef _Float16 half4 __attribute__((ext_vector_type(4)));
typedef float f32x4 __attribute__((ext_vector_type(4)));

__device__ inline f32x4 mfma16(half8 a, half8 b, f32x4 c) {
  return __builtin_amdgcn_mfma_f32_16x16x32_f16(a, b, c, 0, 0, 0);
}

// -------- software grid barrier (sense via generation counter) ----------
// bar[0] = arrival counter, bar[1] = generation. Requires all blocks resident.
__device__ __forceinline__ void gridbar(unsigned* bar) {
  __syncthreads();
  if (threadIdx.x == 0) {
    __threadfence();  // release: flush this block's global writes (L2 wb)
    unsigned gen = __hip_atomic_load(&bar[1], __ATOMIC_ACQUIRE,
                                     __HIP_MEMORY_SCOPE_AGENT);
    unsigned a = __hip_atomic_fetch_add(&bar[0], 1u, __ATOMIC_ACQ_REL,
                                        __HIP_MEMORY_SCOPE_AGENT);
    if (a == NBLK - 1) {
      __hip_atomic_store(&bar[0], 0u, __ATOMIC_RELAXED, __HIP_MEMORY_SCOPE_AGENT);
      __hip_atomic_fetch_add(&bar[1], 1u, __ATOMIC_RELEASE,
                             __HIP_MEMORY_SCOPE_AGENT);
    } else {
      while (__hip_atomic_load(&bar[1], __ATOMIC_ACQUIRE,
                               __HIP_MEMORY_SCOPE_AGENT) == gen)
        __builtin_amdgcn_s_sleep(2);
    }
  }
  __syncthreads();
}

// ---------------- weight packing (f16) ----------------
__global__ __launch_bounds__(256) void prep_pack(
    const float* __restrict__ Wf, const float* __restrict__ Wdil,
    const float* __restrict__ Wc, const float* __restrict__ Wskip,
    const float* __restrict__ Wout, const float* __restrict__ Wl1,
    const float* __restrict__ Wl2, const float* __restrict__ bdil,
    const float* __restrict__ bc, const float* __restrict__ bskip,
    _Float16* __restrict__ wdp, _Float16* __restrict__ wcp,
    _Float16* __restrict__ wop, _Float16* __restrict__ wskp,
    _Float16* __restrict__ wfp, _Float16* __restrict__ wl1p,
    _Float16* __restrict__ wl2p, float* __restrict__ bde,
    float* __restrict__ bsk, unsigned* __restrict__ bar)
{
  if (blockIdx.x == 0 && threadIdx.x < 2) bar[threadIdx.x] = 0u;  // barrier init
  const float Q = 0.70710678118654752440f;
  const int WDP_E = 20 * 3 * 128 * 64;   // [l][tau][n][kc]
  const int WCP_E = 20 * 128 * 96;       // [l][n][kc pad96]
  const int WOP_E = 20 * 64 * 64;        // [l][n][kc]
  const int WSK_E = 256 * 1280;          // [n][l*64+kc], scale q^(1-l)
  const int WFP_E = 64 * 512;            // [n][tau*256+ci]
  const int WL_E  = 256 * 256;
  const int BDE_E = 20 * 128;
  const int BSK_E = 256;
  const int TOTAL = WDP_E + WCP_E + WOP_E + WSK_E + WFP_E + 2 * WL_E + BDE_E + BSK_E;
  for (int i = blockIdx.x * blockDim.x + threadIdx.x; i < TOTAL;
       i += gridDim.x * blockDim.x) {
    int j = i;
    if (j < WDP_E) {
      int l = j / (3 * 128 * 64); int r2 = j % (3 * 128 * 64);
      int tau = r2 / (128 * 64);  int r3 = r2 % (128 * 64);
      int n = r3 >> 6; int kc = r3 & 63;
      wdp[j] = (_Float16)Wdil[((l * 128 + n) * 64 + kc) * 3 + tau];
      continue;
    }
    j -= WDP_E;
    if (j < WCP_E) {
      int l = j / (128 * 96); int r2 = j % (128 * 96);
      int n = r2 / 96; int kc = r2 % 96;
      wcp[j] = (_Float16)(kc < 80 ? Wc[(l * 128 + n) * 80 + kc] : 0.f);
      continue;
    }
    j -= WCP_E;
    if (j < WOP_E) {
      int l = j >> 12; int r2 = j & 4095;
      int n = r2 >> 6; int kc = r2 & 63;
      wop[j] = (_Float16)Wout[(l * 64 + n) * 64 + kc];
      continue;
    }
    j -= WOP_E;
    if (j < WSK_E) {
      int n = j / 1280; int k = j % 1280;
      int l = k >> 6; int kc = k & 63;
      float f = (l == 0) ? 1.f : powf(Q, (float)(1 - l));
      wskp[j] = (_Float16)(Wskip[(l * 256 + n) * 64 + kc] * f);
      continue;
    }
    j -= WSK_E;
    if (j < WFP_E) {
      int n = j >> 9; int k = j & 511;
      int tau = k >> 8; int ci = k & 255;
      wfp[j] = (_Float16)Wf[(n * 256 + ci) * 2 + tau];
      continue;
    }
    j -= WFP_E;
    if (j < WL_E) { wl1p[j] = (_Float16)Wl1[j]; continue; }
    j -= WL_E;
    if (j < WL_E) { wl2p[j] = (_Float16)Wl2[j]; continue; }
    j -= WL_E;
    if (j < BDE_E) { bde[j] = bdil[j] + bc[j]; continue; }
    j -= BDE_E;
    {
      int n = j;
      float s = 0.f;
      for (int l = 0; l < NLAYERS; ++l) {
        float w = powf(Q, (float)(l == 0 ? 19 : 20 - l));
        s += bskip[l * 256 + n] * w;
      }
      bsk[n] = s;
    }
  }
}

// ---------------- transpose (B,C,T) f32 -> (BT,Cpad) f16 ----------------
__global__ __launch_bounds__(256) void tr_kernel(
    const float* __restrict__ src, _Float16* __restrict__ dst, int C, int Cpad, int CB)
{
  __shared__ float tile[32 * 33];
  int bid = blockIdx.x;
  int cb = bid % CB;
  int tb = (bid / CB) % (T_LEN / 32);
  int bb = bid / (CB * (T_LEN / 32));
  int t0 = tb * 32, ch0 = cb * 32;
  int tl = threadIdx.x & 31, cl = threadIdx.x >> 5;
#pragma unroll
  for (int i = 0; i < 4; ++i) {
    int ch = cl + 8 * i;
    float v = (ch0 + ch < C) ? src[((size_t)bb * C + ch0 + ch) * T_LEN + t0 + tl] : 0.f;
    tile[ch * 33 + tl] = v;
  }
  __syncthreads();
  int t = threadIdx.x >> 3;
  int c4 = (threadIdx.x & 7) * 4;
  half4 hv = {(_Float16)tile[(c4 + 0) * 33 + t], (_Float16)tile[(c4 + 1) * 33 + t],
              (_Float16)tile[(c4 + 2) * 33 + t], (_Float16)tile[(c4 + 3) * 33 + t]};
  *(half4*)&dst[((size_t)bb * T_LEN + t0 + t) * Cpad + ch0 + c4] = hv;
}

// ---------------- first conv: h0 = tanh(Wf*[x(t-1);x(t)] + bf), f16 out ----
__global__ __launch_bounds__(256, 4) void first_conv(
    const _Float16* __restrict__ xt, const _Float16* __restrict__ wfp,
    const float* __restrict__ bf, _Float16* __restrict__ h0)
{
  __shared__ _Float16 As[128 * 72];
  __shared__ _Float16 Bs[64 * 72];
  const int tid = threadIdx.x;
  const int lane = tid & 63, w = tid >> 6;
  const int wx = w & 1, wy = w >> 1;
  const int l15 = lane & 15, quad = lane >> 4;
  const int p0 = blockIdx.x * 128;
  const int b = p0 >> 14, t0 = p0 & (T_LEN - 1);
  const int r = tid >> 1, halfo = (tid & 1) * 32;

  f32x4 acc[4][2];
#pragma unroll
  for (int mi = 0; mi < 4; ++mi)
#pragma unroll
    for (int ni = 0; ni < 2; ++ni) { f32x4 z = {0.f, 0.f, 0.f, 0.f}; acc[mi][ni] = z; }

  for (int s = 0; s < 8; ++s) {
    int tau = s >> 2, ci0 = (s & 3) * 64;
    int ts = t0 + r - 1 + tau;
    if (ts >= 0) {
      const uint4* src = (const uint4*)(xt + ((size_t)(b * T_LEN + ts) * 256 + ci0 + halfo));
#pragma unroll
      for (int j = 0; j < 4; ++j) *(uint4*)&As[r * 72 + halfo + 8 * j] = src[j];
    } else {
      uint4 z = {0, 0, 0, 0};
#pragma unroll
      for (int j = 0; j < 4; ++j) *(uint4*)&As[r * 72 + halfo + 8 * j] = z;
    }
    if (tid < 128) {
      const uint4* s4 = (const uint4*)(wfp + ((size_t)r * 512 + tau * 256 + ci0 + halfo));
#pragma unroll
      for (int j = 0; j < 4; ++j) *(uint4*)&Bs[r * 72 + halfo + 8 * j] = s4[j];
    }
    __syncthreads();
#pragma unroll
    for (int kc = 0; kc < 2; ++kc) {
      const int k0 = kc * 32 + quad * 8;
      half8 af[4], bfr[2];
#pragma unroll
      for (int mi = 0; mi < 4; ++mi)
        af[mi] = *(const half8*)&As[(64 * wy + 16 * mi + l15) * 72 + k0];
#pragma unroll
      for (int ni = 0; ni < 2; ++ni)
        bfr[ni] = *(const half8*)&Bs[(32 * wx + 16 * ni + l15) * 72 + k0];
#pragma unroll
      for (int mi = 0; mi < 4; ++mi)
#pragma unroll
        for (int ni = 0; ni < 2; ++ni)
          acc[mi][ni] = mfma16(af[mi], bfr[ni], acc[mi][ni]);
    }
    __syncthreads();
  }
#pragma unroll
  for (int mi = 0; mi < 4; ++mi)
#pragma unroll
    for (int ni = 0; ni < 2; ++ni) {
      int col = 32 * wx + 16 * ni + l15;
      int rowb = 64 * wy + 16 * mi + quad * 4;
      float bo = bf[col];
      size_t base = ((size_t)p0 + rowb) * 64 + col;
#pragma unroll
      for (int reg = 0; reg < 4; ++reg) {
        float v = acc[mi][ni][reg] + bo;
        float e = __expf(2.f * v);
        h0[base + (size_t)64 * reg] = (_Float16)(1.f - 2.f * __builtin_amdgcn_rcpf(e + 1.f));
      }
    }
}

// ---------------- block-local skip flush phase (inside fused kernel) ------
// 512 threads = two independent 256-thread halves; half h handles n0=h*128.
// mode 0: Abuf = acc   mode 1: Abuf += acc   mode 2: skr = relu((acc+Abuf)*q^19+bsk)
__device__ __forceinline__ void flush_phase(
    int tid, int p0, const _Float16* __restrict__ zbuf,
    const _Float16* __restrict__ wskp, _Float16* __restrict__ Abuf,
    const float* __restrict__ bsk, _Float16* __restrict__ skr,
    _Float16* smem, int l0, int g, int mode)
{
  _Float16* As = smem;                                   // shared z tile
  const int half = tid >> 8;
  _Float16* Bsh = smem + (1 + half) * (128 * 72);        // per-half Wskip tile
  const int tloc = tid & 255;
  const int lane = tloc & 63, w4 = tloc >> 6;
  const int wx = w4 & 1, wy = w4 >> 1;
  const int l15 = lane & 15, quad = lane >> 4;
  const int n0 = half * 128;
  const int r = tloc >> 1, halfo = (tloc & 1) * 32;

  f32x4 acc[4][4];
#pragma unroll
  for (int mi = 0; mi < 4; ++mi)
#pragma unroll
    for (int ni = 0; ni < 4; ++ni) { f32x4 z = {0.f, 0.f, 0.f, 0.f}; acc[mi][ni] = z; }

  __syncthreads();  // all prior readers of smem done before restaging
#pragma unroll 1
  for (int j = 0; j < g; ++j) {
    const int lj = l0 + j;
    const _Float16* zsl = zbuf + (size_t)(lj & 7) * ((size_t)BT * 64);
    if (half == 0) {
      const uint4* sa = (const uint4*)(zsl + ((size_t)(p0 + r) * 64 + halfo));
#pragma unroll
      for (int jj = 0; jj < 4; ++jj) *(uint4*)&As[r * 72 + halfo + 8 * jj] = sa[jj];
    }
    const uint4* sb = (const uint4*)(wskp + ((size_t)(n0 + r) * 1280 + lj * 64 + halfo));
#pragma unroll
    for (int jj = 0; jj < 4; ++jj) *(uint4*)&Bsh[r * 72 + halfo + 8 * jj] = sb[jj];
    __syncthreads();
#pragma unroll
    for (int kc = 0; kc < 2; ++kc) {
      const int k0 = kc * 32 + quad * 8;
      half8 af[4], bfr[4];
#pragma unroll
      for (int mi = 0; mi < 4; ++mi)
        af[mi] = *(const half8*)&As[(64 * wy + 16 * mi + l15) * 72 + k0];
#pragma unroll
      for (int ni = 0; ni < 4; ++ni)
        bfr[ni] = *(const half8*)&Bsh[(64 * wx + 16 * ni + l15) * 72 + k0];
#pragma unroll
      for (int mi = 0; mi < 4; ++mi)
#pragma unroll
        for (int ni = 0; ni < 4; ++ni)
          acc[mi][ni] = mfma16(af[mi], bfr[ni], acc[mi][ni]);
    }
    __syncthreads();
  }
  const float Q19 = 0.0013810679320049757f;  // sqrt(0.5)^19
#pragma unroll
  for (int mi = 0; mi < 4; ++mi)
#pragma unroll
    for (int ni = 0; ni < 4; ++ni) {
      int col = n0 + 64 * wx + 16 * ni + l15;
      int rowb = 64 * wy + 16 * mi + quad * 4;
      size_t base = ((size_t)p0 + rowb) * 256 + col;
      if (mode == 2) {
        float bb = bsk[col];
#pragma unroll
        for (int reg = 0; reg < 4; ++reg) {
          float v = (acc[mi][ni][reg] + (float)Abuf[base + (size_t)256 * reg]) * Q19 + bb;
          skr[base + (size_t)256 * reg] = (_Float16)(v > 0.f ? v : 0.f);
        }
      } else if (mode == 1) {
#pragma unroll
        for (int reg = 0; reg < 4; ++reg) {
          size_t a = base + (size_t)256 * reg;
          Abuf[a] = (_Float16)((float)Abuf[a] + acc[mi][ni][reg]);
        }
      } else {
#pragma unroll
        for (int reg = 0; reg < 4; ++reg)
          Abuf[base + (size_t)256 * reg] = (_Float16)acc[mi][ni][reg];
      }
    }
}

// ---------------- fused 20-layer residual stack + flushes -----------------
// 512 blocks x 512 threads, exactly 2 blocks/CU (resource-guaranteed
// co-residency). Software grid barrier only between layers (h ping-pong
// hazard). Flushes at l=7/15/19 are block-local (z-ring rows p0 are written
// and read by the same block).
__global__ __launch_bounds__(512, 4) void wavenet_layers(
    _Float16* __restrict__ hA, _Float16* __restrict__ hB,
    const _Float16* __restrict__ ctp,
    const _Float16* __restrict__ wdp, const _Float16* __restrict__ wcp,
    const _Float16* __restrict__ wop, const _Float16* __restrict__ wskp,
    const float* __restrict__ bde, const float* __restrict__ bout,
    _Float16* __restrict__ zbuf, _Float16* __restrict__ Abuf,
    const float* __restrict__ bsk, _Float16* __restrict__ skr,
    unsigned* __restrict__ bar)
{
  __shared__ _Float16 smem[3 * 128 * 72];   // 55296 B (layer uses 2/3, flush all 3)
  __shared__ float bde_s[128];
  _Float16* As = smem;
  _Float16* Bs = smem + 128 * 72;

  const int tid = threadIdx.x;
  const int lane = tid & 63, w = tid >> 6;        // 8 waves
  const int wx = w & 1, wy = w >> 1;              // 2 (N) x 4 (M)
  const int l15 = lane & 15, quad = lane >> 4;
  const int p0 = blockIdx.x * 128;
  const int b = p0 >> 14, t0 = p0 & (T_LEN - 1);
  const int r2 = tid >> 2, qo = (tid & 3) * 16;   // staging: row, 16-elem chunk
  const int o8 = (tid & 3) * 8;                   // K=32 stage chunk

#pragma unroll 1
  for (int l = 0; l < NLAYERS; ++l) {
    const _Float16* hprev = (l & 1) ? hB : hA;
    _Float16* hnext = (l & 1) ? hA : hB;
    const int d = 1 << (l % 10);
    const _Float16* wdp_l = wdp + (size_t)l * (3 * 128 * 64);
    const _Float16* wcp_l = wcp + (size_t)l * (128 * 96);
    const _Float16* wop_l = wop + (size_t)l * (64 * 64);
    const float* bout_l = bout + l * 64;
    _Float16* zslot = zbuf + (size_t)(l & 7) * ((size_t)BT * 64);

    if (tid < 128) bde_s[tid] = bde[l * 128 + tid];

    f32x4 acc[2][4];
#pragma unroll
    for (int mi = 0; mi < 2; ++mi)
#pragma unroll
      for (int ni = 0; ni < 4; ++ni) { f32x4 z = {0.f, 0.f, 0.f, 0.f}; acc[mi][ni] = z; }

    // K stages: h[t-2d], h[t-d], h[t] (64 each), cond[0:64], cond[64:96] (K=32)
    for (int s = 0; s < 5; ++s) {
      if (s < 3) {
        int ts = t0 + r2 - (2 - s) * d;
        if (ts >= 0) {
          const uint4* src = (const uint4*)(hprev + ((size_t)(b * T_LEN + ts) * 64 + qo));
          *(uint4*)&As[r2 * 72 + qo] = src[0];
          *(uint4*)&As[r2 * 72 + qo + 8] = src[1];
        } else {
          uint4 z4 = {0, 0, 0, 0};
          *(uint4*)&As[r2 * 72 + qo] = z4;
          *(uint4*)&As[r2 * 72 + qo + 8] = z4;
        }
        const uint4* sb = (const uint4*)(wdp_l + ((size_t)s * 8192 + r2 * 64 + qo));
        *(uint4*)&Bs[r2 * 72 + qo] = sb[0];
        *(uint4*)&Bs[r2 * 72 + qo + 8] = sb[1];
      } else if (s == 3) {
        const uint4* sa = (const uint4*)(ctp + ((size_t)(p0 + r2) * 96 + qo));
        *(uint4*)&As[r2 * 72 + qo] = sa[0];
        *(uint4*)&As[r2 * 72 + qo + 8] = sa[1];
        const uint4* sb = (const uint4*)(wcp_l + ((size_t)r2 * 96 + qo));
        *(uint4*)&Bs[r2 * 72 + qo] = sb[0];
        *(uint4*)&Bs[r2 * 72 + qo + 8] = sb[1];
      } else {  // s == 4: K=32 tail of cond
        *(uint4*)&As[r2 * 72 + o8] = *(const uint4*)(ctp + ((size_t)(p0 + r2) * 96 + 64 + o8));
        *(uint4*)&Bs[r2 * 72 + o8] = *(const uint4*)(wcp_l + ((size_t)r2 * 96 + 64 + o8));
      }
      __syncthreads();
      const int nkc = (s == 4) ? 1 : 2;
      for (int kc = 0; kc < nkc; ++kc) {
        const int k0 = kc * 32 + quad * 8;
        half8 af[2], bfr[4];
#pragma unroll
        for (int mi = 0; mi < 2; ++mi)
          af[mi] = *(const half8*)&As[(32 * wy + 16 * mi + l15) * 72 + k0];
#pragma unroll
        for (int ni = 0; ni < 4; ++ni) {
          int ncol = 32 * wx + 16 * (ni & 1) + 64 * (ni >> 1);  // ch and ch+64
          bfr[ni] = *(const half8*)&Bs[(ncol + l15) * 72 + k0];
        }
#pragma unroll
        for (int mi = 0; mi < 2; ++mi)
#pragma unroll
          for (int ni = 0; ni < 4; ++ni)
            acc[mi][ni] = mfma16(af[mi], bfr[ni], acc[mi][ni]);
      }
      __syncthreads();
    }

    // gate: z = tanh(y[ch]) * sigmoid(y[ch+64]) -> Zs (aliases As)
#pragma unroll
    for (int mi = 0; mi < 2; ++mi)
#pragma unroll
      for (int ni2 = 0; ni2 < 2; ++ni2) {
        int colb = 32 * wx + 16 * ni2 + l15;
        float ba = bde_s[colb], bb = bde_s[colb + 64];
#pragma unroll
        for (int reg = 0; reg < 4; ++reg) {
          float av = acc[mi][ni2][reg] + ba;
          float gv = acc[mi][ni2 + 2][reg] + bb;
          float ea = __expf(2.f * av);
          float th = 1.f - 2.f * __builtin_amdgcn_rcpf(ea + 1.f);
          float sg = __builtin_amdgcn_rcpf(1.f + __expf(-gv));
          As[(32 * wy + 16 * mi + quad * 4 + reg) * 72 + colb] = (_Float16)(th * sg);
        }
      }

    // stage W_out (64x64) into Bs (skip for dead h of layer 19)
    if (l < NLAYERS - 1 && tid < 256) {
      int row = tid >> 2;
      const uint4* sb = (const uint4*)(wop_l + ((size_t)row * 64 + qo));
      *(uint4*)&Bs[row * 72 + qo] = sb[0];
      *(uint4*)&Bs[row * 72 + qo + 8] = sb[1];
    }
    __syncthreads();

    // z -> global ring slot (consumed block-locally by flush_phase)
    {
      uint4 v0 = *(const uint4*)&As[r2 * 72 + qo];
      uint4 v1 = *(const uint4*)&As[r2 * 72 + qo + 8];
      uint4* dst = (uint4*)(zslot + ((size_t)(p0 + r2) * 64 + qo));
      dst[0] = v0; dst[1] = v1;
    }

    if (l < NLAYERS - 1) {
      // phase 4: h_out = (Wout*z + b_out + h_in) * SQH
      f32x4 a4[2][2];
#pragma unroll
      for (int mi = 0; mi < 2; ++mi)
#pragma unroll
        for (int ni = 0; ni < 2; ++ni) { f32x4 z = {0.f, 0.f, 0.f, 0.f}; a4[mi][ni] = z; }
#pragma unroll
      for (int kc = 0; kc < 2; ++kc) {
        const int k0 = kc * 32 + quad * 8;
        half8 af[2], bfr[2];
#pragma unroll
        for (int mi = 0; mi < 2; ++mi)
          af[mi] = *(const half8*)&As[(32 * wy + 16 * mi + l15) * 72 + k0];
#pragma unroll
        for (int ni = 0; ni < 2; ++ni)
          bfr[ni] = *(const half8*)&Bs[(32 * wx + 16 * ni + l15) * 72 + k0];
#pragma unroll
        for (int mi = 0; mi < 2; ++mi)
#pragma unroll
          for (int ni = 0; ni < 2; ++ni)
            a4[mi][ni] = mfma16(af[mi], bfr[ni], a4[mi][ni]);
      }
#pragma unroll
      for (int mi = 0; mi < 2; ++mi)
#pragma unroll
        for (int ni = 0; ni < 2; ++ni) {
          int col = 32 * wx + 16 * ni + l15;
          int rowb = 32 * wy + 16 * mi + quad * 4;
          float bo = bout_l[col];
          size_t base = ((size_t)p0 + rowb) * 64 + col;
#pragma unroll
          for (int reg = 0; reg < 4; ++reg) {
            float hv = (float)hprev[base + (size_t)64 * reg];
            hnext[base + (size_t)64 * reg] = (_Float16)((a4[mi][ni][reg] + bo + hv) * SQH);
          }
        }
    } else {
      __threadfence_block();  // own z-slot store -> own reload in flush below
    }

    // block-local deferred skip flushes (no grid sync needed: same-p0 data)
    if (l == 7 || l == 15 || l == NLAYERS - 1) {
      const int l0   = (l == 7) ? 0 : (l == 15) ? 8 : 16;
      const int g    = (l == NLAYERS - 1) ? 4 : 8;
      const int mode = (l == 7) ? 0 : (l == 15) ? 1 : 2;
      flush_phase(tid, p0, zbuf, wskp, Abuf, bsk, skr, smem, l0, g, mode);
    }

    if (l < NLAYERS - 1) gridbar(bar);
  }
}

// ---------------- generic 256x256 GEMM (last1 / last2) -------------------
__global__ __launch_bounds__(256, 4) void gemm256(
    const _Float16* __restrict__ Asrc, const _Float16* __restrict__ Bp,
    const float* __restrict__ bias, void* __restrict__ dst, int mode)
{
  __shared__ _Float16 smem[2 * 128 * 72];
  _Float16* As = smem;
  _Float16* Bs = smem + 128 * 72;
  const int tid = threadIdx.x;
  const int lane = tid & 63, w = tid >> 6;
  const int wx = w & 1, wy = w >> 1;
  const int l15 = lane & 15, quad = lane >> 4;
  const int p0 = blockIdx.x * 128;
  const int n0 = blockIdx.y * 128;
  const int r = tid >> 1, halfo = (tid & 1) * 32;

  f32x4 acc[4][4];
#pragma unroll
  for (int mi = 0; mi < 4; ++mi)
#pragma unroll
    for (int ni = 0; ni < 4; ++ni) { f32x4 z = {0.f, 0.f, 0.f, 0.f}; acc[mi][ni] = z; }

  for (int c4 = 0; c4 < 4; ++c4) {
    int k0g = c4 * 64;
    const uint4* sa = (const uint4*)(Asrc + ((size_t)(p0 + r) * 256 + k0g + halfo));
#pragma unroll
    for (int jj = 0; jj < 4; ++jj) *(uint4*)&As[r * 72 + halfo + 8 * jj] = sa[jj];
    const uint4* sb = (const uint4*)(Bp + ((size_t)(n0 + r) * 256 + k0g + halfo));
#pragma unroll
    for (int jj = 0; jj < 4; ++jj) *(uint4*)&Bs[r * 72 + halfo + 8 * jj] = sb[jj];
    __syncthreads();
#pragma unroll
    for (int kc = 0; kc < 2; ++kc) {
      const int k0 = kc * 32 + quad * 8;
      half8 af[4], bfr[4];
#pragma unroll
      for (int mi = 0; mi < 4; ++mi)
        af[mi] = *(const half8*)&As[(64 * wy + 16 * mi + l15) * 72 + k0];
#pragma unroll
      for (int ni = 0; ni < 4; ++ni)
        bfr[ni] = *(const half8*)&Bs[(64 * wx + 16 * ni + l15) * 72 + k0];
#pragma unroll
      for (int mi = 0; mi < 4; ++mi)
#pragma unroll
        for (int ni = 0; ni < 4; ++ni)
          acc[mi][ni] = mfma16(af[mi], bfr[ni], acc[mi][ni]);
    }
    __syncthreads();
  }
  if (mode == 0) {
#pragma unroll
    for (int mi = 0; mi < 4; ++mi)
#pragma unroll
      for (int ni = 0; ni < 4; ++ni) {
        int col = n0 + 64 * wx + 16 * ni + l15;
        int rowb = 64 * wy + 16 * mi + quad * 4;
        float bv = bias[col];
        _Float16* o = (_Float16*)dst;
#pragma unroll
        for (int reg = 0; reg < 4; ++reg) {
          float v = acc[mi][ni][reg] + bv;
          o[((size_t)(p0 + rowb + reg)) * 256 + col] = (_Float16)(v > 0.f ? v : 0.f);
        }
      }
  } else {
    // transposed coalesced store: two passes of 64 columns through LDS
    float* Ts = (float*)smem;       // 64 x 132 floats = 33792 B
    const int b = p0 >> 14, t0g = p0 & (T_LEN - 1);
    for (int pass = 0; pass < 2; ++pass) {
      if (wx == pass) {
#pragma unroll
        for (int mi = 0; mi < 4; ++mi)
#pragma unroll
          for (int ni = 0; ni < 4; ++ni) {
            int col_l = 16 * ni + l15;
            float bv = bias[n0 + 64 * pass + col_l];
            int tl = 64 * wy + 16 * mi + quad * 4;
#pragma unroll
            for (int reg = 0; reg < 4; ++reg)
              Ts[col_l * 132 + tl + reg] = acc[mi][ni][reg] + bv;
          }
      }
      __syncthreads();
      {
        int col_l = tid >> 2;
        int tq = (tid & 3) * 32;
        float* o = (float*)dst + ((size_t)b * 256 + n0 + 64 * pass + col_l) * T_LEN + t0g + tq;
#pragma unroll
        for (int j = 0; j < 8; ++j)
          *(float4*)(o + 4 * j) = *(const float4*)&Ts[col_l * 132 + tq + 4 * j];
      }
      __syncthreads();
    }
  }
}

extern "C" void kernel_launch(void* const* d_in, const int* in_sizes, int n_in,
                              void* d_out, int out_size, void* d_ws, size_t ws_size,
                              hipStream_t stream)
{
  const float* x     = (const float*)d_in[0];
  const float* c     = (const float*)d_in[1];
  const float* Wf    = (const float*)d_in[2];
  const float* bf    = (const float*)d_in[3];
  const float* Wdil  = (const float*)d_in[4];
  const float* bdil  = (const float*)d_in[5];
  const float* Wc    = (const float*)d_in[6];
  const float* bc    = (const float*)d_in[7];
  const float* Wskip = (const float*)d_in[8];
  const float* bskip = (const float*)d_in[9];
  const float* Wout  = (const float*)d_in[10];
  const float* bout  = (const float*)d_in[11];
  const float* Wl1   = (const float*)d_in[12];
  const float* bl1   = (const float*)d_in[13];
  const float* Wl2   = (const float*)d_in[14];
  const float* bl2   = (const float*)d_in[15];

  char* base = (char*)d_ws;
  // 8-slot z ring (64 MiB). Aliases: xt = slots 0-3 (consumed by first_conv
  // before layer 0 writes slot 0); skr = slots 4-7 (written at flush l=19,
  // after slots 4-7's z consumed at flush l=15, cross-block safe via the
  // intervening grid barriers); y1 = slots 0-3 (free after flush l=19).
  // Abuf (f16) lives in d_out, dead before gemm256 #2 writes the final f32
  // output there.
  _Float16* zbuf = (_Float16*)base;
  _Float16* xt   = zbuf;
  _Float16* skr  = zbuf + (size_t)4 * BT * 64;
  _Float16* y1   = zbuf;
  _Float16* ctp  = (_Float16*)(base + 67108864);   // BT*96 f16 = 12.58 MB
  _Float16* hA   = (_Float16*)(base + 79691776);   // BT*64 f16 = 8.39 MB
  _Float16* hB   = (_Float16*)(base + 88080384);
  _Float16* wdp  = (_Float16*)(base + 96468992);
  _Float16* wcp  = wdp  + (size_t)20 * 3 * 128 * 64;
  _Float16* wop  = wcp  + (size_t)20 * 128 * 96;
  _Float16* wskp = wop  + (size_t)20 * 64 * 64;
  _Float16* wfp  = wskp + (size_t)256 * 1280;
  _Float16* wl1p = wfp  + (size_t)64 * 512;
  _Float16* wl2p = wl1p + (size_t)256 * 256;
  float*    bde  = (float*)(wl2p + (size_t)256 * 256);
  float*    bsk  = bde + 20 * 128;
  unsigned* bar  = (unsigned*)(bsk + 256);
  _Float16* Abuf = (_Float16*)d_out;               // f16 skip accumulator

  prep_pack<<<2048, 256, 0, stream>>>(Wf, Wdil, Wc, Wskip, Wout, Wl1, Wl2,
                                      bdil, bc, bskip,
                                      wdp, wcp, wop, wskp, wfp, wl1p, wl2p,
                                      bde, bsk, bar);
  tr_kernel<<<NB * (T_LEN / 32) * 8, 256, 0, stream>>>(x, xt, 256, 256, 8);
  tr_kernel<<<NB * (T_LEN / 32) * 3, 256, 0, stream>>>(c, ctp, 80, 96, 3);
  first_conv<<<512, 256, 0, stream>>>(xt, wfp, bf, hA);

  wavenet_layers<<<NBLK, 512, 0, stream>>>(hA, hB, ctp, wdp, wcp, wop, wskp,
                                           bde, bout, zbuf, Abuf, bsk, skr, bar);

  gemm256<<<dim3(512, 2), 256, 0, stream>>>(skr, wl1p, bl1, (void*)y1, 0);
  gemm256<<<dim3(512, 2), 256, 0, stream>>>(y1, wl2p, bl2, d_out, 1);
}

// Round 3
// 1853.942 us; speedup vs baseline: 1.5268x; 1.5268x over previous
//
#include <hip/hip_runtime.h>
#include <math.h>

// WaveNet (4,256,16384), 20 layers. Round 7: fused persistent kernel as in
// round 6, but with a coherence-minimal software grid barrier:
//  - spin on RELAXED atomic loads (global_load sc1 reads MALL; NO per-poll
//    buffer_inv). Round-6's acquire-load-per-poll invalidated L2 every
//    iteration -> 1.2 GB HBM traffic, 110us/barrier.
//  - exactly ONE release fence (L2 wb) before arrival and ONE acquire fence
//    (L1+L2 inv) after the generation bump per block per barrier.
//  - generation bump is a RELEASE RMW so the counter reset is MALL-ordered
//    before it (no lost-increment race at the next barrier).
// Also: phase-4 epilogue now reads h[t] from LDS (dual-written at stage s==2)
// instead of re-reading 8.4 MB/layer from global.

#define T_LEN   16384
#define NB      4
#define BT      (NB * T_LEN)     // 65536
#define NLAYERS 20
#define NBLK    512
#define SQH     0.70710678118654752440f

typedef _Float16 half8 __attribute__((ext_vector_type(8)));
typedef _Float16 half4 __attribute__((ext_vector_type(4)));
typedef float f32x4 __attribute__((ext_vector_type(4)));

__device__ inline f32x4 mfma16(half8 a, half8 b, f32x4 c) {
  return __builtin_amdgcn_mfma_f32_16x16x32_f16(a, b, c, 0, 0, 0);
}

// -------- software grid barrier (coherence-minimal) ----------------------
// bar[0] = arrival counter, bar[1] = generation. All blocks resident.
__device__ __forceinline__ void gridbar(unsigned* bar) {
  __syncthreads();
  if (threadIdx.x == 0) {
    // release: drain this block's stores, write back dirty L2 (once).
    __builtin_amdgcn_fence(__ATOMIC_RELEASE, "agent");
    unsigned gen = __hip_atomic_load(&bar[1], __ATOMIC_RELAXED,
                                     __HIP_MEMORY_SCOPE_AGENT);
    unsigned a = __hip_atomic_fetch_add(&bar[0], 1u, __ATOMIC_RELAXED,
                                        __HIP_MEMORY_SCOPE_AGENT);
    if (a == NBLK - 1) {
      __hip_atomic_store(&bar[0], 0u, __ATOMIC_RELAXED,
                         __HIP_MEMORY_SCOPE_AGENT);
      // RELEASE: orders the counter reset before the generation bump at MALL.
      __hip_atomic_fetch_add(&bar[1], 1u, __ATOMIC_RELEASE,
                             __HIP_MEMORY_SCOPE_AGENT);
    } else {
      // RELAXED poll: global_load sc1 from MALL, no cache invalidation.
      while (__hip_atomic_load(&bar[1], __ATOMIC_RELAXED,
                               __HIP_MEMORY_SCOPE_AGENT) == gen)
        __builtin_amdgcn_s_sleep(8);
    }
    // acquire: single L1(+L2) invalidate so this block sees remote h writes.
    __builtin_amdgcn_fence(__ATOMIC_ACQUIRE, "agent");
  }
  __syncthreads();
}

// ---------------- weight packing (f16) ----------------
__global__ __launch_bounds__(256) void prep_pack(
    const float* __restrict__ Wf, const float* __restrict__ Wdil,
    const float* __restrict__ Wc, const float* __restrict__ Wskip,
    const float* __restrict__ Wout, const float* __restrict__ Wl1,
    const float* __restrict__ Wl2, const float* __restrict__ bdil,
    const float* __restrict__ bc, const float* __restrict__ bskip,
    _Float16* __restrict__ wdp, _Float16* __restrict__ wcp,
    _Float16* __restrict__ wop, _Float16* __restrict__ wskp,
    _Float16* __restrict__ wfp, _Float16* __restrict__ wl1p,
    _Float16* __restrict__ wl2p, float* __restrict__ bde,
    float* __restrict__ bsk, unsigned* __restrict__ bar)
{
  if (blockIdx.x == 0 && threadIdx.x < 2) bar[threadIdx.x] = 0u;  // barrier init
  const float Q = 0.70710678118654752440f;
  const int WDP_E = 20 * 3 * 128 * 64;   // [l][tau][n][kc]
  const int WCP_E = 20 * 128 * 96;       // [l][n][kc pad96]
  const int WOP_E = 20 * 64 * 64;        // [l][n][kc]
  const int WSK_E = 256 * 1280;          // [n][l*64+kc], scale q^(1-l)
  const int WFP_E = 64 * 512;            // [n][tau*256+ci]
  const int WL_E  = 256 * 256;
  const int BDE_E = 20 * 128;
  const int BSK_E = 256;
  const int TOTAL = WDP_E + WCP_E + WOP_E + WSK_E + WFP_E + 2 * WL_E + BDE_E + BSK_E;
  for (int i = blockIdx.x * blockDim.x + threadIdx.x; i < TOTAL;
       i += gridDim.x * blockDim.x) {
    int j = i;
    if (j < WDP_E) {
      int l = j / (3 * 128 * 64); int r2 = j % (3 * 128 * 64);
      int tau = r2 / (128 * 64);  int r3 = r2 % (128 * 64);
      int n = r3 >> 6; int kc = r3 & 63;
      wdp[j] = (_Float16)Wdil[((l * 128 + n) * 64 + kc) * 3 + tau];
      continue;
    }
    j -= WDP_E;
    if (j < WCP_E) {
      int l = j / (128 * 96); int r2 = j % (128 * 96);
      int n = r2 / 96; int kc = r2 % 96;
      wcp[j] = (_Float16)(kc < 80 ? Wc[(l * 128 + n) * 80 + kc] : 0.f);
      continue;
    }
    j -= WCP_E;
    if (j < WOP_E) {
      int l = j >> 12; int r2 = j & 4095;
      int n = r2 >> 6; int kc = r2 & 63;
      wop[j] = (_Float16)Wout[(l * 64 + n) * 64 + kc];
      continue;
    }
    j -= WOP_E;
    if (j < WSK_E) {
      int n = j / 1280; int k = j % 1280;
      int l = k >> 6; int kc = k & 63;
      float f = (l == 0) ? 1.f : powf(Q, (float)(1 - l));
      wskp[j] = (_Float16)(Wskip[(l * 256 + n) * 64 + kc] * f);
      continue;
    }
    j -= WSK_E;
    if (j < WFP_E) {
      int n = j >> 9; int k = j & 511;
      int tau = k >> 8; int ci = k & 255;
      wfp[j] = (_Float16)Wf[(n * 256 + ci) * 2 + tau];
      continue;
    }
    j -= WFP_E;
    if (j < WL_E) { wl1p[j] = (_Float16)Wl1[j]; continue; }
    j -= WL_E;
    if (j < WL_E) { wl2p[j] = (_Float16)Wl2[j]; continue; }
    j -= WL_E;
    if (j < BDE_E) { bde[j] = bdil[j] + bc[j]; continue; }
    j -= BDE_E;
    {
      int n = j;
      float s = 0.f;
      for (int l = 0; l < NLAYERS; ++l) {
        float w = powf(Q, (float)(l == 0 ? 19 : 20 - l));
        s += bskip[l * 256 + n] * w;
      }
      bsk[n] = s;
    }
  }
}

// ---------------- transpose (B,C,T) f32 -> (BT,Cpad) f16 ----------------
__global__ __launch_bounds__(256) void tr_kernel(
    const float* __restrict__ src, _Float16* __restrict__ dst, int C, int Cpad, int CB)
{
  __shared__ float tile[32 * 33];
  int bid = blockIdx.x;
  int cb = bid % CB;
  int tb = (bid / CB) % (T_LEN / 32);
  int bb = bid / (CB * (T_LEN / 32));
  int t0 = tb * 32, ch0 = cb * 32;
  int tl = threadIdx.x & 31, cl = threadIdx.x >> 5;
#pragma unroll
  for (int i = 0; i < 4; ++i) {
    int ch = cl + 8 * i;
    float v = (ch0 + ch < C) ? src[((size_t)bb * C + ch0 + ch) * T_LEN + t0 + tl] : 0.f;
    tile[ch * 33 + tl] = v;
  }
  __syncthreads();
  int t = threadIdx.x >> 3;
  int c4 = (threadIdx.x & 7) * 4;
  half4 hv = {(_Float16)tile[(c4 + 0) * 33 + t], (_Float16)tile[(c4 + 1) * 33 + t],
              (_Float16)tile[(c4 + 2) * 33 + t], (_Float16)tile[(c4 + 3) * 33 + t]};
  *(half4*)&dst[((size_t)bb * T_LEN + t0 + t) * Cpad + ch0 + c4] = hv;
}

// ---------------- first conv: h0 = tanh(Wf*[x(t-1);x(t)] + bf), f16 out ----
__global__ __launch_bounds__(256, 4) void first_conv(
    const _Float16* __restrict__ xt, const _Float16* __restrict__ wfp,
    const float* __restrict__ bf, _Float16* __restrict__ h0)
{
  __shared__ _Float16 As[128 * 72];
  __shared__ _Float16 Bs[64 * 72];
  const int tid = threadIdx.x;
  const int lane = tid & 63, w = tid >> 6;
  const int wx = w & 1, wy = w >> 1;
  const int l15 = lane & 15, quad = lane >> 4;
  const int p0 = blockIdx.x * 128;
  const int b = p0 >> 14, t0 = p0 & (T_LEN - 1);
  const int r = tid >> 1, halfo = (tid & 1) * 32;

  f32x4 acc[4][2];
#pragma unroll
  for (int mi = 0; mi < 4; ++mi)
#pragma unroll
    for (int ni = 0; ni < 2; ++ni) { f32x4 z = {0.f, 0.f, 0.f, 0.f}; acc[mi][ni] = z; }

  for (int s = 0; s < 8; ++s) {
    int tau = s >> 2, ci0 = (s & 3) * 64;
    int ts = t0 + r - 1 + tau;
    if (ts >= 0) {
      const uint4* src = (const uint4*)(xt + ((size_t)(b * T_LEN + ts) * 256 + ci0 + halfo));
#pragma unroll
      for (int j = 0; j < 4; ++j) *(uint4*)&As[r * 72 + halfo + 8 * j] = src[j];
    } else {
      uint4 z = {0, 0, 0, 0};
#pragma unroll
      for (int j = 0; j < 4; ++j) *(uint4*)&As[r * 72 + halfo + 8 * j] = z;
    }
    if (tid < 128) {
      const uint4* s4 = (const uint4*)(wfp + ((size_t)r * 512 + tau * 256 + ci0 + halfo));
#pragma unroll
      for (int j = 0; j < 4; ++j) *(uint4*)&Bs[r * 72 + halfo + 8 * j] = s4[j];
    }
    __syncthreads();
#pragma unroll
    for (int kc = 0; kc < 2; ++kc) {
      const int k0 = kc * 32 + quad * 8;
      half8 af[4], bfr[2];
#pragma unroll
      for (int mi = 0; mi < 4; ++mi)
        af[mi] = *(const half8*)&As[(64 * wy + 16 * mi + l15) * 72 + k0];
#pragma unroll
      for (int ni = 0; ni < 2; ++ni)
        bfr[ni] = *(const half8*)&Bs[(32 * wx + 16 * ni + l15) * 72 + k0];
#pragma unroll
      for (int mi = 0; mi < 4; ++mi)
#pragma unroll
        for (int ni = 0; ni < 2; ++ni)
          acc[mi][ni] = mfma16(af[mi], bfr[ni], acc[mi][ni]);
    }
    __syncthreads();
  }
#pragma unroll
  for (int mi = 0; mi < 4; ++mi)
#pragma unroll
    for (int ni = 0; ni < 2; ++ni) {
      int col = 32 * wx + 16 * ni + l15;
      int rowb = 64 * wy + 16 * mi + quad * 4;
      float bo = bf[col];
      size_t base = ((size_t)p0 + rowb) * 64 + col;
#pragma unroll
      for (int reg = 0; reg < 4; ++reg) {
        float v = acc[mi][ni][reg] + bo;
        float e = __expf(2.f * v);
        h0[base + (size_t)64 * reg] = (_Float16)(1.f - 2.f * __builtin_amdgcn_rcpf(e + 1.f));
      }
    }
}

// ---------------- block-local skip flush phase (inside fused kernel) ------
// 512 threads = two independent 256-thread halves; half h handles n0=h*128.
// mode 0: Abuf = acc   mode 1: Abuf += acc   mode 2: skr = relu((acc+Abuf)*q^19+bsk)
__device__ __forceinline__ void flush_phase(
    int tid, int p0, const _Float16* __restrict__ zbuf,
    const _Float16* __restrict__ wskp, _Float16* __restrict__ Abuf,
    const float* __restrict__ bsk, _Float16* __restrict__ skr,
    _Float16* smem, int l0, int g, int mode)
{
  _Float16* As = smem;                                   // shared z tile
  const int half = tid >> 8;
  _Float16* Bsh = smem + (1 + half) * (128 * 72);        // per-half Wskip tile
  const int tloc = tid & 255;
  const int lane = tloc & 63, w4 = tloc >> 6;
  const int wx = w4 & 1, wy = w4 >> 1;
  const int l15 = lane & 15, quad = lane >> 4;
  const int n0 = half * 128;
  const int r = tloc >> 1, halfo = (tloc & 1) * 32;

  f32x4 acc[4][4];
#pragma unroll
  for (int mi = 0; mi < 4; ++mi)
#pragma unroll
    for (int ni = 0; ni < 4; ++ni) { f32x4 z = {0.f, 0.f, 0.f, 0.f}; acc[mi][ni] = z; }

  __syncthreads();  // all prior readers of smem done before restaging
#pragma unroll 1
  for (int j = 0; j < g; ++j) {
    const int lj = l0 + j;
    const _Float16* zsl = zbuf + (size_t)(lj & 7) * ((size_t)BT * 64);
    if (half == 0) {
      const uint4* sa = (const uint4*)(zsl + ((size_t)(p0 + r) * 64 + halfo));
#pragma unroll
      for (int jj = 0; jj < 4; ++jj) *(uint4*)&As[r * 72 + halfo + 8 * jj] = sa[jj];
    }
    const uint4* sb = (const uint4*)(wskp + ((size_t)(n0 + r) * 1280 + lj * 64 + halfo));
#pragma unroll
    for (int jj = 0; jj < 4; ++jj) *(uint4*)&Bsh[r * 72 + halfo + 8 * jj] = sb[jj];
    __syncthreads();
#pragma unroll
    for (int kc = 0; kc < 2; ++kc) {
      const int k0 = kc * 32 + quad * 8;
      half8 af[4], bfr[4];
#pragma unroll
      for (int mi = 0; mi < 4; ++mi)
        af[mi] = *(const half8*)&As[(64 * wy + 16 * mi + l15) * 72 + k0];
#pragma unroll
      for (int ni = 0; ni < 4; ++ni)
        bfr[ni] = *(const half8*)&Bsh[(64 * wx + 16 * ni + l15) * 72 + k0];
#pragma unroll
      for (int mi = 0; mi < 4; ++mi)
#pragma unroll
        for (int ni = 0; ni < 4; ++ni)
          acc[mi][ni] = mfma16(af[mi], bfr[ni], acc[mi][ni]);
    }
    __syncthreads();
  }
  const float Q19 = 0.0013810679320049757f;  // sqrt(0.5)^19
#pragma unroll
  for (int mi = 0; mi < 4; ++mi)
#pragma unroll
    for (int ni = 0; ni < 4; ++ni) {
      int col = n0 + 64 * wx + 16 * ni + l15;
      int rowb = 64 * wy + 16 * mi + quad * 4;
      size_t base = ((size_t)p0 + rowb) * 256 + col;
      if (mode == 2) {
        float bb = bsk[col];
#pragma unroll
        for (int reg = 0; reg < 4; ++reg) {
          float v = (acc[mi][ni][reg] + (float)Abuf[base + (size_t)256 * reg]) * Q19 + bb;
          skr[base + (size_t)256 * reg] = (_Float16)(v > 0.f ? v : 0.f);
        }
      } else if (mode == 1) {
#pragma unroll
        for (int reg = 0; reg < 4; ++reg) {
          size_t a = base + (size_t)256 * reg;
          Abuf[a] = (_Float16)((float)Abuf[a] + acc[mi][ni][reg]);
        }
      } else {
#pragma unroll
        for (int reg = 0; reg < 4; ++reg)
          Abuf[base + (size_t)256 * reg] = (_Float16)acc[mi][ni][reg];
      }
    }
}

// ---------------- fused 20-layer residual stack + flushes -----------------
// 512 blocks x 512 threads, exactly 2 blocks/CU (resource-guaranteed
// co-residency). Software grid barrier only between layers (h ping-pong
// hazard). Flushes at l=7/15/19 are block-local.
__global__ __launch_bounds__(512, 4) void wavenet_layers(
    _Float16* __restrict__ hA, _Float16* __restrict__ hB,
    const _Float16* __restrict__ ctp,
    const _Float16* __restrict__ wdp, const _Float16* __restrict__ wcp,
    const _Float16* __restrict__ wop, const _Float16* __restrict__ wskp,
    const float* __restrict__ bde, const float* __restrict__ bout,
    _Float16* __restrict__ zbuf, _Float16* __restrict__ Abuf,
    const float* __restrict__ bsk, _Float16* __restrict__ skr,
    unsigned* __restrict__ bar)
{
  __shared__ _Float16 smem[3 * 128 * 72];   // 55296 B
  __shared__ float bde_s[128];
  _Float16* As = smem;
  _Float16* Bs = smem + 128 * 72;
  _Float16* Cs = smem + 2 * 128 * 72;       // h[t] tile, kept for epilogue

  const int tid = threadIdx.x;
  const int lane = tid & 63, w = tid >> 6;        // 8 waves
  const int wx = w & 1, wy = w >> 1;              // 2 (N) x 4 (M)
  const int l15 = lane & 15, quad = lane >> 4;
  const int p0 = blockIdx.x * 128;
  const int b = p0 >> 14, t0 = p0 & (T_LEN - 1);
  const int r2 = tid >> 2, qo = (tid & 3) * 16;   // staging: row, 16-elem chunk
  const int o8 = (tid & 3) * 8;                   // K=32 stage chunk

#pragma unroll 1
  for (int l = 0; l < NLAYERS; ++l) {
    const _Float16* hprev = (l & 1) ? hB : hA;
    _Float16* hnext = (l & 1) ? hA : hB;
    const int d = 1 << (l % 10);
    const _Float16* wdp_l = wdp + (size_t)l * (3 * 128 * 64);
    const _Float16* wcp_l = wcp + (size_t)l * (128 * 96);
    const _Float16* wop_l = wop + (size_t)l * (64 * 64);
    const float* bout_l = bout + l * 64;
    _Float16* zslot = zbuf + (size_t)(l & 7) * ((size_t)BT * 64);

    if (tid < 128) bde_s[tid] = bde[l * 128 + tid];

    f32x4 acc[2][4];
#pragma unroll
    for (int mi = 0; mi < 2; ++mi)
#pragma unroll
      for (int ni = 0; ni < 4; ++ni) { f32x4 z = {0.f, 0.f, 0.f, 0.f}; acc[mi][ni] = z; }

    // K stages: h[t-2d], h[t-d], h[t] (64 each), cond[0:64], cond[64:96] (K=32)
    for (int s = 0; s < 5; ++s) {
      if (s < 3) {
        int ts = t0 + r2 - (2 - s) * d;
        if (ts >= 0) {
          const uint4* src = (const uint4*)(hprev + ((size_t)(b * T_LEN + ts) * 64 + qo));
          uint4 v0 = src[0], v1 = src[1];
          *(uint4*)&As[r2 * 72 + qo] = v0;
          *(uint4*)&As[r2 * 72 + qo + 8] = v1;
          if (s == 2) {           // keep h[t] tile for the residual epilogue
            *(uint4*)&Cs[r2 * 72 + qo] = v0;
            *(uint4*)&Cs[r2 * 72 + qo + 8] = v1;
          }
        } else {
          uint4 z4 = {0, 0, 0, 0};
          *(uint4*)&As[r2 * 72 + qo] = z4;
          *(uint4*)&As[r2 * 72 + qo + 8] = z4;
        }
        const uint4* sb = (const uint4*)(wdp_l + ((size_t)s * 8192 + r2 * 64 + qo));
        *(uint4*)&Bs[r2 * 72 + qo] = sb[0];
        *(uint4*)&Bs[r2 * 72 + qo + 8] = sb[1];
      } else if (s == 3) {
        const uint4* sa = (const uint4*)(ctp + ((size_t)(p0 + r2) * 96 + qo));
        *(uint4*)&As[r2 * 72 + qo] = sa[0];
        *(uint4*)&As[r2 * 72 + qo + 8] = sa[1];
        const uint4* sb = (const uint4*)(wcp_l + ((size_t)r2 * 96 + qo));
        *(uint4*)&Bs[r2 * 72 + qo] = sb[0];
        *(uint4*)&Bs[r2 * 72 + qo + 8] = sb[1];
      } else {  // s == 4: K=32 tail of cond
        *(uint4*)&As[r2 * 72 + o8] = *(const uint4*)(ctp + ((size_t)(p0 + r2) * 96 + 64 + o8));
        *(uint4*)&Bs[r2 * 72 + o8] = *(const uint4*)(wcp_l + ((size_t)r2 * 96 + 64 + o8));
      }
      __syncthreads();
      const int nkc = (s == 4) ? 1 : 2;
      for (int kc = 0; kc < nkc; ++kc) {
        const int k0 = kc * 32 + quad * 8;
        half8 af[2], bfr[4];
#pragma unroll
        for (int mi = 0; mi < 2; ++mi)
          af[mi] = *(const half8*)&As[(32 * wy + 16 * mi + l15) * 72 + k0];
#pragma unroll
        for (int ni = 0; ni < 4; ++ni) {
          int ncol = 32 * wx + 16 * (ni & 1) + 64 * (ni >> 1);  // ch and ch+64
          bfr[ni] = *(const half8*)&Bs[(ncol + l15) * 72 + k0];
        }
#pragma unroll
        for (int mi = 0; mi < 2; ++mi)
#pragma unroll
          for (int ni = 0; ni < 4; ++ni)
            acc[mi][ni] = mfma16(af[mi], bfr[ni], acc[mi][ni]);
      }
      __syncthreads();
    }

    // gate: z = tanh(y[ch]) * sigmoid(y[ch+64]) -> Zs (aliases As)
#pragma unroll
    for (int mi = 0; mi < 2; ++mi)
#pragma unroll
      for (int ni2 = 0; ni2 < 2; ++ni2) {
        int colb = 32 * wx + 16 * ni2 + l15;
        float ba = bde_s[colb], bb = bde_s[colb + 64];
#pragma unroll
        for (int reg = 0; reg < 4; ++reg) {
          float av = acc[mi][ni2][reg] + ba;
          float gv = acc[mi][ni2 + 2][reg] + bb;
          float ea = __expf(2.f * av);
          float th = 1.f - 2.f * __builtin_amdgcn_rcpf(ea + 1.f);
          float sg = __builtin_amdgcn_rcpf(1.f + __expf(-gv));
          As[(32 * wy + 16 * mi + quad * 4 + reg) * 72 + colb] = (_Float16)(th * sg);
        }
      }

    // stage W_out (64x64) into Bs (skip for dead h of layer 19)
    if (l < NLAYERS - 1 && tid < 256) {
      int row = tid >> 2;
      const uint4* sb = (const uint4*)(wop_l + ((size_t)row * 64 + qo));
      *(uint4*)&Bs[row * 72 + qo] = sb[0];
      *(uint4*)&Bs[row * 72 + qo + 8] = sb[1];
    }
    __syncthreads();

    // z -> global ring slot (consumed block-locally by flush_phase)
    {
      uint4 v0 = *(const uint4*)&As[r2 * 72 + qo];
      uint4 v1 = *(const uint4*)&As[r2 * 72 + qo + 8];
      uint4* dst = (uint4*)(zslot + ((size_t)(p0 + r2) * 64 + qo));
      dst[0] = v0; dst[1] = v1;
    }

    if (l < NLAYERS - 1) {
      // phase 4: h_out = (Wout*z + b_out + h_in) * SQH   (h_in from Cs/LDS)
      f32x4 a4[2][2];
#pragma unroll
      for (int mi = 0; mi < 2; ++mi)
#pragma unroll
        for (int ni = 0; ni < 2; ++ni) { f32x4 z = {0.f, 0.f, 0.f, 0.f}; a4[mi][ni] = z; }
#pragma unroll
      for (int kc = 0; kc < 2; ++kc) {
        const int k0 = kc * 32 + quad * 8;
        half8 af[2], bfr[2];
#pragma unroll
        for (int mi = 0; mi < 2; ++mi)
          af[mi] = *(const half8*)&As[(32 * wy + 16 * mi + l15) * 72 + k0];
#pragma unroll
        for (int ni = 0; ni < 2; ++ni)
          bfr[ni] = *(const half8*)&Bs[(32 * wx + 16 * ni + l15) * 72 + k0];
#pragma unroll
        for (int mi = 0; mi < 2; ++mi)
#pragma unroll
          for (int ni = 0; ni < 2; ++ni)
            a4[mi][ni] = mfma16(af[mi], bfr[ni], a4[mi][ni]);
      }
#pragma unroll
      for (int mi = 0; mi < 2; ++mi)
#pragma unroll
        for (int ni = 0; ni < 2; ++ni) {
          int col = 32 * wx + 16 * ni + l15;
          int rowb = 32 * wy + 16 * mi + quad * 4;
          float bo = bout_l[col];
          size_t base = ((size_t)p0 + rowb) * 64 + col;
#pragma unroll
          for (int reg = 0; reg < 4; ++reg) {
            float hv = (float)Cs[(rowb + reg) * 72 + col];
            hnext[base + (size_t)64 * reg] = (_Float16)((a4[mi][ni][reg] + bo + hv) * SQH);
          }
        }
    } else {
      __threadfence_block();  // own z-slot store -> own reload in flush below
    }

    // block-local deferred skip flushes (no grid sync needed: same-p0 data)
    if (l == 7 || l == 15 || l == NLAYERS - 1) {
      const int l0   = (l == 7) ? 0 : (l == 15) ? 8 : 16;
      const int g    = (l == NLAYERS - 1) ? 4 : 8;
      const int mode = (l == 7) ? 0 : (l == 15) ? 1 : 2;
      flush_phase(tid, p0, zbuf, wskp, Abuf, bsk, skr, smem, l0, g, mode);
    }

    if (l < NLAYERS - 1) gridbar(bar);
  }
}

// ---------------- generic 256x256 GEMM (last1 / last2) -------------------
__global__ __launch_bounds__(256, 4) void gemm256(
    const _Float16* __restrict__ Asrc, const _Float16* __restrict__ Bp,
    const float* __restrict__ bias, void* __restrict__ dst, int mode)
{
  __shared__ _Float16 smem[2 * 128 * 72];
  _Float16* As = smem;
  _Float16* Bs = smem + 128 * 72;
  const int tid = threadIdx.x;
  const int lane = tid & 63, w = tid >> 6;
  const int wx = w & 1, wy = w >> 1;
  const int l15 = lane & 15, quad = lane >> 4;
  const int p0 = blockIdx.x * 128;
  const int n0 = blockIdx.y * 128;
  const int r = tid >> 1, halfo = (tid & 1) * 32;

  f32x4 acc[4][4];
#pragma unroll
  for (int mi = 0; mi < 4; ++mi)
#pragma unroll
    for (int ni = 0; ni < 4; ++ni) { f32x4 z = {0.f, 0.f, 0.f, 0.f}; acc[mi][ni] = z; }

  for (int c4 = 0; c4 < 4; ++c4) {
    int k0g = c4 * 64;
    const uint4* sa = (const uint4*)(Asrc + ((size_t)(p0 + r) * 256 + k0g + halfo));
#pragma unroll
    for (int jj = 0; jj < 4; ++jj) *(uint4*)&As[r * 72 + halfo + 8 * jj] = sa[jj];
    const uint4* sb = (const uint4*)(Bp + ((size_t)(n0 + r) * 256 + k0g + halfo));
#pragma unroll
    for (int jj = 0; jj < 4; ++jj) *(uint4*)&Bs[r * 72 + halfo + 8 * jj] = sb[jj];
    __syncthreads();
#pragma unroll
    for (int kc = 0; kc < 2; ++kc) {
      const int k0 = kc * 32 + quad * 8;
      half8 af[4], bfr[4];
#pragma unroll
      for (int mi = 0; mi < 4; ++mi)
        af[mi] = *(const half8*)&As[(64 * wy + 16 * mi + l15) * 72 + k0];
#pragma unroll
      for (int ni = 0; ni < 4; ++ni)
        bfr[ni] = *(const half8*)&Bs[(64 * wx + 16 * ni + l15) * 72 + k0];
#pragma unroll
      for (int mi = 0; mi < 4; ++mi)
#pragma unroll
        for (int ni = 0; ni < 4; ++ni)
          acc[mi][ni] = mfma16(af[mi], bfr[ni], acc[mi][ni]);
    }
    __syncthreads();
  }
  if (mode == 0) {
#pragma unroll
    for (int mi = 0; mi < 4; ++mi)
#pragma unroll
      for (int ni = 0; ni < 4; ++ni) {
        int col = n0 + 64 * wx + 16 * ni + l15;
        int rowb = 64 * wy + 16 * mi + quad * 4;
        float bv = bias[col];
        _Float16* o = (_Float16*)dst;
#pragma unroll
        for (int reg = 0; reg < 4; ++reg) {
          float v = acc[mi][ni][reg] + bv;
          o[((size_t)(p0 + rowb + reg)) * 256 + col] = (_Float16)(v > 0.f ? v : 0.f);
        }
      }
  } else {
    // transposed coalesced store: two passes of 64 columns through LDS
    float* Ts = (float*)smem;       // 64 x 132 floats = 33792 B
    const int b = p0 >> 14, t0g = p0 & (T_LEN - 1);
    for (int pass = 0; pass < 2; ++pass) {
      if (wx == pass) {
#pragma unroll
        for (int mi = 0; mi < 4; ++mi)
#pragma unroll
          for (int ni = 0; ni < 4; ++ni) {
            int col_l = 16 * ni + l15;
            float bv = bias[n0 + 64 * pass + col_l];
            int tl = 64 * wy + 16 * mi + quad * 4;
#pragma unroll
            for (int reg = 0; reg < 4; ++reg)
              Ts[col_l * 132 + tl + reg] = acc[mi][ni][reg] + bv;
          }
      }
      __syncthreads();
      {
        int col_l = tid >> 2;
        int tq = (tid & 3) * 32;
        float* o = (float*)dst + ((size_t)b * 256 + n0 + 64 * pass + col_l) * T_LEN + t0g + tq;
#pragma unroll
        for (int j = 0; j < 8; ++j)
          *(float4*)(o + 4 * j) = *(const float4*)&Ts[col_l * 132 + tq + 4 * j];
      }
      __syncthreads();
    }
  }
}

extern "C" void kernel_launch(void* const* d_in, const int* in_sizes, int n_in,
                              void* d_out, int out_size, void* d_ws, size_t ws_size,
                              hipStream_t stream)
{
  const float* x     = (const float*)d_in[0];
  const float* c     = (const float*)d_in[1];
  const float* Wf    = (const float*)d_in[2];
  const float* bf    = (const float*)d_in[3];
  const float* Wdil  = (const float*)d_in[4];
  const float* bdil  = (const float*)d_in[5];
  const float* Wc    = (const float*)d_in[6];
  const float* bc    = (const float*)d_in[7];
  const float* Wskip = (const float*)d_in[8];
  const float* bskip = (const float*)d_in[9];
  const float* Wout  = (const float*)d_in[10];
  const float* bout  = (const float*)d_in[11];
  const float* Wl1   = (const float*)d_in[12];
  const float* bl1   = (const float*)d_in[13];
  const float* Wl2   = (const float*)d_in[14];
  const float* bl2   = (const float*)d_in[15];

  char* base = (char*)d_ws;
  _Float16* zbuf = (_Float16*)base;
  _Float16* xt   = zbuf;
  _Float16* skr  = zbuf + (size_t)4 * BT * 64;
  _Float16* y1   = zbuf;
  _Float16* ctp  = (_Float16*)(base + 67108864);   // BT*96 f16 = 12.58 MB
  _Float16* hA   = (_Float16*)(base + 79691776);   // BT*64 f16 = 8.39 MB
  _Float16* hB   = (_Float16*)(base + 88080384);
  _Float16* wdp  = (_Float16*)(base + 96468992);
  _Float16* wcp  = wdp  + (size_t)20 * 3 * 128 * 64;
  _Float16* wop  = wcp  + (size_t)20 * 128 * 96;
  _Float16* wskp = wop  + (size_t)20 * 64 * 64;
  _Float16* wfp  = wskp + (size_t)256 * 1280;
  _Float16* wl1p = wfp  + (size_t)64 * 512;
  _Float16* wl2p = wl1p + (size_t)256 * 256;
  float*    bde  = (float*)(wl2p + (size_t)256 * 256);
  float*    bsk  = bde + 20 * 128;
  unsigned* bar  = (unsigned*)(bsk + 256);
  _Float16* Abuf = (_Float16*)d_out;               // f16 skip accumulator

  prep_pack<<<2048, 256, 0, stream>>>(Wf, Wdil, Wc, Wskip, Wout, Wl1, Wl2,
                                      bdil, bc, bskip,
                                      wdp, wcp, wop, wskp, wfp, wl1p, wl2p,
                                      bde, bsk, bar);
  tr_kernel<<<NB * (T_LEN / 32) * 8, 256, 0, stream>>>(x, xt, 256, 256, 8);
  tr_kernel<<<NB * (T_LEN / 32) * 3, 256, 0, stream>>>(c, ctp, 80, 96, 3);
  first_conv<<<512, 256, 0, stream>>>(xt, wfp, bf, hA);

  wavenet_layers<<<NBLK, 512, 0, stream>>>(hA, hB, ctp, wdp, wcp, wop, wskp,
                                           bde, bout, zbuf, Abuf, bsk, skr, bar);

  gemm256<<<dim3(512, 2), 256, 0, stream>>>(skr, wl1p, bl1, (void*)y1, 0);
  gemm256<<<dim3(512, 2), 256, 0, stream>>>(y1, wl2p, bl2, d_out, 1);
}

// Round 4
// 1150.052 us; speedup vs baseline: 2.4612x; 1.6121x over previous
//
#include <hip/hip_runtime.h>
#include <math.h>

// WaveNet (4,256,16384), 20 layers. Round 8: fused persistent kernel with
// FENCE-FREE grid barrier. Round 7 showed the per-barrier agent acquire fence
// (full L2 invalidate, 19x/block) forced cold-cache HBM refill of ctp/weights
// every layer (707 GB/s latency-bound, 82us/layer). Fix: only h crosses
// blocks/XCDs, so move h via sc0 sc1 (system-scope, L1/L2-bypass,
// MALL-coherent) inline-asm loads/stores and DELETE all fences. ctp/weights/z
// stay L2-resident for the whole kernel. Barrier = monotonic counter
// (target NBLK*round, no reset): each thread drains its own sc0sc1 stores
// (vmcnt(0)) before arrival; MALL store-ack before the MALL arrival-RMW gives
// cross-block visibility with zero cache maintenance.
// h epilogue stores now staged through LDS: 2x16B coalesced per thread.

#define T_LEN   16384
#define NB      4
#define BT      (NB * T_LEN)     // 65536
#define NLAYERS 20
#define NBLK    512
#define SQH     0.70710678118654752440f

typedef _Float16 half8 __attribute__((ext_vector_type(8)));
typedef _Float16 half4 __attribute__((ext_vector_type(4)));
typedef float f32x4 __attribute__((ext_vector_type(4)));
typedef unsigned int u32x4 __attribute__((ext_vector_type(4)));

__device__ inline f32x4 mfma16(half8 a, half8 b, f32x4 c) {
  return __builtin_amdgcn_mfma_f32_16x16x32_f16(a, b, c, 0, 0, 0);
}

// -------- MALL-coherent (system-scope, cache-bypass) 32B load/store -------
__device__ __forceinline__ void ld32_mall(const _Float16* p, u32x4& v0, u32x4& v1) {
  asm volatile("global_load_dwordx4 %0, %2, off sc0 sc1\n\t"
               "global_load_dwordx4 %1, %2, off offset:16 sc0 sc1\n\t"
               "s_waitcnt vmcnt(0)"
               : "=&v"(v0), "=&v"(v1) : "v"(p) : "memory");
}
__device__ __forceinline__ void st32_mall(_Float16* p, u32x4 v0, u32x4 v1) {
  asm volatile("global_store_dwordx4 %0, %1, off sc0 sc1\n\t"
               "global_store_dwordx4 %0, %2, off offset:16 sc0 sc1"
               :: "v"(p), "v"(v0), "v"(v1) : "memory");
}

// -------- fence-free software grid barrier (monotonic counter) ------------
// Correct for all-resident blocks: counter reaches NBLK*r only when every
// block has arrived r times (round r+1 arrivals require passing round r).
__device__ __forceinline__ void gridbar(unsigned* bar, unsigned target) {
  asm volatile("s_waitcnt vmcnt(0)" ::: "memory");  // drain own sc0sc1 stores
  __syncthreads();
  if (threadIdx.x == 0) {
    __hip_atomic_fetch_add(&bar[0], 1u, __ATOMIC_RELAXED,
                           __HIP_MEMORY_SCOPE_AGENT);
    while (__hip_atomic_load(&bar[0], __ATOMIC_RELAXED,
                             __HIP_MEMORY_SCOPE_AGENT) < target)
      __builtin_amdgcn_s_sleep(8);
  }
  __syncthreads();
}

// ---------------- weight packing (f16) ----------------
__global__ __launch_bounds__(256) void prep_pack(
    const float* __restrict__ Wf, const float* __restrict__ Wdil,
    const float* __restrict__ Wc, const float* __restrict__ Wskip,
    const float* __restrict__ Wout, const float* __restrict__ Wl1,
    const float* __restrict__ Wl2, const float* __restrict__ bdil,
    const float* __restrict__ bc, const float* __restrict__ bskip,
    _Float16* __restrict__ wdp, _Float16* __restrict__ wcp,
    _Float16* __restrict__ wop, _Float16* __restrict__ wskp,
    _Float16* __restrict__ wfp, _Float16* __restrict__ wl1p,
    _Float16* __restrict__ wl2p, float* __restrict__ bde,
    float* __restrict__ bsk, unsigned* __restrict__ bar)
{
  if (blockIdx.x == 0 && threadIdx.x < 2) bar[threadIdx.x] = 0u;  // barrier init
  const float Q = 0.70710678118654752440f;
  const int WDP_E = 20 * 3 * 128 * 64;   // [l][tau][n][kc]
  const int WCP_E = 20 * 128 * 96;       // [l][n][kc pad96]
  const int WOP_E = 20 * 64 * 64;        // [l][n][kc]
  const int WSK_E = 256 * 1280;          // [n][l*64+kc], scale q^(1-l)
  const int WFP_E = 64 * 512;            // [n][tau*256+ci]
  const int WL_E  = 256 * 256;
  const int BDE_E = 20 * 128;
  const int BSK_E = 256;
  const int TOTAL = WDP_E + WCP_E + WOP_E + WSK_E + WFP_E + 2 * WL_E + BDE_E + BSK_E;
  for (int i = blockIdx.x * blockDim.x + threadIdx.x; i < TOTAL;
       i += gridDim.x * blockDim.x) {
    int j = i;
    if (j < WDP_E) {
      int l = j / (3 * 128 * 64); int r2 = j % (3 * 128 * 64);
      int tau = r2 / (128 * 64);  int r3 = r2 % (128 * 64);
      int n = r3 >> 6; int kc = r3 & 63;
      wdp[j] = (_Float16)Wdil[((l * 128 + n) * 64 + kc) * 3 + tau];
      continue;
    }
    j -= WDP_E;
    if (j < WCP_E) {
      int l = j / (128 * 96); int r2 = j % (128 * 96);
      int n = r2 / 96; int kc = r2 % 96;
      wcp[j] = (_Float16)(kc < 80 ? Wc[(l * 128 + n) * 80 + kc] : 0.f);
      continue;
    }
    j -= WCP_E;
    if (j < WOP_E) {
      int l = j >> 12; int r2 = j & 4095;
      int n = r2 >> 6; int kc = r2 & 63;
      wop[j] = (_Float16)Wout[(l * 64 + n) * 64 + kc];
      continue;
    }
    j -= WOP_E;
    if (j < WSK_E) {
      int n = j / 1280; int k = j % 1280;
      int l = k >> 6; int kc = k & 63;
      float f = (l == 0) ? 1.f : powf(Q, (float)(1 - l));
      wskp[j] = (_Float16)(Wskip[(l * 256 + n) * 64 + kc] * f);
      continue;
    }
    j -= WSK_E;
    if (j < WFP_E) {
      int n = j >> 9; int k = j & 511;
      int tau = k >> 8; int ci = k & 255;
      wfp[j] = (_Float16)Wf[(n * 256 + ci) * 2 + tau];
      continue;
    }
    j -= WFP_E;
    if (j < WL_E) { wl1p[j] = (_Float16)Wl1[j]; continue; }
    j -= WL_E;
    if (j < WL_E) { wl2p[j] = (_Float16)Wl2[j]; continue; }
    j -= WL_E;
    if (j < BDE_E) { bde[j] = bdil[j] + bc[j]; continue; }
    j -= BDE_E;
    {
      int n = j;
      float s = 0.f;
      for (int l = 0; l < NLAYERS; ++l) {
        float w = powf(Q, (float)(l == 0 ? 19 : 20 - l));
        s += bskip[l * 256 + n] * w;
      }
      bsk[n] = s;
    }
  }
}

// ---------------- transpose (B,C,T) f32 -> (BT,Cpad) f16 ----------------
__global__ __launch_bounds__(256) void tr_kernel(
    const float* __restrict__ src, _Float16* __restrict__ dst, int C, int Cpad, int CB)
{
  __shared__ float tile[32 * 33];
  int bid = blockIdx.x;
  int cb = bid % CB;
  int tb = (bid / CB) % (T_LEN / 32);
  int bb = bid / (CB * (T_LEN / 32));
  int t0 = tb * 32, ch0 = cb * 32;
  int tl = threadIdx.x & 31, cl = threadIdx.x >> 5;
#pragma unroll
  for (int i = 0; i < 4; ++i) {
    int ch = cl + 8 * i;
    float v = (ch0 + ch < C) ? src[((size_t)bb * C + ch0 + ch) * T_LEN + t0 + tl] : 0.f;
    tile[ch * 33 + tl] = v;
  }
  __syncthreads();
  int t = threadIdx.x >> 3;
  int c4 = (threadIdx.x & 7) * 4;
  half4 hv = {(_Float16)tile[(c4 + 0) * 33 + t], (_Float16)tile[(c4 + 1) * 33 + t],
              (_Float16)tile[(c4 + 2) * 33 + t], (_Float16)tile[(c4 + 3) * 33 + t]};
  *(half4*)&dst[((size_t)bb * T_LEN + t0 + t) * Cpad + ch0 + c4] = hv;
}

// ---------------- first conv: h0 = tanh(Wf*[x(t-1);x(t)] + bf), f16 out ----
__global__ __launch_bounds__(256, 4) void first_conv(
    const _Float16* __restrict__ xt, const _Float16* __restrict__ wfp,
    const float* __restrict__ bf, _Float16* __restrict__ h0)
{
  __shared__ _Float16 As[128 * 72];
  __shared__ _Float16 Bs[64 * 72];
  const int tid = threadIdx.x;
  const int lane = tid & 63, w = tid >> 6;
  const int wx = w & 1, wy = w >> 1;
  const int l15 = lane & 15, quad = lane >> 4;
  const int p0 = blockIdx.x * 128;
  const int b = p0 >> 14, t0 = p0 & (T_LEN - 1);
  const int r = tid >> 1, halfo = (tid & 1) * 32;

  f32x4 acc[4][2];
#pragma unroll
  for (int mi = 0; mi < 4; ++mi)
#pragma unroll
    for (int ni = 0; ni < 2; ++ni) { f32x4 z = {0.f, 0.f, 0.f, 0.f}; acc[mi][ni] = z; }

  for (int s = 0; s < 8; ++s) {
    int tau = s >> 2, ci0 = (s & 3) * 64;
    int ts = t0 + r - 1 + tau;
    if (ts >= 0) {
      const uint4* src = (const uint4*)(xt + ((size_t)(b * T_LEN + ts) * 256 + ci0 + halfo));
#pragma unroll
      for (int j = 0; j < 4; ++j) *(uint4*)&As[r * 72 + halfo + 8 * j] = src[j];
    } else {
      uint4 z = {0, 0, 0, 0};
#pragma unroll
      for (int j = 0; j < 4; ++j) *(uint4*)&As[r * 72 + halfo + 8 * j] = z;
    }
    if (tid < 128) {
      const uint4* s4 = (const uint4*)(wfp + ((size_t)r * 512 + tau * 256 + ci0 + halfo));
#pragma unroll
      for (int j = 0; j < 4; ++j) *(uint4*)&Bs[r * 72 + halfo + 8 * j] = s4[j];
    }
    __syncthreads();
#pragma unroll
    for (int kc = 0; kc < 2; ++kc) {
      const int k0 = kc * 32 + quad * 8;
      half8 af[4], bfr[2];
#pragma unroll
      for (int mi = 0; mi < 4; ++mi)
        af[mi] = *(const half8*)&As[(64 * wy + 16 * mi + l15) * 72 + k0];
#pragma unroll
      for (int ni = 0; ni < 2; ++ni)
        bfr[ni] = *(const half8*)&Bs[(32 * wx + 16 * ni + l15) * 72 + k0];
#pragma unroll
      for (int mi = 0; mi < 4; ++mi)
#pragma unroll
        for (int ni = 0; ni < 2; ++ni)
          acc[mi][ni] = mfma16(af[mi], bfr[ni], acc[mi][ni]);
    }
    __syncthreads();
  }
#pragma unroll
  for (int mi = 0; mi < 4; ++mi)
#pragma unroll
    for (int ni = 0; ni < 2; ++ni) {
      int col = 32 * wx + 16 * ni + l15;
      int rowb = 64 * wy + 16 * mi + quad * 4;
      float bo = bf[col];
      size_t base = ((size_t)p0 + rowb) * 64 + col;
#pragma unroll
      for (int reg = 0; reg < 4; ++reg) {
        float v = acc[mi][ni][reg] + bo;
        float e = __expf(2.f * v);
        h0[base + (size_t)64 * reg] = (_Float16)(1.f - 2.f * __builtin_amdgcn_rcpf(e + 1.f));
      }
    }
}

// ---------------- block-local skip flush phase (inside fused kernel) ------
// 512 threads = two independent 256-thread halves; half h handles n0=h*128.
// mode 0: Abuf = acc   mode 1: Abuf += acc   mode 2: skr = relu((acc+Abuf)*q^19+bsk)
__device__ __forceinline__ void flush_phase(
    int tid, int p0, const _Float16* __restrict__ zbuf,
    const _Float16* __restrict__ wskp, _Float16* __restrict__ Abuf,
    const float* __restrict__ bsk, _Float16* __restrict__ skr,
    _Float16* smem, int l0, int g, int mode)
{
  _Float16* As = smem;                                   // shared z tile
  const int half = tid >> 8;
  _Float16* Bsh = smem + (1 + half) * (128 * 72);        // per-half Wskip tile
  const int tloc = tid & 255;
  const int lane = tloc & 63, w4 = tloc >> 6;
  const int wx = w4 & 1, wy = w4 >> 1;
  const int l15 = lane & 15, quad = lane >> 4;
  const int n0 = half * 128;
  const int r = tloc >> 1, halfo = (tloc & 1) * 32;

  f32x4 acc[4][4];
#pragma unroll
  for (int mi = 0; mi < 4; ++mi)
#pragma unroll
    for (int ni = 0; ni < 4; ++ni) { f32x4 z = {0.f, 0.f, 0.f, 0.f}; acc[mi][ni] = z; }

  __syncthreads();  // all prior readers of smem done before restaging
#pragma unroll 1
  for (int j = 0; j < g; ++j) {
    const int lj = l0 + j;
    const _Float16* zsl = zbuf + (size_t)(lj & 7) * ((size_t)BT * 64);
    if (half == 0) {
      const uint4* sa = (const uint4*)(zsl + ((size_t)(p0 + r) * 64 + halfo));
#pragma unroll
      for (int jj = 0; jj < 4; ++jj) *(uint4*)&As[r * 72 + halfo + 8 * jj] = sa[jj];
    }
    const uint4* sb = (const uint4*)(wskp + ((size_t)(n0 + r) * 1280 + lj * 64 + halfo));
#pragma unroll
    for (int jj = 0; jj < 4; ++jj) *(uint4*)&Bsh[r * 72 + halfo + 8 * jj] = sb[jj];
    __syncthreads();
#pragma unroll
    for (int kc = 0; kc < 2; ++kc) {
      const int k0 = kc * 32 + quad * 8;
      half8 af[4], bfr[4];
#pragma unroll
      for (int mi = 0; mi < 4; ++mi)
        af[mi] = *(const half8*)&As[(64 * wy + 16 * mi + l15) * 72 + k0];
#pragma unroll
      for (int ni = 0; ni < 4; ++ni)
        bfr[ni] = *(const half8*)&Bsh[(64 * wx + 16 * ni + l15) * 72 + k0];
#pragma unroll
      for (int mi = 0; mi < 4; ++mi)
#pragma unroll
        for (int ni = 0; ni < 4; ++ni)
          acc[mi][ni] = mfma16(af[mi], bfr[ni], acc[mi][ni]);
    }
    __syncthreads();
  }
  const float Q19 = 0.0013810679320049757f;  // sqrt(0.5)^19
#pragma unroll
  for (int mi = 0; mi < 4; ++mi)
#pragma unroll
    for (int ni = 0; ni < 4; ++ni) {
      int col = n0 + 64 * wx + 16 * ni + l15;
      int rowb = 64 * wy + 16 * mi + quad * 4;
      size_t base = ((size_t)p0 + rowb) * 256 + col;
      if (mode == 2) {
        float bb = bsk[col];
#pragma unroll
        for (int reg = 0; reg < 4; ++reg) {
          float v = (acc[mi][ni][reg] + (float)Abuf[base + (size_t)256 * reg]) * Q19 + bb;
          skr[base + (size_t)256 * reg] = (_Float16)(v > 0.f ? v : 0.f);
        }
      } else if (mode == 1) {
#pragma unroll
        for (int reg = 0; reg < 4; ++reg) {
          size_t a = base + (size_t)256 * reg;
          Abuf[a] = (_Float16)((float)Abuf[a] + acc[mi][ni][reg]);
        }
      } else {
#pragma unroll
        for (int reg = 0; reg < 4; ++reg)
          Abuf[base + (size_t)256 * reg] = (_Float16)acc[mi][ni][reg];
      }
    }
}

// ---------------- fused 20-layer residual stack + flushes -----------------
// 512 blocks x 512 threads, exactly 2 blocks/CU (resource-guaranteed
// co-residency). Fence-free software grid barrier between layers; h moves
// via sc0sc1 (MALL-coherent); everything else stays L2-cached all 20 layers.
__global__ __launch_bounds__(512, 4) void wavenet_layers(
    _Float16* __restrict__ hA, _Float16* __restrict__ hB,
    const _Float16* __restrict__ ctp,
    const _Float16* __restrict__ wdp, const _Float16* __restrict__ wcp,
    const _Float16* __restrict__ wop, const _Float16* __restrict__ wskp,
    const float* __restrict__ bde, const float* __restrict__ bout,
    _Float16* __restrict__ zbuf, _Float16* __restrict__ Abuf,
    const float* __restrict__ bsk, _Float16* __restrict__ skr,
    unsigned* __restrict__ bar)
{
  __shared__ _Float16 smem[3 * 128 * 72];   // 55296 B
  __shared__ float bde_s[128];
  _Float16* As = smem;
  _Float16* Bs = smem + 128 * 72;
  _Float16* Cs = smem + 2 * 128 * 72;       // h[t] tile; epilogue in/out

  const int tid = threadIdx.x;
  const int lane = tid & 63, w = tid >> 6;        // 8 waves
  const int wx = w & 1, wy = w >> 1;              // 2 (N) x 4 (M)
  const int l15 = lane & 15, quad = lane >> 4;
  const int p0 = blockIdx.x * 128;
  const int b = p0 >> 14, t0 = p0 & (T_LEN - 1);
  const int r2 = tid >> 2, qo = (tid & 3) * 16;   // staging: row, 16-elem chunk
  const int o8 = (tid & 3) * 8;                   // K=32 stage chunk

#pragma unroll 1
  for (int l = 0; l < NLAYERS; ++l) {
    const _Float16* hprev = (l & 1) ? hB : hA;
    _Float16* hnext = (l & 1) ? hA : hB;
    const int d = 1 << (l % 10);
    const _Float16* wdp_l = wdp + (size_t)l * (3 * 128 * 64);
    const _Float16* wcp_l = wcp + (size_t)l * (128 * 96);
    const _Float16* wop_l = wop + (size_t)l * (64 * 64);
    const float* bout_l = bout + l * 64;
    _Float16* zslot = zbuf + (size_t)(l & 7) * ((size_t)BT * 64);

    if (tid < 128) bde_s[tid] = bde[l * 128 + tid];

    f32x4 acc[2][4];
#pragma unroll
    for (int mi = 0; mi < 2; ++mi)
#pragma unroll
      for (int ni = 0; ni < 4; ++ni) { f32x4 z = {0.f, 0.f, 0.f, 0.f}; acc[mi][ni] = z; }

    // K stages: h[t-2d], h[t-d], h[t] (64 each), cond[0:64], cond[64:96] (K=32)
    for (int s = 0; s < 5; ++s) {
      if (s < 3) {
        int ts = t0 + r2 - (2 - s) * d;
        if (ts >= 0) {
          u32x4 v0, v1;
          ld32_mall(hprev + ((size_t)(b * T_LEN + ts) * 64 + qo), v0, v1);
          *(u32x4*)&As[r2 * 72 + qo] = v0;
          *(u32x4*)&As[r2 * 72 + qo + 8] = v1;
          if (s == 2) {           // keep h[t] tile for the residual epilogue
            *(u32x4*)&Cs[r2 * 72 + qo] = v0;
            *(u32x4*)&Cs[r2 * 72 + qo + 8] = v1;
          }
        } else {
          uint4 z4 = {0, 0, 0, 0};
          *(uint4*)&As[r2 * 72 + qo] = z4;
          *(uint4*)&As[r2 * 72 + qo + 8] = z4;
        }
        const uint4* sb = (const uint4*)(wdp_l + ((size_t)s * 8192 + r2 * 64 + qo));
        *(uint4*)&Bs[r2 * 72 + qo] = sb[0];
        *(uint4*)&Bs[r2 * 72 + qo + 8] = sb[1];
      } else if (s == 3) {
        const uint4* sa = (const uint4*)(ctp + ((size_t)(p0 + r2) * 96 + qo));
        *(uint4*)&As[r2 * 72 + qo] = sa[0];
        *(uint4*)&As[r2 * 72 + qo + 8] = sa[1];
        const uint4* sb = (const uint4*)(wcp_l + ((size_t)r2 * 96 + qo));
        *(uint4*)&Bs[r2 * 72 + qo] = sb[0];
        *(uint4*)&Bs[r2 * 72 + qo + 8] = sb[1];
      } else {  // s == 4: K=32 tail of cond
        *(uint4*)&As[r2 * 72 + o8] = *(const uint4*)(ctp + ((size_t)(p0 + r2) * 96 + 64 + o8));
        *(uint4*)&Bs[r2 * 72 + o8] = *(const uint4*)(wcp_l + ((size_t)r2 * 96 + 64 + o8));
      }
      __syncthreads();
      const int nkc = (s == 4) ? 1 : 2;
      for (int kc = 0; kc < nkc; ++kc) {
        const int k0 = kc * 32 + quad * 8;
        half8 af[2], bfr[4];
#pragma unroll
        for (int mi = 0; mi < 2; ++mi)
          af[mi] = *(const half8*)&As[(32 * wy + 16 * mi + l15) * 72 + k0];
#pragma unroll
        for (int ni = 0; ni < 4; ++ni) {
          int ncol = 32 * wx + 16 * (ni & 1) + 64 * (ni >> 1);  // ch and ch+64
          bfr[ni] = *(const half8*)&Bs[(ncol + l15) * 72 + k0];
        }
#pragma unroll
        for (int mi = 0; mi < 2; ++mi)
#pragma unroll
          for (int ni = 0; ni < 4; ++ni)
            acc[mi][ni] = mfma16(af[mi], bfr[ni], acc[mi][ni]);
      }
      __syncthreads();
    }

    // gate: z = tanh(y[ch]) * sigmoid(y[ch+64]) -> Zs (aliases As)
#pragma unroll
    for (int mi = 0; mi < 2; ++mi)
#pragma unroll
      for (int ni2 = 0; ni2 < 2; ++ni2) {
        int colb = 32 * wx + 16 * ni2 + l15;
        float ba = bde_s[colb], bb = bde_s[colb + 64];
#pragma unroll
        for (int reg = 0; reg < 4; ++reg) {
          float av = acc[mi][ni2][reg] + ba;
          float gv = acc[mi][ni2 + 2][reg] + bb;
          float ea = __expf(2.f * av);
          float th = 1.f - 2.f * __builtin_amdgcn_rcpf(ea + 1.f);
          float sg = __builtin_amdgcn_rcpf(1.f + __expf(-gv));
          As[(32 * wy + 16 * mi + quad * 4 + reg) * 72 + colb] = (_Float16)(th * sg);
        }
      }

    // stage W_out (64x64) into Bs (skip for dead h of layer 19)
    if (l < NLAYERS - 1 && tid < 256) {
      int row = tid >> 2;
      const uint4* sb = (const uint4*)(wop_l + ((size_t)row * 64 + qo));
      *(uint4*)&Bs[row * 72 + qo] = sb[0];
      *(uint4*)&Bs[row * 72 + qo + 8] = sb[1];
    }
    __syncthreads();

    // z -> global ring slot (consumed block-locally by flush_phase)
    {
      uint4 v0 = *(const uint4*)&As[r2 * 72 + qo];
      uint4 v1 = *(const uint4*)&As[r2 * 72 + qo + 8];
      uint4* dst = (uint4*)(zslot + ((size_t)(p0 + r2) * 64 + qo));
      dst[0] = v0; dst[1] = v1;
    }

    if (l < NLAYERS - 1) {
      // phase 4: h_out = (Wout*z + b_out + h_in) * SQH  (h_in from Cs; result
      // written back into Cs, then copied out coalesced via sc0sc1)
      f32x4 a4[2][2];
#pragma unroll
      for (int mi = 0; mi < 2; ++mi)
#pragma unroll
        for (int ni = 0; ni < 2; ++ni) { f32x4 z = {0.f, 0.f, 0.f, 0.f}; a4[mi][ni] = z; }
#pragma unroll
      for (int kc = 0; kc < 2; ++kc) {
        const int k0 = kc * 32 + quad * 8;
        half8 af[2], bfr[2];
#pragma unroll
        for (int mi = 0; mi < 2; ++mi)
          af[mi] = *(const half8*)&As[(32 * wy + 16 * mi + l15) * 72 + k0];
#pragma unroll
        for (int ni = 0; ni < 2; ++ni)
          bfr[ni] = *(const half8*)&Bs[(32 * wx + 16 * ni + l15) * 72 + k0];
#pragma unroll
        for (int mi = 0; mi < 2; ++mi)
#pragma unroll
          for (int ni = 0; ni < 2; ++ni)
            a4[mi][ni] = mfma16(af[mi], bfr[ni], a4[mi][ni]);
      }
#pragma unroll
      for (int mi = 0; mi < 2; ++mi)
#pragma unroll
        for (int ni = 0; ni < 2; ++ni) {
          int col = 32 * wx + 16 * ni + l15;
          int rowb = 32 * wy + 16 * mi + quad * 4;
          float bo = bout_l[col];
#pragma unroll
          for (int reg = 0; reg < 4; ++reg) {
            float hv = (float)Cs[(rowb + reg) * 72 + col];
            Cs[(rowb + reg) * 72 + col] =
                (_Float16)((a4[mi][ni][reg] + bo + hv) * SQH);
          }
        }
      __syncthreads();
      {
        u32x4 v0 = *(const u32x4*)&Cs[r2 * 72 + qo];
        u32x4 v1 = *(const u32x4*)&Cs[r2 * 72 + qo + 8];
        st32_mall(hnext + ((size_t)(p0 + r2) * 64 + qo), v0, v1);
      }
    } else {
      __threadfence_block();  // own z-slot store -> own reload in flush below
    }

    // block-local deferred skip flushes (no grid sync needed: same-p0 data)
    if (l == 7 || l == 15 || l == NLAYERS - 1) {
      const int l0   = (l == 7) ? 0 : (l == 15) ? 8 : 16;
      const int g    = (l == NLAYERS - 1) ? 4 : 8;
      const int mode = (l == 7) ? 0 : (l == 15) ? 1 : 2;
      flush_phase(tid, p0, zbuf, wskp, Abuf, bsk, skr, smem, l0, g, mode);
    }

    if (l < NLAYERS - 1) gridbar(bar, (unsigned)(NBLK * (l + 1)));
  }
}

// ---------------- generic 256x256 GEMM (last1 / last2) -------------------
__global__ __launch_bounds__(256, 4) void gemm256(
    const _Float16* __restrict__ Asrc, const _Float16* __restrict__ Bp,
    const float* __restrict__ bias, void* __restrict__ dst, int mode)
{
  __shared__ _Float16 smem[2 * 128 * 72];
  _Float16* As = smem;
  _Float16* Bs = smem + 128 * 72;
  const int tid = threadIdx.x;
  const int lane = tid & 63, w = tid >> 6;
  const int wx = w & 1, wy = w >> 1;
  const int l15 = lane & 15, quad = lane >> 4;
  const int p0 = blockIdx.x * 128;
  const int n0 = blockIdx.y * 128;
  const int r = tid >> 1, halfo = (tid & 1) * 32;

  f32x4 acc[4][4];
#pragma unroll
  for (int mi = 0; mi < 4; ++mi)
#pragma unroll
    for (int ni = 0; ni < 4; ++ni) { f32x4 z = {0.f, 0.f, 0.f, 0.f}; acc[mi][ni] = z; }

  for (int c4 = 0; c4 < 4; ++c4) {
    int k0g = c4 * 64;
    const uint4* sa = (const uint4*)(Asrc + ((size_t)(p0 + r) * 256 + k0g + halfo));
#pragma unroll
    for (int jj = 0; jj < 4; ++jj) *(uint4*)&As[r * 72 + halfo + 8 * jj] = sa[jj];
    const uint4* sb = (const uint4*)(Bp + ((size_t)(n0 + r) * 256 + k0g + halfo));
#pragma unroll
    for (int jj = 0; jj < 4; ++jj) *(uint4*)&Bs[r * 72 + halfo + 8 * jj] = sb[jj];
    __syncthreads();
#pragma unroll
    for (int kc = 0; kc < 2; ++kc) {
      const int k0 = kc * 32 + quad * 8;
      half8 af[4], bfr[4];
#pragma unroll
      for (int mi = 0; mi < 4; ++mi)
        af[mi] = *(const half8*)&As[(64 * wy + 16 * mi + l15) * 72 + k0];
#pragma unroll
      for (int ni = 0; ni < 4; ++ni)
        bfr[ni] = *(const half8*)&Bs[(64 * wx + 16 * ni + l15) * 72 + k0];
#pragma unroll
      for (int mi = 0; mi < 4; ++mi)
#pragma unroll
        for (int ni = 0; ni < 4; ++ni)
          acc[mi][ni] = mfma16(af[mi], bfr[ni], acc[mi][ni]);
    }
    __syncthreads();
  }
  if (mode == 0) {
#pragma unroll
    for (int mi = 0; mi < 4; ++mi)
#pragma unroll
      for (int ni = 0; ni < 4; ++ni) {
        int col = n0 + 64 * wx + 16 * ni + l15;
        int rowb = 64 * wy + 16 * mi + quad * 4;
        float bv = bias[col];
        _Float16* o = (_Float16*)dst;
#pragma unroll
        for (int reg = 0; reg < 4; ++reg) {
          float v = acc[mi][ni][reg] + bv;
          o[((size_t)(p0 + rowb + reg)) * 256 + col] = (_Float16)(v > 0.f ? v : 0.f);
        }
      }
  } else {
    // transposed coalesced store: two passes of 64 columns through LDS
    float* Ts = (float*)smem;       // 64 x 132 floats = 33792 B
    const int b = p0 >> 14, t0g = p0 & (T_LEN - 1);
    for (int pass = 0; pass < 2; ++pass) {
      if (wx == pass) {
#pragma unroll
        for (int mi = 0; mi < 4; ++mi)
#pragma unroll
          for (int ni = 0; ni < 4; ++ni) {
            int col_l = 16 * ni + l15;
            float bv = bias[n0 + 64 * pass + col_l];
            int tl = 64 * wy + 16 * mi + quad * 4;
#pragma unroll
            for (int reg = 0; reg < 4; ++reg)
              Ts[col_l * 132 + tl + reg] = acc[mi][ni][reg] + bv;
          }
      }
      __syncthreads();
      {
        int col_l = tid >> 2;
        int tq = (tid & 3) * 32;
        float* o = (float*)dst + ((size_t)b * 256 + n0 + 64 * pass + col_l) * T_LEN + t0g + tq;
#pragma unroll
        for (int j = 0; j < 8; ++j)
          *(float4*)(o + 4 * j) = *(const float4*)&Ts[col_l * 132 + tq + 4 * j];
      }
      __syncthreads();
    }
  }
}

extern "C" void kernel_launch(void* const* d_in, const int* in_sizes, int n_in,
                              void* d_out, int out_size, void* d_ws, size_t ws_size,
                              hipStream_t stream)
{
  const float* x     = (const float*)d_in[0];
  const float* c     = (const float*)d_in[1];
  const float* Wf    = (const float*)d_in[2];
  const float* bf    = (const float*)d_in[3];
  const float* Wdil  = (const float*)d_in[4];
  const float* bdil  = (const float*)d_in[5];
  const float* Wc    = (const float*)d_in[6];
  const float* bc    = (const float*)d_in[7];
  const float* Wskip = (const float*)d_in[8];
  const float* bskip = (const float*)d_in[9];
  const float* Wout  = (const float*)d_in[10];
  const float* bout  = (const float*)d_in[11];
  const float* Wl1   = (const float*)d_in[12];
  const float* bl1   = (const float*)d_in[13];
  const float* Wl2   = (const float*)d_in[14];
  const float* bl2   = (const float*)d_in[15];

  char* base = (char*)d_ws;
  _Float16* zbuf = (_Float16*)base;
  _Float16* xt   = zbuf;
  _Float16* skr  = zbuf + (size_t)4 * BT * 64;
  _Float16* y1   = zbuf;
  _Float16* ctp  = (_Float16*)(base + 67108864);   // BT*96 f16 = 12.58 MB
  _Float16* hA   = (_Float16*)(base + 79691776);   // BT*64 f16 = 8.39 MB
  _Float16* hB   = (_Float16*)(base + 88080384);
  _Float16* wdp  = (_Float16*)(base + 96468992);
  _Float16* wcp  = wdp  + (size_t)20 * 3 * 128 * 64;
  _Float16* wop  = wcp  + (size_t)20 * 128 * 96;
  _Float16* wskp = wop  + (size_t)20 * 64 * 64;
  _Float16* wfp  = wskp + (size_t)256 * 1280;
  _Float16* wl1p = wfp  + (size_t)64 * 512;
  _Float16* wl2p = wl1p + (size_t)256 * 256;
  float*    bde  = (float*)(wl2p + (size_t)256 * 256);
  float*    bsk  = bde + 20 * 128;
  unsigned* bar  = (unsigned*)(bsk + 256);
  _Float16* Abuf = (_Float16*)d_out;               // f16 skip accumulator

  prep_pack<<<2048, 256, 0, stream>>>(Wf, Wdil, Wc, Wskip, Wout, Wl1, Wl2,
                                      bdil, bc, bskip,
                                      wdp, wcp, wop, wskp, wfp, wl1p, wl2p,
                                      bde, bsk, bar);
  tr_kernel<<<NB * (T_LEN / 32) * 8, 256, 0, stream>>>(x, xt, 256, 256, 8);
  tr_kernel<<<NB * (T_LEN / 32) * 3, 256, 0, stream>>>(c, ctp, 80, 96, 3);
  first_conv<<<512, 256, 0, stream>>>(xt, wfp, bf, hA);

  wavenet_layers<<<NBLK, 512, 0, stream>>>(hA, hB, ctp, wdp, wcp, wop, wskp,
                                           bde, bout, zbuf, Abuf, bsk, skr, bar);

  gemm256<<<dim3(512, 2), 256, 0, stream>>>(skr, wl1p, bl1, (void*)y1, 0);
  gemm256<<<dim3(512, 2), 256, 0, stream>>>(y1, wl2p, bl2, d_out, 1);
}

// Round 5
// 955.587 us; speedup vs baseline: 2.9621x; 1.2035x over previous
//
#include <hip/hip_runtime.h>
#include <math.h>

// WaveNet (4,256,16384), 20 layers. Round 9: REVERT to the multi-kernel
// round-0 structure (fused persistent-kernel path measured 45us/layer floor:
// sc0sc1 h traffic at 1.4TB/s + software-barrier straggler cost beat it).
// On top of round-0 (640us):
//  - T14 async-STAGE prefetch (depth 1) in layer_kernel / flush_kernel /
//    gemm256: issue stage s+1 global loads into regs right after stage s's
//    LDS write, hiding L2/MALL latency under sync+MFMA+sync.
//  - layer epilogue reads h[t] from LDS (Cs, dual-written at stage s==2)
//    instead of re-reading 8.4 MB/layer from global; h stores coalesced
//    32B/thread via Cs.
//  - layer 19 skips the dead phase-4 (h output unused).

#define T_LEN   16384
#define NB      4
#define BT      (NB * T_LEN)     // 65536
#define NLAYERS 20
#define SQH     0.70710678118654752440f

typedef _Float16 half8 __attribute__((ext_vector_type(8)));
typedef _Float16 half4 __attribute__((ext_vector_type(4)));
typedef float f32x4 __attribute__((ext_vector_type(4)));

__device__ inline f32x4 mfma16(half8 a, half8 b, f32x4 c) {
  return __builtin_amdgcn_mfma_f32_16x16x32_f16(a, b, c, 0, 0, 0);
}

// ---------------- weight packing (f16) ----------------
__global__ __launch_bounds__(256) void prep_pack(
    const float* __restrict__ Wf, const float* __restrict__ Wdil,
    const float* __restrict__ Wc, const float* __restrict__ Wskip,
    const float* __restrict__ Wout, const float* __restrict__ Wl1,
    const float* __restrict__ Wl2, const float* __restrict__ bdil,
    const float* __restrict__ bc, const float* __restrict__ bskip,
    _Float16* __restrict__ wdp, _Float16* __restrict__ wcp,
    _Float16* __restrict__ wop, _Float16* __restrict__ wskp,
    _Float16* __restrict__ wfp, _Float16* __restrict__ wl1p,
    _Float16* __restrict__ wl2p, float* __restrict__ bde,
    float* __restrict__ bsk)
{
  const float Q = 0.70710678118654752440f;
  const int WDP_E = 20 * 3 * 128 * 64;   // [l][tau][n][kc]
  const int WCP_E = 20 * 128 * 96;       // [l][n][kc pad96]
  const int WOP_E = 20 * 64 * 64;        // [l][n][kc]
  const int WSK_E = 256 * 1280;          // [n][l*64+kc], scale q^(1-l)
  const int WFP_E = 64 * 512;            // [n][tau*256+ci]
  const int WL_E  = 256 * 256;
  const int BDE_E = 20 * 128;
  const int BSK_E = 256;
  const int TOTAL = WDP_E + WCP_E + WOP_E + WSK_E + WFP_E + 2 * WL_E + BDE_E + BSK_E;
  for (int i = blockIdx.x * blockDim.x + threadIdx.x; i < TOTAL;
       i += gridDim.x * blockDim.x) {
    int j = i;
    if (j < WDP_E) {
      int l = j / (3 * 128 * 64); int r2 = j % (3 * 128 * 64);
      int tau = r2 / (128 * 64);  int r3 = r2 % (128 * 64);
      int n = r3 >> 6; int kc = r3 & 63;
      wdp[j] = (_Float16)Wdil[((l * 128 + n) * 64 + kc) * 3 + tau];
      continue;
    }
    j -= WDP_E;
    if (j < WCP_E) {
      int l = j / (128 * 96); int r2 = j % (128 * 96);
      int n = r2 / 96; int kc = r2 % 96;
      wcp[j] = (_Float16)(kc < 80 ? Wc[(l * 128 + n) * 80 + kc] : 0.f);
      continue;
    }
    j -= WCP_E;
    if (j < WOP_E) {
      int l = j >> 12; int r2 = j & 4095;
      int n = r2 >> 6; int kc = r2 & 63;
      wop[j] = (_Float16)Wout[(l * 64 + n) * 64 + kc];
      continue;
    }
    j -= WOP_E;
    if (j < WSK_E) {
      int n = j / 1280; int k = j % 1280;
      int l = k >> 6; int kc = k & 63;
      float f = (l == 0) ? 1.f : powf(Q, (float)(1 - l));
      wskp[j] = (_Float16)(Wskip[(l * 256 + n) * 64 + kc] * f);
      continue;
    }
    j -= WSK_E;
    if (j < WFP_E) {
      int n = j >> 9; int k = j & 511;
      int tau = k >> 8; int ci = k & 255;
      wfp[j] = (_Float16)Wf[(n * 256 + ci) * 2 + tau];
      continue;
    }
    j -= WFP_E;
    if (j < WL_E) { wl1p[j] = (_Float16)Wl1[j]; continue; }
    j -= WL_E;
    if (j < WL_E) { wl2p[j] = (_Float16)Wl2[j]; continue; }
    j -= WL_E;
    if (j < BDE_E) { bde[j] = bdil[j] + bc[j]; continue; }
    j -= BDE_E;
    {
      int n = j;
      float s = 0.f;
      for (int l = 0; l < NLAYERS; ++l) {
        float w = powf(Q, (float)(l == 0 ? 19 : 20 - l));
        s += bskip[l * 256 + n] * w;
      }
      bsk[n] = s;
    }
  }
}

// ---------------- transpose (B,C,T) f32 -> (BT,Cpad) f16 ----------------
__global__ __launch_bounds__(256) void tr_kernel(
    const float* __restrict__ src, _Float16* __restrict__ dst, int C, int Cpad, int CB)
{
  __shared__ float tile[32 * 33];
  int bid = blockIdx.x;
  int cb = bid % CB;
  int tb = (bid / CB) % (T_LEN / 32);
  int bb = bid / (CB * (T_LEN / 32));
  int t0 = tb * 32, ch0 = cb * 32;
  int tl = threadIdx.x & 31, cl = threadIdx.x >> 5;
#pragma unroll
  for (int i = 0; i < 4; ++i) {
    int ch = cl + 8 * i;
    float v = (ch0 + ch < C) ? src[((size_t)bb * C + ch0 + ch) * T_LEN + t0 + tl] : 0.f;
    tile[ch * 33 + tl] = v;
  }
  __syncthreads();
  int t = threadIdx.x >> 3;
  int c4 = (threadIdx.x & 7) * 4;
  half4 hv = {(_Float16)tile[(c4 + 0) * 33 + t], (_Float16)tile[(c4 + 1) * 33 + t],
              (_Float16)tile[(c4 + 2) * 33 + t], (_Float16)tile[(c4 + 3) * 33 + t]};
  *(half4*)&dst[((size_t)bb * T_LEN + t0 + t) * Cpad + ch0 + c4] = hv;
}

// ---------------- first conv: h0 = tanh(Wf*[x(t-1);x(t)] + bf), f16 out ----
__global__ __launch_bounds__(256, 4) void first_conv(
    const _Float16* __restrict__ xt, const _Float16* __restrict__ wfp,
    const float* __restrict__ bf, _Float16* __restrict__ h0)
{
  __shared__ _Float16 As[128 * 72];
  __shared__ _Float16 Bs[64 * 72];
  const int tid = threadIdx.x;
  const int lane = tid & 63, w = tid >> 6;
  const int wx = w & 1, wy = w >> 1;
  const int l15 = lane & 15, quad = lane >> 4;
  const int p0 = blockIdx.x * 128;
  const int b = p0 >> 14, t0 = p0 & (T_LEN - 1);
  const int r = tid >> 1, halfo = (tid & 1) * 32;

  f32x4 acc[4][2];
#pragma unroll
  for (int mi = 0; mi < 4; ++mi)
#pragma unroll
    for (int ni = 0; ni < 2; ++ni) { f32x4 z = {0.f, 0.f, 0.f, 0.f}; acc[mi][ni] = z; }

  for (int s = 0; s < 8; ++s) {
    int tau = s >> 2, ci0 = (s & 3) * 64;
    int ts = t0 + r - 1 + tau;
    if (ts >= 0) {
      const uint4* src = (const uint4*)(xt + ((size_t)(b * T_LEN + ts) * 256 + ci0 + halfo));
#pragma unroll
      for (int j = 0; j < 4; ++j) *(uint4*)&As[r * 72 + halfo + 8 * j] = src[j];
    } else {
      uint4 z = {0, 0, 0, 0};
#pragma unroll
      for (int j = 0; j < 4; ++j) *(uint4*)&As[r * 72 + halfo + 8 * j] = z;
    }
    if (tid < 128) {
      const uint4* s4 = (const uint4*)(wfp + ((size_t)r * 512 + tau * 256 + ci0 + halfo));
#pragma unroll
      for (int j = 0; j < 4; ++j) *(uint4*)&Bs[r * 72 + halfo + 8 * j] = s4[j];
    }
    __syncthreads();
#pragma unroll
    for (int kc = 0; kc < 2; ++kc) {
      const int k0 = kc * 32 + quad * 8;
      half8 af[4], bfr[2];
#pragma unroll
      for (int mi = 0; mi < 4; ++mi)
        af[mi] = *(const half8*)&As[(64 * wy + 16 * mi + l15) * 72 + k0];
#pragma unroll
      for (int ni = 0; ni < 2; ++ni)
        bfr[ni] = *(const half8*)&Bs[(32 * wx + 16 * ni + l15) * 72 + k0];
#pragma unroll
      for (int mi = 0; mi < 4; ++mi)
#pragma unroll
        for (int ni = 0; ni < 2; ++ni)
          acc[mi][ni] = mfma16(af[mi], bfr[ni], acc[mi][ni]);
    }
    __syncthreads();
  }
#pragma unroll
  for (int mi = 0; mi < 4; ++mi)
#pragma unroll
    for (int ni = 0; ni < 2; ++ni) {
      int col = 32 * wx + 16 * ni + l15;
      int rowb = 64 * wy + 16 * mi + quad * 4;
      float bo = bf[col];
      size_t base = ((size_t)p0 + rowb) * 64 + col;
#pragma unroll
      for (int reg = 0; reg < 4; ++reg) {
        float v = acc[mi][ni][reg] + bo;
        float e = __expf(2.f * v);
        h0[base + (size_t)64 * reg] = (_Float16)(1.f - 2.f * __builtin_amdgcn_rcpf(e + 1.f));
      }
    }
}

// ---------------- one residual layer: 512 threads, 8 waves (2x4) -----------
// T14 depth-1 prefetch: stage s+1's global loads issue right after stage s's
// LDS write; latency hides under sync+MFMA+sync.
__global__ __launch_bounds__(512, 4) void layer_kernel(
    const _Float16* __restrict__ hprev, _Float16* __restrict__ hnext,
    const _Float16* __restrict__ ctp,
    const _Float16* __restrict__ wdp_l, const _Float16* __restrict__ wcp_l,
    const _Float16* __restrict__ wop_l,
    const float* __restrict__ bde_l, const float* __restrict__ bout_l,
    _Float16* __restrict__ zslot, int d, int last)
{
  __shared__ _Float16 As[128 * 72];
  __shared__ _Float16 Bs[128 * 72];
  __shared__ _Float16 Cs[128 * 72];   // own h[t] tile for the epilogue
  __shared__ float bde_s[128];

  const int tid = threadIdx.x;
  const int lane = tid & 63, w = tid >> 6;        // 8 waves
  const int wx = w & 1, wy = w >> 1;              // 2 (N) x 4 (M)
  const int l15 = lane & 15, quad = lane >> 4;
  const int p0 = blockIdx.x * 128;
  const int b = p0 >> 14, t0 = p0 & (T_LEN - 1);
  const int r2 = tid >> 2, qo = (tid & 3) * 16;   // staging: row, 16-elem chunk
  const int o8 = (tid & 3) * 8;                   // K=32 stage chunk

  if (tid < 128) bde_s[tid] = bde_l[tid];

  f32x4 acc[2][4];
#pragma unroll
  for (int mi = 0; mi < 2; ++mi)
#pragma unroll
    for (int ni = 0; ni < 4; ++ni) { f32x4 z = {0.f, 0.f, 0.f, 0.f}; acc[mi][ni] = z; }

  // stage payload regs
  uint4 pa0, pa1, pb0, pb1;
  bool paz = false;

  auto issue = [&](int s) {
    if (s < 3) {
      int ts = t0 + r2 - (2 - s) * d;
      paz = (ts < 0);
      int tsc = paz ? 0 : ts;
      const uint4* src = (const uint4*)(hprev + ((size_t)(b * T_LEN + tsc) * 64 + qo));
      pa0 = src[0]; pa1 = src[1];
      const uint4* sb = (const uint4*)(wdp_l + ((size_t)s * 8192 + r2 * 64 + qo));
      pb0 = sb[0]; pb1 = sb[1];
    } else if (s == 3) {
      paz = false;
      const uint4* sa = (const uint4*)(ctp + ((size_t)(p0 + r2) * 96 + qo));
      pa0 = sa[0]; pa1 = sa[1];
      const uint4* sb = (const uint4*)(wcp_l + ((size_t)r2 * 96 + qo));
      pb0 = sb[0]; pb1 = sb[1];
    } else {  // s == 4: K=32 tail of cond (16B per thread)
      paz = false;
      pa0 = *(const uint4*)(ctp + ((size_t)(p0 + r2) * 96 + 64 + o8));
      pb0 = *(const uint4*)(wcp_l + ((size_t)r2 * 96 + 64 + o8));
    }
  };

  issue(0);
#pragma unroll 1
  for (int s = 0; s < 5; ++s) {
    // commit stage s payload to LDS
    if (s < 3) {
      if (!paz) {
        *(uint4*)&As[r2 * 72 + qo] = pa0;
        *(uint4*)&As[r2 * 72 + qo + 8] = pa1;
      } else {
        uint4 z4 = {0, 0, 0, 0};
        *(uint4*)&As[r2 * 72 + qo] = z4;
        *(uint4*)&As[r2 * 72 + qo + 8] = z4;
      }
      if (s == 2) {  // keep own h[t] tile for the residual epilogue
        if (!paz) {
          *(uint4*)&Cs[r2 * 72 + qo] = pa0;
          *(uint4*)&Cs[r2 * 72 + qo + 8] = pa1;
        } else {
          uint4 z4 = {0, 0, 0, 0};
          *(uint4*)&Cs[r2 * 72 + qo] = z4;
          *(uint4*)&Cs[r2 * 72 + qo + 8] = z4;
        }
      }
      *(uint4*)&Bs[r2 * 72 + qo] = pb0;
      *(uint4*)&Bs[r2 * 72 + qo + 8] = pb1;
    } else if (s == 3) {
      *(uint4*)&As[r2 * 72 + qo] = pa0;
      *(uint4*)&As[r2 * 72 + qo + 8] = pa1;
      *(uint4*)&Bs[r2 * 72 + qo] = pb0;
      *(uint4*)&Bs[r2 * 72 + qo + 8] = pb1;
    } else {
      *(uint4*)&As[r2 * 72 + o8] = pa0;
      *(uint4*)&Bs[r2 * 72 + o8] = pb0;
    }
    // prefetch stage s+1 (overlaps sync + MFMA + sync below)
    if (s < 4) issue(s + 1);
    __syncthreads();
    const int nkc = (s == 4) ? 1 : 2;
    for (int kc = 0; kc < nkc; ++kc) {
      const int k0 = kc * 32 + quad * 8;
      half8 af[2], bfr[4];
#pragma unroll
      for (int mi = 0; mi < 2; ++mi)
        af[mi] = *(const half8*)&As[(32 * wy + 16 * mi + l15) * 72 + k0];
#pragma unroll
      for (int ni = 0; ni < 4; ++ni) {
        int ncol = 32 * wx + 16 * (ni & 1) + 64 * (ni >> 1);  // ch and ch+64
        bfr[ni] = *(const half8*)&Bs[(ncol + l15) * 72 + k0];
      }
#pragma unroll
      for (int mi = 0; mi < 2; ++mi)
#pragma unroll
        for (int ni = 0; ni < 4; ++ni)
          acc[mi][ni] = mfma16(af[mi], bfr[ni], acc[mi][ni]);
    }
    __syncthreads();
  }

  // gate: z = tanh(y[ch]) * sigmoid(y[ch+64]) -> Zs (aliases As)
#pragma unroll
  for (int mi = 0; mi < 2; ++mi)
#pragma unroll
    for (int ni2 = 0; ni2 < 2; ++ni2) {
      int colb = 32 * wx + 16 * ni2 + l15;
      float ba = bde_s[colb], bb = bde_s[colb + 64];
#pragma unroll
      for (int reg = 0; reg < 4; ++reg) {
        float av = acc[mi][ni2][reg] + ba;
        float gv = acc[mi][ni2 + 2][reg] + bb;
        float ea = __expf(2.f * av);
        float th = 1.f - 2.f * __builtin_amdgcn_rcpf(ea + 1.f);
        float sg = __builtin_amdgcn_rcpf(1.f + __expf(-gv));
        As[(32 * wy + 16 * mi + quad * 4 + reg) * 72 + colb] = (_Float16)(th * sg);
      }
    }

  // stage W_out (64x64) into Bs (skip for the dead h of the last layer)
  if (!last && tid < 256) {
    int row = tid >> 2;
    const uint4* sb = (const uint4*)(wop_l + ((size_t)row * 64 + qo));
    *(uint4*)&Bs[row * 72 + qo] = sb[0];
    *(uint4*)&Bs[row * 72 + qo + 8] = sb[1];
  }
  __syncthreads();

  // z -> global ring slot
  {
    uint4 v0 = *(const uint4*)&As[r2 * 72 + qo];
    uint4 v1 = *(const uint4*)&As[r2 * 72 + qo + 8];
    uint4* dst = (uint4*)(zslot + ((size_t)(p0 + r2) * 64 + qo));
    dst[0] = v0; dst[1] = v1;
  }

  if (last) return;

  // phase 4: h_out = (Wout*z + b_out + h_in) * SQH   (h_in from Cs/LDS)
  f32x4 a4[2][2];
#pragma unroll
  for (int mi = 0; mi < 2; ++mi)
#pragma unroll
    for (int ni = 0; ni < 2; ++ni) { f32x4 z = {0.f, 0.f, 0.f, 0.f}; a4[mi][ni] = z; }
#pragma unroll
  for (int kc = 0; kc < 2; ++kc) {
    const int k0 = kc * 32 + quad * 8;
    half8 af[2], bfr[2];
#pragma unroll
    for (int mi = 0; mi < 2; ++mi)
      af[mi] = *(const half8*)&As[(32 * wy + 16 * mi + l15) * 72 + k0];
#pragma unroll
    for (int ni = 0; ni < 2; ++ni)
      bfr[ni] = *(const half8*)&Bs[(32 * wx + 16 * ni + l15) * 72 + k0];
#pragma unroll
    for (int mi = 0; mi < 2; ++mi)
#pragma unroll
      for (int ni = 0; ni < 2; ++ni)
        a4[mi][ni] = mfma16(af[mi], bfr[ni], a4[mi][ni]);
  }
#pragma unroll
  for (int mi = 0; mi < 2; ++mi)
#pragma unroll
    for (int ni = 0; ni < 2; ++ni) {
      int col = 32 * wx + 16 * ni + l15;
      int rowb = 32 * wy + 16 * mi + quad * 4;
      float bo = bout_l[col];
#pragma unroll
      for (int reg = 0; reg < 4; ++reg) {
        float hv = (float)Cs[(rowb + reg) * 72 + col];
        Cs[(rowb + reg) * 72 + col] = (_Float16)((a4[mi][ni][reg] + bo + hv) * SQH);
      }
    }
  __syncthreads();
  {
    uint4 v0 = *(const uint4*)&Cs[r2 * 72 + qo];
    uint4 v1 = *(const uint4*)&Cs[r2 * 72 + qo + 8];
    uint4* dst = (uint4*)(hnext + ((size_t)(p0 + r2) * 64 + qo));
    dst[0] = v0; dst[1] = v1;
  }
}

// ---------------- deferred skip flush ------------------------------------
// mode 0: Abuf = acc (f16)   mode 1: Abuf += acc (f16)
// mode 2: skr = relu((acc + Abuf) * q^19 + bsk) as f16 (final, fused epilogue)
__global__ __launch_bounds__(256, 4) void flush_kernel(
    const _Float16* __restrict__ zbuf, const _Float16* __restrict__ wskp,
    _Float16* __restrict__ Abuf, const float* __restrict__ bsk,
    _Float16* __restrict__ skr, int l0, int g, int mode)
{
  __shared__ _Float16 As[128 * 72];
  __shared__ _Float16 Bs[128 * 72];
  const int tid = threadIdx.x;
  const int lane = tid & 63, w = tid >> 6;
  const int wx = w & 1, wy = w >> 1;
  const int l15 = lane & 15, quad = lane >> 4;
  const int p0 = blockIdx.x * 128;
  const int n0 = blockIdx.y * 128;
  const int r = tid >> 1, halfo = (tid & 1) * 32;

  f32x4 acc[4][4];
#pragma unroll
  for (int mi = 0; mi < 4; ++mi)
#pragma unroll
    for (int ni = 0; ni < 4; ++ni) { f32x4 z = {0.f, 0.f, 0.f, 0.f}; acc[mi][ni] = z; }

  uint4 pa[4], pb[4];
  auto issuef = [&](int j) {
    const int lj = l0 + j;
    const _Float16* zsl = zbuf + (size_t)(lj & 7) * ((size_t)BT * 64);
    const uint4* sa = (const uint4*)(zsl + ((size_t)(p0 + r) * 64 + halfo));
#pragma unroll
    for (int jj = 0; jj < 4; ++jj) pa[jj] = sa[jj];
    const uint4* sb = (const uint4*)(wskp + ((size_t)(n0 + r) * 1280 + lj * 64 + halfo));
#pragma unroll
    for (int jj = 0; jj < 4; ++jj) pb[jj] = sb[jj];
  };

  issuef(0);
#pragma unroll 1
  for (int j = 0; j < g; ++j) {
#pragma unroll
    for (int jj = 0; jj < 4; ++jj) *(uint4*)&As[r * 72 + halfo + 8 * jj] = pa[jj];
#pragma unroll
    for (int jj = 0; jj < 4; ++jj) *(uint4*)&Bs[r * 72 + halfo + 8 * jj] = pb[jj];
    if (j + 1 < g) issuef(j + 1);
    __syncthreads();
#pragma unroll
    for (int kc = 0; kc < 2; ++kc) {
      const int k0 = kc * 32 + quad * 8;
      half8 af[4], bfr[4];
#pragma unroll
      for (int mi = 0; mi < 4; ++mi)
        af[mi] = *(const half8*)&As[(64 * wy + 16 * mi + l15) * 72 + k0];
#pragma unroll
      for (int ni = 0; ni < 4; ++ni)
        bfr[ni] = *(const half8*)&Bs[(64 * wx + 16 * ni + l15) * 72 + k0];
#pragma unroll
      for (int mi = 0; mi < 4; ++mi)
#pragma unroll
        for (int ni = 0; ni < 4; ++ni)
          acc[mi][ni] = mfma16(af[mi], bfr[ni], acc[mi][ni]);
    }
    __syncthreads();
  }
  const float Q19 = 0.0013810679320049757f;  // sqrt(0.5)^19
#pragma unroll
  for (int mi = 0; mi < 4; ++mi)
#pragma unroll
    for (int ni = 0; ni < 4; ++ni) {
      int col = n0 + 64 * wx + 16 * ni + l15;
      int rowb = 64 * wy + 16 * mi + quad * 4;
      size_t base = ((size_t)p0 + rowb) * 256 + col;
      if (mode == 2) {
        float bb = bsk[col];
#pragma unroll
        for (int reg = 0; reg < 4; ++reg) {
          float v = (acc[mi][ni][reg] + (float)Abuf[base + (size_t)256 * reg]) * Q19 + bb;
          skr[base + (size_t)256 * reg] = (_Float16)(v > 0.f ? v : 0.f);
        }
      } else if (mode == 1) {
#pragma unroll
        for (int reg = 0; reg < 4; ++reg) {
          size_t a = base + (size_t)256 * reg;
          Abuf[a] = (_Float16)((float)Abuf[a] + acc[mi][ni][reg]);
        }
      } else {
#pragma unroll
        for (int reg = 0; reg < 4; ++reg)
          Abuf[base + (size_t)256 * reg] = (_Float16)acc[mi][ni][reg];
      }
    }
}

// ---------------- generic 256x256 GEMM (last1 / last2) -------------------
// mode 0: dst f16 row-major (BT,256), relu.  mode 1: dst f32 (B,256,T), +bias,
// coalesced via LDS transpose.
__global__ __launch_bounds__(256, 4) void gemm256(
    const _Float16* __restrict__ Asrc, const _Float16* __restrict__ Bp,
    const float* __restrict__ bias, void* __restrict__ dst, int mode)
{
  __shared__ _Float16 smem[2 * 128 * 72];
  _Float16* As = smem;
  _Float16* Bs = smem + 128 * 72;
  const int tid = threadIdx.x;
  const int lane = tid & 63, w = tid >> 6;
  const int wx = w & 1, wy = w >> 1;
  const int l15 = lane & 15, quad = lane >> 4;
  const int p0 = blockIdx.x * 128;
  const int n0 = blockIdx.y * 128;
  const int r = tid >> 1, halfo = (tid & 1) * 32;

  f32x4 acc[4][4];
#pragma unroll
  for (int mi = 0; mi < 4; ++mi)
#pragma unroll
    for (int ni = 0; ni < 4; ++ni) { f32x4 z = {0.f, 0.f, 0.f, 0.f}; acc[mi][ni] = z; }

  uint4 pa[4], pb[4];
  auto issueg = [&](int c4) {
    const int k0g = c4 * 64;
    const uint4* sa = (const uint4*)(Asrc + ((size_t)(p0 + r) * 256 + k0g + halfo));
#pragma unroll
    for (int jj = 0; jj < 4; ++jj) pa[jj] = sa[jj];
    const uint4* sb = (const uint4*)(Bp + ((size_t)(n0 + r) * 256 + k0g + halfo));
#pragma unroll
    for (int jj = 0; jj < 4; ++jj) pb[jj] = sb[jj];
  };

  issueg(0);
#pragma unroll 1
  for (int c4 = 0; c4 < 4; ++c4) {
#pragma unroll
    for (int jj = 0; jj < 4; ++jj) *(uint4*)&As[r * 72 + halfo + 8 * jj] = pa[jj];
#pragma unroll
    for (int jj = 0; jj < 4; ++jj) *(uint4*)&Bs[r * 72 + halfo + 8 * jj] = pb[jj];
    if (c4 < 3) issueg(c4 + 1);
    __syncthreads();
#pragma unroll
    for (int kc = 0; kc < 2; ++kc) {
      const int k0 = kc * 32 + quad * 8;
      half8 af[4], bfr[4];
#pragma unroll
      for (int mi = 0; mi < 4; ++mi)
        af[mi] = *(const half8*)&As[(64 * wy + 16 * mi + l15) * 72 + k0];
#pragma unroll
      for (int ni = 0; ni < 4; ++ni)
        bfr[ni] = *(const half8*)&Bs[(64 * wx + 16 * ni + l15) * 72 + k0];
#pragma unroll
      for (int mi = 0; mi < 4; ++mi)
#pragma unroll
        for (int ni = 0; ni < 4; ++ni)
          acc[mi][ni] = mfma16(af[mi], bfr[ni], acc[mi][ni]);
    }
    __syncthreads();
  }
  if (mode == 0) {
#pragma unroll
    for (int mi = 0; mi < 4; ++mi)
#pragma unroll
      for (int ni = 0; ni < 4; ++ni) {
        int col = n0 + 64 * wx + 16 * ni + l15;
        int rowb = 64 * wy + 16 * mi + quad * 4;
        float bv = bias[col];
        _Float16* o = (_Float16*)dst;
#pragma unroll
        for (int reg = 0; reg < 4; ++reg) {
          float v = acc[mi][ni][reg] + bv;
          o[((size_t)(p0 + rowb + reg)) * 256 + col] = (_Float16)(v > 0.f ? v : 0.f);
        }
      }
  } else {
    // transposed coalesced store: two passes of 64 columns through LDS
    float* Ts = (float*)smem;       // 64 x 132 floats = 33792 B
    const int b = p0 >> 14, t0g = p0 & (T_LEN - 1);
    for (int pass = 0; pass < 2; ++pass) {
      if (wx == pass) {
#pragma unroll
        for (int mi = 0; mi < 4; ++mi)
#pragma unroll
          for (int ni = 0; ni < 4; ++ni) {
            int col_l = 16 * ni + l15;
            float bv = bias[n0 + 64 * pass + col_l];
            int tl = 64 * wy + 16 * mi + quad * 4;
#pragma unroll
            for (int reg = 0; reg < 4; ++reg)
              Ts[col_l * 132 + tl + reg] = acc[mi][ni][reg] + bv;
          }
      }
      __syncthreads();
      {
        int col_l = tid >> 2;
        int tq = (tid & 3) * 32;
        float* o = (float*)dst + ((size_t)b * 256 + n0 + 64 * pass + col_l) * T_LEN + t0g + tq;
#pragma unroll
        for (int j = 0; j < 8; ++j)
          *(float4*)(o + 4 * j) = *(const float4*)&Ts[col_l * 132 + tq + 4 * j];
      }
      __syncthreads();
    }
  }
}

extern "C" void kernel_launch(void* const* d_in, const int* in_sizes, int n_in,
                              void* d_out, int out_size, void* d_ws, size_t ws_size,
                              hipStream_t stream)
{
  const float* x     = (const float*)d_in[0];
  const float* c     = (const float*)d_in[1];
  const float* Wf    = (const float*)d_in[2];
  const float* bf    = (const float*)d_in[3];
  const float* Wdil  = (const float*)d_in[4];
  const float* bdil  = (const float*)d_in[5];
  const float* Wc    = (const float*)d_in[6];
  const float* bc    = (const float*)d_in[7];
  const float* Wskip = (const float*)d_in[8];
  const float* bskip = (const float*)d_in[9];
  const float* Wout  = (const float*)d_in[10];
  const float* bout  = (const float*)d_in[11];
  const float* Wl1   = (const float*)d_in[12];
  const float* bl1   = (const float*)d_in[13];
  const float* Wl2   = (const float*)d_in[14];
  const float* bl2   = (const float*)d_in[15];

  char* base = (char*)d_ws;
  // 8-slot z ring (64 MiB). Aliases: xt = slots 0-3 (consumed by first_conv
  // before layer 0 writes slot 0); skr = slots 4-7 (free after flush2);
  // y1 = slots 0-3 (free after flush3). Abuf (f16) lives in d_out, dead
  // before gemm256 #2 writes the final f32 output there.
  _Float16* zbuf = (_Float16*)base;
  _Float16* xt   = zbuf;
  _Float16* skr  = zbuf + (size_t)4 * BT * 64;
  _Float16* y1   = zbuf;
  _Float16* ctp  = (_Float16*)(base + 67108864);   // BT*96 f16 = 12.58 MB
  _Float16* hA   = (_Float16*)(base + 79691776);   // BT*64 f16 = 8.39 MB
  _Float16* hB   = (_Float16*)(base + 88080384);
  _Float16* wdp  = (_Float16*)(base + 96468992);
  _Float16* wcp  = wdp  + (size_t)20 * 3 * 128 * 64;
  _Float16* wop  = wcp  + (size_t)20 * 128 * 96;
  _Float16* wskp = wop  + (size_t)20 * 64 * 64;
  _Float16* wfp  = wskp + (size_t)256 * 1280;
  _Float16* wl1p = wfp  + (size_t)64 * 512;
  _Float16* wl2p = wl1p + (size_t)256 * 256;
  float*    bde  = (float*)(wl2p + (size_t)256 * 256);
  float*    bsk  = bde + 20 * 128;
  _Float16* Abuf = (_Float16*)d_out;               // f16 skip accumulator

  prep_pack<<<2048, 256, 0, stream>>>(Wf, Wdil, Wc, Wskip, Wout, Wl1, Wl2,
                                      bdil, bc, bskip,
                                      wdp, wcp, wop, wskp, wfp, wl1p, wl2p,
                                      bde, bsk);
  tr_kernel<<<NB * (T_LEN / 32) * 8, 256, 0, stream>>>(x, xt, 256, 256, 8);
  tr_kernel<<<NB * (T_LEN / 32) * 3, 256, 0, stream>>>(c, ctp, 80, 96, 3);
  first_conv<<<512, 256, 0, stream>>>(xt, wfp, bf, hA);

  const _Float16* hin = hA;
  _Float16* hout = hB;
  for (int l = 0; l < NLAYERS; ++l) {
    int d = 1 << (l % 10);
    layer_kernel<<<512, 512, 0, stream>>>(
        hin, hout, ctp,
        wdp + (size_t)l * 3 * 128 * 64, wcp + (size_t)l * 128 * 96,
        wop + (size_t)l * 64 * 64, bde + l * 128, bout + l * 64,
        zbuf + (size_t)(l & 7) * BT * 64, d, (l == NLAYERS - 1) ? 1 : 0);
    _Float16* tmp = (_Float16*)hin; hin = hout; hout = tmp;
    if (l == 7)  flush_kernel<<<dim3(512, 2), 256, 0, stream>>>(zbuf, wskp, Abuf, bsk, skr, 0, 8, 0);
    if (l == 15) flush_kernel<<<dim3(512, 2), 256, 0, stream>>>(zbuf, wskp, Abuf, bsk, skr, 8, 8, 1);
    if (l == 19) flush_kernel<<<dim3(512, 2), 256, 0, stream>>>(zbuf, wskp, Abuf, bsk, skr, 16, 4, 2);
  }
  gemm256<<<dim3(512, 2), 256, 0, stream>>>(skr, wl1p, bl1, (void*)y1, 0);
  gemm256<<<dim3(512, 2), 256, 0, stream>>>(y1, wl2p, bl2, d_out, 1);
}

// Round 6
// 720.942 us; speedup vs baseline: 3.9261x; 1.3255x over previous
//
#include <hip/hip_runtime.h>
#include <math.h>

// WaveNet (4,256,16384), 20 layers. Round 10. From round-5 post-mortem:
//  - flush/gemm reg-prefetch caused VGPR spill to scratch (~270MB HBM traffic,
//    flush 35->103us). REVERTED to direct global->LDS staging.
//  - flush_kernel is now 512-thread (one block computes both 128-col halves,
//    staging the z tile ONCE): z read 134->67MB. Structure identical to the
//    correctness-proven fused flush_phase of rounds 2-4.
//  - layer_kernel: LDS double-buffer (A0/A1/B0/B1, 74KB, 2 blocks/CU), ONE
//    barrier per K-stage: issue(s+1)->regs, barrier, MFMA(s), ds_write(s+1).
//    Load latency hides under MFMA; payload only 16 VGPRs (fits budget).
//    h[t] kept in A0 for the residual epilogue (no global re-read); gate
//    z->A1, Wout->B1; coalesced 32B h stores; layer 19 skips dead phase-4.

#define T_LEN   16384
#define NB      4
#define BT      (NB * T_LEN)     // 65536
#define NLAYERS 20
#define SQH     0.70710678118654752440f

typedef _Float16 half8 __attribute__((ext_vector_type(8)));
typedef _Float16 half4 __attribute__((ext_vector_type(4)));
typedef float f32x4 __attribute__((ext_vector_type(4)));

__device__ inline f32x4 mfma16(half8 a, half8 b, f32x4 c) {
  return __builtin_amdgcn_mfma_f32_16x16x32_f16(a, b, c, 0, 0, 0);
}

// ---------------- weight packing (f16) ----------------
__global__ __launch_bounds__(256) void prep_pack(
    const float* __restrict__ Wf, const float* __restrict__ Wdil,
    const float* __restrict__ Wc, const float* __restrict__ Wskip,
    const float* __restrict__ Wout, const float* __restrict__ Wl1,
    const float* __restrict__ Wl2, const float* __restrict__ bdil,
    const float* __restrict__ bc, const float* __restrict__ bskip,
    _Float16* __restrict__ wdp, _Float16* __restrict__ wcp,
    _Float16* __restrict__ wop, _Float16* __restrict__ wskp,
    _Float16* __restrict__ wfp, _Float16* __restrict__ wl1p,
    _Float16* __restrict__ wl2p, float* __restrict__ bde,
    float* __restrict__ bsk)
{
  const float Q = 0.70710678118654752440f;
  const int WDP_E = 20 * 3 * 128 * 64;   // [l][tau][n][kc]
  const int WCP_E = 20 * 128 * 96;       // [l][n][kc pad96]
  const int WOP_E = 20 * 64 * 64;        // [l][n][kc]
  const int WSK_E = 256 * 1280;          // [n][l*64+kc], scale q^(1-l)
  const int WFP_E = 64 * 512;            // [n][tau*256+ci]
  const int WL_E  = 256 * 256;
  const int BDE_E = 20 * 128;
  const int BSK_E = 256;
  const int TOTAL = WDP_E + WCP_E + WOP_E + WSK_E + WFP_E + 2 * WL_E + BDE_E + BSK_E;
  for (int i = blockIdx.x * blockDim.x + threadIdx.x; i < TOTAL;
       i += gridDim.x * blockDim.x) {
    int j = i;
    if (j < WDP_E) {
      int l = j / (3 * 128 * 64); int r2 = j % (3 * 128 * 64);
      int tau = r2 / (128 * 64);  int r3 = r2 % (128 * 64);
      int n = r3 >> 6; int kc = r3 & 63;
      wdp[j] = (_Float16)Wdil[((l * 128 + n) * 64 + kc) * 3 + tau];
      continue;
    }
    j -= WDP_E;
    if (j < WCP_E) {
      int l = j / (128 * 96); int r2 = j % (128 * 96);
      int n = r2 / 96; int kc = r2 % 96;
      wcp[j] = (_Float16)(kc < 80 ? Wc[(l * 128 + n) * 80 + kc] : 0.f);
      continue;
    }
    j -= WCP_E;
    if (j < WOP_E) {
      int l = j >> 12; int r2 = j & 4095;
      int n = r2 >> 6; int kc = r2 & 63;
      wop[j] = (_Float16)Wout[(l * 64 + n) * 64 + kc];
      continue;
    }
    j -= WOP_E;
    if (j < WSK_E) {
      int n = j / 1280; int k = j % 1280;
      int l = k >> 6; int kc = k & 63;
      float f = (l == 0) ? 1.f : powf(Q, (float)(1 - l));
      wskp[j] = (_Float16)(Wskip[(l * 256 + n) * 64 + kc] * f);
      continue;
    }
    j -= WSK_E;
    if (j < WFP_E) {
      int n = j >> 9; int k = j & 511;
      int tau = k >> 8; int ci = k & 255;
      wfp[j] = (_Float16)Wf[(n * 256 + ci) * 2 + tau];
      continue;
    }
    j -= WFP_E;
    if (j < WL_E) { wl1p[j] = (_Float16)Wl1[j]; continue; }
    j -= WL_E;
    if (j < WL_E) { wl2p[j] = (_Float16)Wl2[j]; continue; }
    j -= WL_E;
    if (j < BDE_E) { bde[j] = bdil[j] + bc[j]; continue; }
    j -= BDE_E;
    {
      int n = j;
      float s = 0.f;
      for (int l = 0; l < NLAYERS; ++l) {
        float w = powf(Q, (float)(l == 0 ? 19 : 20 - l));
        s += bskip[l * 256 + n] * w;
      }
      bsk[n] = s;
    }
  }
}

// ---------------- transpose (B,C,T) f32 -> (BT,Cpad) f16 ----------------
__global__ __launch_bounds__(256) void tr_kernel(
    const float* __restrict__ src, _Float16* __restrict__ dst, int C, int Cpad, int CB)
{
  __shared__ float tile[32 * 33];
  int bid = blockIdx.x;
  int cb = bid % CB;
  int tb = (bid / CB) % (T_LEN / 32);
  int bb = bid / (CB * (T_LEN / 32));
  int t0 = tb * 32, ch0 = cb * 32;
  int tl = threadIdx.x & 31, cl = threadIdx.x >> 5;
#pragma unroll
  for (int i = 0; i < 4; ++i) {
    int ch = cl + 8 * i;
    float v = (ch0 + ch < C) ? src[((size_t)bb * C + ch0 + ch) * T_LEN + t0 + tl] : 0.f;
    tile[ch * 33 + tl] = v;
  }
  __syncthreads();
  int t = threadIdx.x >> 3;
  int c4 = (threadIdx.x & 7) * 4;
  half4 hv = {(_Float16)tile[(c4 + 0) * 33 + t], (_Float16)tile[(c4 + 1) * 33 + t],
              (_Float16)tile[(c4 + 2) * 33 + t], (_Float16)tile[(c4 + 3) * 33 + t]};
  *(half4*)&dst[((size_t)bb * T_LEN + t0 + t) * Cpad + ch0 + c4] = hv;
}

// ---------------- first conv: h0 = tanh(Wf*[x(t-1);x(t)] + bf), f16 out ----
__global__ __launch_bounds__(256, 4) void first_conv(
    const _Float16* __restrict__ xt, const _Float16* __restrict__ wfp,
    const float* __restrict__ bf, _Float16* __restrict__ h0)
{
  __shared__ _Float16 As[128 * 72];
  __shared__ _Float16 Bs[64 * 72];
  const int tid = threadIdx.x;
  const int lane = tid & 63, w = tid >> 6;
  const int wx = w & 1, wy = w >> 1;
  const int l15 = lane & 15, quad = lane >> 4;
  const int p0 = blockIdx.x * 128;
  const int b = p0 >> 14, t0 = p0 & (T_LEN - 1);
  const int r = tid >> 1, halfo = (tid & 1) * 32;

  f32x4 acc[4][2];
#pragma unroll
  for (int mi = 0; mi < 4; ++mi)
#pragma unroll
    for (int ni = 0; ni < 2; ++ni) { f32x4 z = {0.f, 0.f, 0.f, 0.f}; acc[mi][ni] = z; }

  for (int s = 0; s < 8; ++s) {
    int tau = s >> 2, ci0 = (s & 3) * 64;
    int ts = t0 + r - 1 + tau;
    if (ts >= 0) {
      const uint4* src = (const uint4*)(xt + ((size_t)(b * T_LEN + ts) * 256 + ci0 + halfo));
#pragma unroll
      for (int j = 0; j < 4; ++j) *(uint4*)&As[r * 72 + halfo + 8 * j] = src[j];
    } else {
      uint4 z = {0, 0, 0, 0};
#pragma unroll
      for (int j = 0; j < 4; ++j) *(uint4*)&As[r * 72 + halfo + 8 * j] = z;
    }
    if (tid < 128) {
      const uint4* s4 = (const uint4*)(wfp + ((size_t)r * 512 + tau * 256 + ci0 + halfo));
#pragma unroll
      for (int j = 0; j < 4; ++j) *(uint4*)&Bs[r * 72 + halfo + 8 * j] = s4[j];
    }
    __syncthreads();
#pragma unroll
    for (int kc = 0; kc < 2; ++kc) {
      const int k0 = kc * 32 + quad * 8;
      half8 af[4], bfr[2];
#pragma unroll
      for (int mi = 0; mi < 4; ++mi)
        af[mi] = *(const half8*)&As[(64 * wy + 16 * mi + l15) * 72 + k0];
#pragma unroll
      for (int ni = 0; ni < 2; ++ni)
        bfr[ni] = *(const half8*)&Bs[(32 * wx + 16 * ni + l15) * 72 + k0];
#pragma unroll
      for (int mi = 0; mi < 4; ++mi)
#pragma unroll
        for (int ni = 0; ni < 2; ++ni)
          acc[mi][ni] = mfma16(af[mi], bfr[ni], acc[mi][ni]);
    }
    __syncthreads();
  }
#pragma unroll
  for (int mi = 0; mi < 4; ++mi)
#pragma unroll
    for (int ni = 0; ni < 2; ++ni) {
      int col = 32 * wx + 16 * ni + l15;
      int rowb = 64 * wy + 16 * mi + quad * 4;
      float bo = bf[col];
      size_t base = ((size_t)p0 + rowb) * 64 + col;
#pragma unroll
      for (int reg = 0; reg < 4; ++reg) {
        float v = acc[mi][ni][reg] + bo;
        float e = __expf(2.f * v);
        h0[base + (size_t)64 * reg] = (_Float16)(1.f - 2.f * __builtin_amdgcn_rcpf(e + 1.f));
      }
    }
}

// ---------------- one residual layer: 512 threads, 8 waves (2x4) -----------
// Double-buffered LDS, one barrier per K-stage. Stage order:
//   s0 cond[0:64] (K64), s1 cond[64:96] (K32), s2 h[t-2d], s3 h[t-d], s4 h[t]
// commit(s) -> set s&1. After the loop: A0 = h[t] (epilogue residual),
// A1/B1 free -> gate z / Wout.
__global__ __launch_bounds__(512, 4) void layer_kernel(
    const _Float16* __restrict__ hprev, _Float16* __restrict__ hnext,
    const _Float16* __restrict__ ctp,
    const _Float16* __restrict__ wdp_l, const _Float16* __restrict__ wcp_l,
    const _Float16* __restrict__ wop_l,
    const float* __restrict__ bde_l, const float* __restrict__ bout_l,
    _Float16* __restrict__ zslot, int d, int last)
{
  __shared__ _Float16 A0[128 * 72];
  __shared__ _Float16 A1[128 * 72];
  __shared__ _Float16 B0[128 * 72];
  __shared__ _Float16 B1[128 * 72];
  __shared__ float bde_s[128];

  const int tid = threadIdx.x;
  const int lane = tid & 63, w = tid >> 6;        // 8 waves
  const int wx = w & 1, wy = w >> 1;              // 2 (N) x 4 (M)
  const int l15 = lane & 15, quad = lane >> 4;
  const int p0 = blockIdx.x * 128;
  const int b = p0 >> 14, t0 = p0 & (T_LEN - 1);
  const int r2 = tid >> 2, qo = (tid & 3) * 16;   // staging: row, 16-elem chunk
  const int o8 = (tid & 3) * 8;                   // K=32 stage chunk

  if (tid < 128) bde_s[tid] = bde_l[tid];

  f32x4 acc[2][4];
#pragma unroll
  for (int mi = 0; mi < 2; ++mi)
#pragma unroll
    for (int ni = 0; ni < 4; ++ni) { f32x4 z = {0.f, 0.f, 0.f, 0.f}; acc[mi][ni] = z; }

  uint4 pa0, pa1, pb0, pb1;
  bool paz = false;

  auto issue = [&](int s) {
    if (s >= 2) {            // h taps: s2 -> -2d, s3 -> -d, s4 -> 0
      int ts = t0 + r2 - (4 - s) * d;
      paz = (ts < 0);
      int tsc = paz ? 0 : ts;
      const uint4* src = (const uint4*)(hprev + ((size_t)(b * T_LEN + tsc) * 64 + qo));
      pa0 = src[0]; pa1 = src[1];
      const uint4* sb = (const uint4*)(wdp_l + ((size_t)(s - 2) * 8192 + r2 * 64 + qo));
      pb0 = sb[0]; pb1 = sb[1];
    } else if (s == 0) {     // cond K=64
      paz = false;
      const uint4* sa = (const uint4*)(ctp + ((size_t)(p0 + r2) * 96 + qo));
      pa0 = sa[0]; pa1 = sa[1];
      const uint4* sb = (const uint4*)(wcp_l + ((size_t)r2 * 96 + qo));
      pb0 = sb[0]; pb1 = sb[1];
    } else {                 // s == 1: cond K=32 tail, 16B per thread
      paz = false;
      pa0 = *(const uint4*)(ctp + ((size_t)(p0 + r2) * 96 + 64 + o8));
      pb0 = *(const uint4*)(wcp_l + ((size_t)r2 * 96 + 64 + o8));
    }
  };
  auto commit = [&](int s) {
    _Float16* A = (s & 1) ? A1 : A0;
    _Float16* B = (s & 1) ? B1 : B0;
    if (s == 1) {
      *(uint4*)&A[r2 * 72 + o8] = pa0;
      *(uint4*)&B[r2 * 72 + o8] = pb0;
    } else {
      if (!paz) {
        *(uint4*)&A[r2 * 72 + qo] = pa0;
        *(uint4*)&A[r2 * 72 + qo + 8] = pa1;
      } else {
        uint4 z4 = {0, 0, 0, 0};
        *(uint4*)&A[r2 * 72 + qo] = z4;
        *(uint4*)&A[r2 * 72 + qo + 8] = z4;
      }
      *(uint4*)&B[r2 * 72 + qo] = pb0;
      *(uint4*)&B[r2 * 72 + qo + 8] = pb1;
    }
  };

  issue(0);
  commit(0);
#pragma unroll 1
  for (int s = 0; s < 5; ++s) {
    if (s < 4) issue(s + 1);       // global loads; latency hides under MFMA(s)
    __syncthreads();               // commit(s) visible; MFMA(s-1) all done
    const _Float16* A = (s & 1) ? A1 : A0;
    const _Float16* B = (s & 1) ? B1 : B0;
    const int nkc = (s == 1) ? 1 : 2;
    for (int kc = 0; kc < nkc; ++kc) {
      const int k0 = kc * 32 + quad * 8;
      half8 af[2], bfr[4];
#pragma unroll
      for (int mi = 0; mi < 2; ++mi)
        af[mi] = *(const half8*)&A[(32 * wy + 16 * mi + l15) * 72 + k0];
#pragma unroll
      for (int ni = 0; ni < 4; ++ni) {
        int ncol = 32 * wx + 16 * (ni & 1) + 64 * (ni >> 1);  // ch and ch+64
        bfr[ni] = *(const half8*)&B[(ncol + l15) * 72 + k0];
      }
#pragma unroll
      for (int mi = 0; mi < 2; ++mi)
#pragma unroll
        for (int ni = 0; ni < 4; ++ni)
          acc[mi][ni] = mfma16(af[mi], bfr[ni], acc[mi][ni]);
    }
    if (s < 4) commit(s + 1);      // set (s+1)&1: safe, all MFMA(s-1) done
  }

  // gate: z = tanh(y[ch]) * sigmoid(y[ch+64]) -> A1 (free: last read was s3)
#pragma unroll
  for (int mi = 0; mi < 2; ++mi)
#pragma unroll
    for (int ni2 = 0; ni2 < 2; ++ni2) {
      int colb = 32 * wx + 16 * ni2 + l15;
      float ba = bde_s[colb], bb = bde_s[colb + 64];
#pragma unroll
      for (int reg = 0; reg < 4; ++reg) {
        float av = acc[mi][ni2][reg] + ba;
        float gv = acc[mi][ni2 + 2][reg] + bb;
        float ea = __expf(2.f * av);
        float th = 1.f - 2.f * __builtin_amdgcn_rcpf(ea + 1.f);
        float sg = __builtin_amdgcn_rcpf(1.f + __expf(-gv));
        A1[(32 * wy + 16 * mi + quad * 4 + reg) * 72 + colb] = (_Float16)(th * sg);
      }
    }

  // stage W_out (64x64) into B1 (free: last read was s3)
  if (!last && tid < 256) {
    int row = tid >> 2;
    const uint4* sb = (const uint4*)(wop_l + ((size_t)row * 64 + qo));
    *(uint4*)&B1[row * 72 + qo] = sb[0];
    *(uint4*)&B1[row * 72 + qo + 8] = sb[1];
  }
  __syncthreads();

  // z -> global ring slot
  {
    uint4 v0 = *(const uint4*)&A1[r2 * 72 + qo];
    uint4 v1 = *(const uint4*)&A1[r2 * 72 + qo + 8];
    uint4* dst = (uint4*)(zslot + ((size_t)(p0 + r2) * 64 + qo));
    dst[0] = v0; dst[1] = v1;
  }

  if (last) return;

  // phase 4: h_out = (Wout*z + b_out + h_in) * SQH   (h_in = A0 = h[t])
  f32x4 a4[2][2];
#pragma unroll
  for (int mi = 0; mi < 2; ++mi)
#pragma unroll
    for (int ni = 0; ni < 2; ++ni) { f32x4 z = {0.f, 0.f, 0.f, 0.f}; a4[mi][ni] = z; }
#pragma unroll
  for (int kc = 0; kc < 2; ++kc) {
    const int k0 = kc * 32 + quad * 8;
    half8 af[2], bfr[2];
#pragma unroll
    for (int mi = 0; mi < 2; ++mi)
      af[mi] = *(const half8*)&A1[(32 * wy + 16 * mi + l15) * 72 + k0];
#pragma unroll
    for (int ni = 0; ni < 2; ++ni)
      bfr[ni] = *(const half8*)&B1[(32 * wx + 16 * ni + l15) * 72 + k0];
#pragma unroll
    for (int mi = 0; mi < 2; ++mi)
#pragma unroll
      for (int ni = 0; ni < 2; ++ni)
        a4[mi][ni] = mfma16(af[mi], bfr[ni], a4[mi][ni]);
  }
#pragma unroll
  for (int mi = 0; mi < 2; ++mi)
#pragma unroll
    for (int ni = 0; ni < 2; ++ni) {
      int col = 32 * wx + 16 * ni + l15;
      int rowb = 32 * wy + 16 * mi + quad * 4;
      float bo = bout_l[col];
#pragma unroll
      for (int reg = 0; reg < 4; ++reg) {
        float hv = (float)A0[(rowb + reg) * 72 + col];   // per-thread-owned cell
        A0[(rowb + reg) * 72 + col] = (_Float16)((a4[mi][ni][reg] + bo + hv) * SQH);
      }
    }
  __syncthreads();
  {
    uint4 v0 = *(const uint4*)&A0[r2 * 72 + qo];
    uint4 v1 = *(const uint4*)&A0[r2 * 72 + qo + 8];
    uint4* dst = (uint4*)(hnext + ((size_t)(p0 + r2) * 64 + qo));
    dst[0] = v0; dst[1] = v1;
  }
}

// ---------------- deferred skip flush (512 threads, both n-halves) --------
// z tile staged ONCE in LDS, shared by both 128-col halves (halves z traffic
// vs the old dim3(*,2) grid). Structure = rounds 2-4's proven flush_phase.
// mode 0: Abuf = acc   mode 1: Abuf += acc   mode 2: skr = relu((acc+Abuf)*q^19+bsk)
__global__ __launch_bounds__(512, 4) void flush_kernel(
    const _Float16* __restrict__ zbuf, const _Float16* __restrict__ wskp,
    _Float16* __restrict__ Abuf, const float* __restrict__ bsk,
    _Float16* __restrict__ skr, int l0, int g, int mode)
{
  __shared__ _Float16 As[128 * 72];
  __shared__ _Float16 Bs0[128 * 72];
  __shared__ _Float16 Bs1[128 * 72];
  const int tid = threadIdx.x;
  const int half = tid >> 8;
  _Float16* Bsh = half ? Bs1 : Bs0;
  const int tloc = tid & 255;
  const int lane = tloc & 63, w4 = tloc >> 6;
  const int wx = w4 & 1, wy = w4 >> 1;
  const int l15 = lane & 15, quad = lane >> 4;
  const int p0 = blockIdx.x * 128;
  const int n0 = half * 128;
  const int r = tloc >> 1, halfo = (tloc & 1) * 32;

  f32x4 acc[4][4];
#pragma unroll
  for (int mi = 0; mi < 4; ++mi)
#pragma unroll
    for (int ni = 0; ni < 4; ++ni) { f32x4 z = {0.f, 0.f, 0.f, 0.f}; acc[mi][ni] = z; }

#pragma unroll 1
  for (int j = 0; j < g; ++j) {
    const int lj = l0 + j;
    const _Float16* zsl = zbuf + (size_t)(lj & 7) * ((size_t)BT * 64);
    if (half == 0) {
      const uint4* sa = (const uint4*)(zsl + ((size_t)(p0 + r) * 64 + halfo));
#pragma unroll
      for (int jj = 0; jj < 4; ++jj) *(uint4*)&As[r * 72 + halfo + 8 * jj] = sa[jj];
    }
    const uint4* sb = (const uint4*)(wskp + ((size_t)(n0 + r) * 1280 + lj * 64 + halfo));
#pragma unroll
    for (int jj = 0; jj < 4; ++jj) *(uint4*)&Bsh[r * 72 + halfo + 8 * jj] = sb[jj];
    __syncthreads();
#pragma unroll
    for (int kc = 0; kc < 2; ++kc) {
      const int k0 = kc * 32 + quad * 8;
      half8 af[4], bfr[4];
#pragma unroll
      for (int mi = 0; mi < 4; ++mi)
        af[mi] = *(const half8*)&As[(64 * wy + 16 * mi + l15) * 72 + k0];
#pragma unroll
      for (int ni = 0; ni < 4; ++ni)
        bfr[ni] = *(const half8*)&Bsh[(64 * wx + 16 * ni + l15) * 72 + k0];
#pragma unroll
      for (int mi = 0; mi < 4; ++mi)
#pragma unroll
        for (int ni = 0; ni < 4; ++ni)
          acc[mi][ni] = mfma16(af[mi], bfr[ni], acc[mi][ni]);
    }
    __syncthreads();
  }
  const float Q19 = 0.0013810679320049757f;  // sqrt(0.5)^19
#pragma unroll
  for (int mi = 0; mi < 4; ++mi)
#pragma unroll
    for (int ni = 0; ni < 4; ++ni) {
      int col = n0 + 64 * wx + 16 * ni + l15;
      int rowb = 64 * wy + 16 * mi + quad * 4;
      size_t base = ((size_t)p0 + rowb) * 256 + col;
      if (mode == 2) {
        float bb = bsk[col];
#pragma unroll
        for (int reg = 0; reg < 4; ++reg) {
          float v = (acc[mi][ni][reg] + (float)Abuf[base + (size_t)256 * reg]) * Q19 + bb;
          skr[base + (size_t)256 * reg] = (_Float16)(v > 0.f ? v : 0.f);
        }
      } else if (mode == 1) {
#pragma unroll
        for (int reg = 0; reg < 4; ++reg) {
          size_t a = base + (size_t)256 * reg;
          Abuf[a] = (_Float16)((float)Abuf[a] + acc[mi][ni][reg]);
        }
      } else {
#pragma unroll
        for (int reg = 0; reg < 4; ++reg)
          Abuf[base + (size_t)256 * reg] = (_Float16)acc[mi][ni][reg];
      }
    }
}

// ---------------- generic 256x256 GEMM (last1 / last2) -------------------
// mode 0: dst f16 row-major (BT,256), relu.  mode 1: dst f32 (B,256,T), +bias,
// coalesced via LDS transpose.
__global__ __launch_bounds__(256, 4) void gemm256(
    const _Float16* __restrict__ Asrc, const _Float16* __restrict__ Bp,
    const float* __restrict__ bias, void* __restrict__ dst, int mode)
{
  __shared__ _Float16 smem[2 * 128 * 72];
  _Float16* As = smem;
  _Float16* Bs = smem + 128 * 72;
  const int tid = threadIdx.x;
  const int lane = tid & 63, w = tid >> 6;
  const int wx = w & 1, wy = w >> 1;
  const int l15 = lane & 15, quad = lane >> 4;
  const int p0 = blockIdx.x * 128;
  const int n0 = blockIdx.y * 128;
  const int r = tid >> 1, halfo = (tid & 1) * 32;

  f32x4 acc[4][4];
#pragma unroll
  for (int mi = 0; mi < 4; ++mi)
#pragma unroll
    for (int ni = 0; ni < 4; ++ni) { f32x4 z = {0.f, 0.f, 0.f, 0.f}; acc[mi][ni] = z; }

  for (int c4 = 0; c4 < 4; ++c4) {
    int k0g = c4 * 64;
    const uint4* sa = (const uint4*)(Asrc + ((size_t)(p0 + r) * 256 + k0g + halfo));
#pragma unroll
    for (int jj = 0; jj < 4; ++jj) *(uint4*)&As[r * 72 + halfo + 8 * jj] = sa[jj];
    const uint4* sb = (const uint4*)(Bp + ((size_t)(n0 + r) * 256 + k0g + halfo));
#pragma unroll
    for (int jj = 0; jj < 4; ++jj) *(uint4*)&Bs[r * 72 + halfo + 8 * jj] = sb[jj];
    __syncthreads();
#pragma unroll
    for (int kc = 0; kc < 2; ++kc) {
      const int k0 = kc * 32 + quad * 8;
      half8 af[4], bfr[4];
#pragma unroll
      for (int mi = 0; mi < 4; ++mi)
        af[mi] = *(const half8*)&As[(64 * wy + 16 * mi + l15) * 72 + k0];
#pragma unroll
      for (int ni = 0; ni < 4; ++ni)
        bfr[ni] = *(const half8*)&Bs[(64 * wx + 16 * ni + l15) * 72 + k0];
#pragma unroll
      for (int mi = 0; mi < 4; ++mi)
#pragma unroll
        for (int ni = 0; ni < 4; ++ni)
          acc[mi][ni] = mfma16(af[mi], bfr[ni], acc[mi][ni]);
    }
    __syncthreads();
  }
  if (mode == 0) {
#pragma unroll
    for (int mi = 0; mi < 4; ++mi)
#pragma unroll
      for (int ni = 0; ni < 4; ++ni) {
        int col = n0 + 64 * wx + 16 * ni + l15;
        int rowb = 64 * wy + 16 * mi + quad * 4;
        float bv = bias[col];
        _Float16* o = (_Float16*)dst;
#pragma unroll
        for (int reg = 0; reg < 4; ++reg) {
          float v = acc[mi][ni][reg] + bv;
          o[((size_t)(p0 + rowb + reg)) * 256 + col] = (_Float16)(v > 0.f ? v : 0.f);
        }
      }
  } else {
    // transposed coalesced store: two passes of 64 columns through LDS
    float* Ts = (float*)smem;       // 64 x 132 floats = 33792 B
    const int b = p0 >> 14, t0g = p0 & (T_LEN - 1);
    for (int pass = 0; pass < 2; ++pass) {
      if (wx == pass) {
#pragma unroll
        for (int mi = 0; mi < 4; ++mi)
#pragma unroll
          for (int ni = 0; ni < 4; ++ni) {
            int col_l = 16 * ni + l15;
            float bv = bias[n0 + 64 * pass + col_l];
            int tl = 64 * wy + 16 * mi + quad * 4;
#pragma unroll
            for (int reg = 0; reg < 4; ++reg)
              Ts[col_l * 132 + tl + reg] = acc[mi][ni][reg] + bv;
          }
      }
      __syncthreads();
      {
        int col_l = tid >> 2;
        int tq = (tid & 3) * 32;
        float* o = (float*)dst + ((size_t)b * 256 + n0 + 64 * pass + col_l) * T_LEN + t0g + tq;
#pragma unroll
        for (int j = 0; j < 8; ++j)
          *(float4*)(o + 4 * j) = *(const float4*)&Ts[col_l * 132 + tq + 4 * j];
      }
      __syncthreads();
    }
  }
}

extern "C" void kernel_launch(void* const* d_in, const int* in_sizes, int n_in,
                              void* d_out, int out_size, void* d_ws, size_t ws_size,
                              hipStream_t stream)
{
  const float* x     = (const float*)d_in[0];
  const float* c     = (const float*)d_in[1];
  const float* Wf    = (const float*)d_in[2];
  const float* bf    = (const float*)d_in[3];
  const float* Wdil  = (const float*)d_in[4];
  const float* bdil  = (const float*)d_in[5];
  const float* Wc    = (const float*)d_in[6];
  const float* bc    = (const float*)d_in[7];
  const float* Wskip = (const float*)d_in[8];
  const float* bskip = (const float*)d_in[9];
  const float* Wout  = (const float*)d_in[10];
  const float* bout  = (const float*)d_in[11];
  const float* Wl1   = (const float*)d_in[12];
  const float* bl1   = (const float*)d_in[13];
  const float* Wl2   = (const float*)d_in[14];
  const float* bl2   = (const float*)d_in[15];

  char* base = (char*)d_ws;
  // 8-slot z ring (64 MiB). Aliases: xt = slots 0-3 (consumed by first_conv
  // before layer 0 writes slot 0); skr = slots 4-7 (free after flush2);
  // y1 = slots 0-3 (free after flush3). Abuf (f16) lives in d_out, dead
  // before gemm256 #2 writes the final f32 output there.
  _Float16* zbuf = (_Float16*)base;
  _Float16* xt   = zbuf;
  _Float16* skr  = zbuf + (size_t)4 * BT * 64;
  _Float16* y1   = zbuf;
  _Float16* ctp  = (_Float16*)(base + 67108864);   // BT*96 f16 = 12.58 MB
  _Float16* hA   = (_Float16*)(base + 79691776);   // BT*64 f16 = 8.39 MB
  _Float16* hB   = (_Float16*)(base + 88080384);
  _Float16* wdp  = (_Float16*)(base + 96468992);
  _Float16* wcp  = wdp  + (size_t)20 * 3 * 128 * 64;
  _Float16* wop  = wcp  + (size_t)20 * 128 * 96;
  _Float16* wskp = wop  + (size_t)20 * 64 * 64;
  _Float16* wfp  = wskp + (size_t)256 * 1280;
  _Float16* wl1p = wfp  + (size_t)64 * 512;
  _Float16* wl2p = wl1p + (size_t)256 * 256;
  float*    bde  = (float*)(wl2p + (size_t)256 * 256);
  float*    bsk  = bde + 20 * 128;
  _Float16* Abuf = (_Float16*)d_out;               // f16 skip accumulator

  prep_pack<<<2048, 256, 0, stream>>>(Wf, Wdil, Wc, Wskip, Wout, Wl1, Wl2,
                                      bdil, bc, bskip,
                                      wdp, wcp, wop, wskp, wfp, wl1p, wl2p,
                                      bde, bsk);
  tr_kernel<<<NB * (T_LEN / 32) * 8, 256, 0, stream>>>(x, xt, 256, 256, 8);
  tr_kernel<<<NB * (T_LEN / 32) * 3, 256, 0, stream>>>(c, ctp, 80, 96, 3);
  first_conv<<<512, 256, 0, stream>>>(xt, wfp, bf, hA);

  const _Float16* hin = hA;
  _Float16* hout = hB;
  for (int l = 0; l < NLAYERS; ++l) {
    int d = 1 << (l % 10);
    layer_kernel<<<512, 512, 0, stream>>>(
        hin, hout, ctp,
        wdp + (size_t)l * 3 * 128 * 64, wcp + (size_t)l * 128 * 96,
        wop + (size_t)l * 64 * 64, bde + l * 128, bout + l * 64,
        zbuf + (size_t)(l & 7) * BT * 64, d, (l == NLAYERS - 1) ? 1 : 0);
    _Float16* tmp = (_Float16*)hin; hin = hout; hout = tmp;
    if (l == 7)  flush_kernel<<<512, 512, 0, stream>>>(zbuf, wskp, Abuf, bsk, skr, 0, 8, 0);
    if (l == 15) flush_kernel<<<512, 512, 0, stream>>>(zbuf, wskp, Abuf, bsk, skr, 8, 8, 1);
    if (l == 19) flush_kernel<<<512, 512, 0, stream>>>(zbuf, wskp, Abuf, bsk, skr, 16, 4, 2);
  }
  gemm256<<<dim3(512, 2), 256, 0, stream>>>(skr, wl1p, bl1, (void*)y1, 0);
  gemm256<<<dim3(512, 2), 256, 0, stream>>>(y1, wl2p, bl2, d_out, 1);
}

// Round 7
// 711.582 us; speedup vs baseline: 3.9778x; 1.0132x over previous
//
#include <hip/hip_runtime.h>
#include <math.h>

// WaveNet (4,256,16384), 20 layers. Round 11 = round-10 structure +
//  (1) T1 chunked XCD swizzle applied CONSISTENTLY in every kernel that
//      touches the p0 row space (layer, flush, first_conv, gemm256, both
//      transposes): rows [k*8192,(k+1)*8192) pin to XCD k across all
//      dispatches, so h/ctp/z/skr/Abuf producer->consumer reuse stays in
//      the local 4MB L2 instead of crossing XCDs via L3/MALL.
//  (2) vectorized x-transpose (float4 loads, 128-t tiles, 4096 blocks)
//      replacing the scalar-load 32x32 version (was 40us, 1.65 TB/s).

#define T_LEN   16384
#define NB      4
#define BT      (NB * T_LEN)     // 65536
#define NLAYERS 20
#define SQH     0.70710678118654752440f

typedef _Float16 half8 __attribute__((ext_vector_type(8)));
typedef _Float16 half4 __attribute__((ext_vector_type(4)));
typedef float f32x4 __attribute__((ext_vector_type(4)));

__device__ inline f32x4 mfma16(half8 a, half8 b, f32x4 c) {
  return __builtin_amdgcn_mfma_f32_16x16x32_f16(a, b, c, 0, 0, 0);
}

// chunked XCD swizzle: physical block pb (XCD = pb%8 round-robin) -> logical
// lb such that consecutive logical blocks share an XCD chunk. nwg % 8 == 0.
__device__ __forceinline__ int xswz(int pb, int nwg) {
  return (pb & 7) * (nwg >> 3) + (pb >> 3);
}

// ---------------- weight packing (f16) ----------------
__global__ __launch_bounds__(256) void prep_pack(
    const float* __restrict__ Wf, const float* __restrict__ Wdil,
    const float* __restrict__ Wc, const float* __restrict__ Wskip,
    const float* __restrict__ Wout, const float* __restrict__ Wl1,
    const float* __restrict__ Wl2, const float* __restrict__ bdil,
    const float* __restrict__ bc, const float* __restrict__ bskip,
    _Float16* __restrict__ wdp, _Float16* __restrict__ wcp,
    _Float16* __restrict__ wop, _Float16* __restrict__ wskp,
    _Float16* __restrict__ wfp, _Float16* __restrict__ wl1p,
    _Float16* __restrict__ wl2p, float* __restrict__ bde,
    float* __restrict__ bsk)
{
  const float Q = 0.70710678118654752440f;
  const int WDP_E = 20 * 3 * 128 * 64;   // [l][tau][n][kc]
  const int WCP_E = 20 * 128 * 96;       // [l][n][kc pad96]
  const int WOP_E = 20 * 64 * 64;        // [l][n][kc]
  const int WSK_E = 256 * 1280;          // [n][l*64+kc], scale q^(1-l)
  const int WFP_E = 64 * 512;            // [n][tau*256+ci]
  const int WL_E  = 256 * 256;
  const int BDE_E = 20 * 128;
  const int BSK_E = 256;
  const int TOTAL = WDP_E + WCP_E + WOP_E + WSK_E + WFP_E + 2 * WL_E + BDE_E + BSK_E;
  for (int i = blockIdx.x * blockDim.x + threadIdx.x; i < TOTAL;
       i += gridDim.x * blockDim.x) {
    int j = i;
    if (j < WDP_E) {
      int l = j / (3 * 128 * 64); int r2 = j % (3 * 128 * 64);
      int tau = r2 / (128 * 64);  int r3 = r2 % (128 * 64);
      int n = r3 >> 6; int kc = r3 & 63;
      wdp[j] = (_Float16)Wdil[((l * 128 + n) * 64 + kc) * 3 + tau];
      continue;
    }
    j -= WDP_E;
    if (j < WCP_E) {
      int l = j / (128 * 96); int r2 = j % (128 * 96);
      int n = r2 / 96; int kc = r2 % 96;
      wcp[j] = (_Float16)(kc < 80 ? Wc[(l * 128 + n) * 80 + kc] : 0.f);
      continue;
    }
    j -= WCP_E;
    if (j < WOP_E) {
      int l = j >> 12; int r2 = j & 4095;
      int n = r2 >> 6; int kc = r2 & 63;
      wop[j] = (_Float16)Wout[(l * 64 + n) * 64 + kc];
      continue;
    }
    j -= WOP_E;
    if (j < WSK_E) {
      int n = j / 1280; int k = j % 1280;
      int l = k >> 6; int kc = k & 63;
      float f = (l == 0) ? 1.f : powf(Q, (float)(1 - l));
      wskp[j] = (_Float16)(Wskip[(l * 256 + n) * 64 + kc] * f);
      continue;
    }
    j -= WSK_E;
    if (j < WFP_E) {
      int n = j >> 9; int k = j & 511;
      int tau = k >> 8; int ci = k & 255;
      wfp[j] = (_Float16)Wf[(n * 256 + ci) * 2 + tau];
      continue;
    }
    j -= WFP_E;
    if (j < WL_E) { wl1p[j] = (_Float16)Wl1[j]; continue; }
    j -= WL_E;
    if (j < WL_E) { wl2p[j] = (_Float16)Wl2[j]; continue; }
    j -= WL_E;
    if (j < BDE_E) { bde[j] = bdil[j] + bc[j]; continue; }
    j -= BDE_E;
    {
      int n = j;
      float s = 0.f;
      for (int l = 0; l < NLAYERS; ++l) {
        float w = powf(Q, (float)(l == 0 ? 19 : 20 - l));
        s += bskip[l * 256 + n] * w;
      }
      bsk[n] = s;
    }
  }
}

// ------- x transpose, vectorized: (B,256,T) f32 -> (BT,256) f16 -----------
// 4096 blocks, 128-t x 32-ch tiles, float4 loads (16B/lane).
__global__ __launch_bounds__(256) void tr_x_kernel(
    const float* __restrict__ src, _Float16* __restrict__ dst)
{
  __shared__ float tile[32 * 132];
  const int lb = xswz(blockIdx.x, 4096);
  const int row_tile = lb >> 3, cb = lb & 7;
  const int bb = row_tile >> 7;
  const int t0 = (row_tile & 127) * 128;
  const int ch0 = cb * 32;
  {
    int ch = threadIdx.x >> 3, tq = (threadIdx.x & 7) * 16;
    const float4* s4 = (const float4*)(src + ((size_t)(bb * 256 + ch0 + ch)) * T_LEN + t0 + tq);
#pragma unroll
    for (int j = 0; j < 4; ++j)
      *(float4*)&tile[ch * 132 + tq + 4 * j] = s4[j];
  }
  __syncthreads();
  {
    int t = threadIdx.x >> 1, c16 = (threadIdx.x & 1) * 16;
    half8 h0, h1;
#pragma unroll
    for (int j = 0; j < 8; ++j) {
      h0[j] = (_Float16)tile[(c16 + j) * 132 + t];
      h1[j] = (_Float16)tile[(c16 + 8 + j) * 132 + t];
    }
    _Float16* o = dst + ((size_t)(bb * T_LEN + t0 + t)) * 256 + ch0 + c16;
    *(half8*)o = h0;
    *(half8*)(o + 8) = h1;
  }
}

// ---------------- transpose (B,C,T) f32 -> (BT,Cpad) f16 (c path) ---------
__global__ __launch_bounds__(256) void tr_kernel(
    const float* __restrict__ src, _Float16* __restrict__ dst, int C, int Cpad, int CB)
{
  __shared__ float tile[32 * 33];
  int lb = xswz(blockIdx.x, gridDim.x);
  int cb = lb % CB;
  int tb = (lb / CB) % (T_LEN / 32);
  int bb = lb / (CB * (T_LEN / 32));
  int t0 = tb * 32, ch0 = cb * 32;
  int tl = threadIdx.x & 31, cl = threadIdx.x >> 5;
#pragma unroll
  for (int i = 0; i < 4; ++i) {
    int ch = cl + 8 * i;
    float v = (ch0 + ch < C) ? src[((size_t)bb * C + ch0 + ch) * T_LEN + t0 + tl] : 0.f;
    tile[ch * 33 + tl] = v;
  }
  __syncthreads();
  int t = threadIdx.x >> 3;
  int c4 = (threadIdx.x & 7) * 4;
  half4 hv = {(_Float16)tile[(c4 + 0) * 33 + t], (_Float16)tile[(c4 + 1) * 33 + t],
              (_Float16)tile[(c4 + 2) * 33 + t], (_Float16)tile[(c4 + 3) * 33 + t]};
  *(half4*)&dst[((size_t)bb * T_LEN + t0 + t) * Cpad + ch0 + c4] = hv;
}

// ---------------- first conv: h0 = tanh(Wf*[x(t-1);x(t)] + bf), f16 out ----
__global__ __launch_bounds__(256, 4) void first_conv(
    const _Float16* __restrict__ xt, const _Float16* __restrict__ wfp,
    const float* __restrict__ bf, _Float16* __restrict__ h0)
{
  __shared__ _Float16 As[128 * 72];
  __shared__ _Float16 Bs[64 * 72];
  const int tid = threadIdx.x;
  const int lane = tid & 63, w = tid >> 6;
  const int wx = w & 1, wy = w >> 1;
  const int l15 = lane & 15, quad = lane >> 4;
  const int p0 = xswz(blockIdx.x, 512) * 128;
  const int b = p0 >> 14, t0 = p0 & (T_LEN - 1);
  const int r = tid >> 1, halfo = (tid & 1) * 32;

  f32x4 acc[4][2];
#pragma unroll
  for (int mi = 0; mi < 4; ++mi)
#pragma unroll
    for (int ni = 0; ni < 2; ++ni) { f32x4 z = {0.f, 0.f, 0.f, 0.f}; acc[mi][ni] = z; }

  for (int s = 0; s < 8; ++s) {
    int tau = s >> 2, ci0 = (s & 3) * 64;
    int ts = t0 + r - 1 + tau;
    if (ts >= 0) {
      const uint4* src = (const uint4*)(xt + ((size_t)(b * T_LEN + ts) * 256 + ci0 + halfo));
#pragma unroll
      for (int j = 0; j < 4; ++j) *(uint4*)&As[r * 72 + halfo + 8 * j] = src[j];
    } else {
      uint4 z = {0, 0, 0, 0};
#pragma unroll
      for (int j = 0; j < 4; ++j) *(uint4*)&As[r * 72 + halfo + 8 * j] = z;
    }
    if (tid < 128) {
      const uint4* s4 = (const uint4*)(wfp + ((size_t)r * 512 + tau * 256 + ci0 + halfo));
#pragma unroll
      for (int j = 0; j < 4; ++j) *(uint4*)&Bs[r * 72 + halfo + 8 * j] = s4[j];
    }
    __syncthreads();
#pragma unroll
    for (int kc = 0; kc < 2; ++kc) {
      const int k0 = kc * 32 + quad * 8;
      half8 af[4], bfr[2];
#pragma unroll
      for (int mi = 0; mi < 4; ++mi)
        af[mi] = *(const half8*)&As[(64 * wy + 16 * mi + l15) * 72 + k0];
#pragma unroll
      for (int ni = 0; ni < 2; ++ni)
        bfr[ni] = *(const half8*)&Bs[(32 * wx + 16 * ni + l15) * 72 + k0];
#pragma unroll
      for (int mi = 0; mi < 4; ++mi)
#pragma unroll
        for (int ni = 0; ni < 2; ++ni)
          acc[mi][ni] = mfma16(af[mi], bfr[ni], acc[mi][ni]);
    }
    __syncthreads();
  }
#pragma unroll
  for (int mi = 0; mi < 4; ++mi)
#pragma unroll
    for (int ni = 0; ni < 2; ++ni) {
      int col = 32 * wx + 16 * ni + l15;
      int rowb = 64 * wy + 16 * mi + quad * 4;
      float bo = bf[col];
      size_t base = ((size_t)p0 + rowb) * 64 + col;
#pragma unroll
      for (int reg = 0; reg < 4; ++reg) {
        float v = acc[mi][ni][reg] + bo;
        float e = __expf(2.f * v);
        h0[base + (size_t)64 * reg] = (_Float16)(1.f - 2.f * __builtin_amdgcn_rcpf(e + 1.f));
      }
    }
}

// ---------------- one residual layer: 512 threads, 8 waves (2x4) -----------
// Double-buffered LDS, one barrier per K-stage. Stage order:
//   s0 cond[0:64] (K64), s1 cond[64:96] (K32), s2 h[t-2d], s3 h[t-d], s4 h[t]
__global__ __launch_bounds__(512, 4) void layer_kernel(
    const _Float16* __restrict__ hprev, _Float16* __restrict__ hnext,
    const _Float16* __restrict__ ctp,
    const _Float16* __restrict__ wdp_l, const _Float16* __restrict__ wcp_l,
    const _Float16* __restrict__ wop_l,
    const float* __restrict__ bde_l, const float* __restrict__ bout_l,
    _Float16* __restrict__ zslot, int d, int last)
{
  __shared__ _Float16 A0[128 * 72];
  __shared__ _Float16 A1[128 * 72];
  __shared__ _Float16 B0[128 * 72];
  __shared__ _Float16 B1[128 * 72];
  __shared__ float bde_s[128];

  const int tid = threadIdx.x;
  const int lane = tid & 63, w = tid >> 6;        // 8 waves
  const int wx = w & 1, wy = w >> 1;              // 2 (N) x 4 (M)
  const int l15 = lane & 15, quad = lane >> 4;
  const int p0 = xswz(blockIdx.x, 512) * 128;
  const int b = p0 >> 14, t0 = p0 & (T_LEN - 1);
  const int r2 = tid >> 2, qo = (tid & 3) * 16;   // staging: row, 16-elem chunk
  const int o8 = (tid & 3) * 8;                   // K=32 stage chunk

  if (tid < 128) bde_s[tid] = bde_l[tid];

  f32x4 acc[2][4];
#pragma unroll
  for (int mi = 0; mi < 2; ++mi)
#pragma unroll
    for (int ni = 0; ni < 4; ++ni) { f32x4 z = {0.f, 0.f, 0.f, 0.f}; acc[mi][ni] = z; }

  uint4 pa0, pa1, pb0, pb1;
  bool paz = false;

  auto issue = [&](int s) {
    if (s >= 2) {            // h taps: s2 -> -2d, s3 -> -d, s4 -> 0
      int ts = t0 + r2 - (4 - s) * d;
      paz = (ts < 0);
      int tsc = paz ? 0 : ts;
      const uint4* src = (const uint4*)(hprev + ((size_t)(b * T_LEN + tsc) * 64 + qo));
      pa0 = src[0]; pa1 = src[1];
      const uint4* sb = (const uint4*)(wdp_l + ((size_t)(s - 2) * 8192 + r2 * 64 + qo));
      pb0 = sb[0]; pb1 = sb[1];
    } else if (s == 0) {     // cond K=64
      paz = false;
      const uint4* sa = (const uint4*)(ctp + ((size_t)(p0 + r2) * 96 + qo));
      pa0 = sa[0]; pa1 = sa[1];
      const uint4* sb = (const uint4*)(wcp_l + ((size_t)r2 * 96 + qo));
      pb0 = sb[0]; pb1 = sb[1];
    } else {                 // s == 1: cond K=32 tail, 16B per thread
      paz = false;
      pa0 = *(const uint4*)(ctp + ((size_t)(p0 + r2) * 96 + 64 + o8));
      pb0 = *(const uint4*)(wcp_l + ((size_t)r2 * 96 + 64 + o8));
    }
  };
  auto commit = [&](int s) {
    _Float16* A = (s & 1) ? A1 : A0;
    _Float16* B = (s & 1) ? B1 : B0;
    if (s == 1) {
      *(uint4*)&A[r2 * 72 + o8] = pa0;
      *(uint4*)&B[r2 * 72 + o8] = pb0;
    } else {
      if (!paz) {
        *(uint4*)&A[r2 * 72 + qo] = pa0;
        *(uint4*)&A[r2 * 72 + qo + 8] = pa1;
      } else {
        uint4 z4 = {0, 0, 0, 0};
        *(uint4*)&A[r2 * 72 + qo] = z4;
        *(uint4*)&A[r2 * 72 + qo + 8] = z4;
      }
      *(uint4*)&B[r2 * 72 + qo] = pb0;
      *(uint4*)&B[r2 * 72 + qo + 8] = pb1;
    }
  };

  issue(0);
  commit(0);
#pragma unroll 1
  for (int s = 0; s < 5; ++s) {
    if (s < 4) issue(s + 1);       // global loads; latency hides under MFMA(s)
    __syncthreads();               // commit(s) visible; MFMA(s-1) all done
    const _Float16* A = (s & 1) ? A1 : A0;
    const _Float16* B = (s & 1) ? B1 : B0;
    const int nkc = (s == 1) ? 1 : 2;
    for (int kc = 0; kc < nkc; ++kc) {
      const int k0 = kc * 32 + quad * 8;
      half8 af[2], bfr[4];
#pragma unroll
      for (int mi = 0; mi < 2; ++mi)
        af[mi] = *(const half8*)&A[(32 * wy + 16 * mi + l15) * 72 + k0];
#pragma unroll
      for (int ni = 0; ni < 4; ++ni) {
        int ncol = 32 * wx + 16 * (ni & 1) + 64 * (ni >> 1);  // ch and ch+64
        bfr[ni] = *(const half8*)&B[(ncol + l15) * 72 + k0];
      }
#pragma unroll
      for (int mi = 0; mi < 2; ++mi)
#pragma unroll
        for (int ni = 0; ni < 4; ++ni)
          acc[mi][ni] = mfma16(af[mi], bfr[ni], acc[mi][ni]);
    }
    if (s < 4) commit(s + 1);      // writes the other buffer parity: safe
  }

  // gate: z = tanh(y[ch]) * sigmoid(y[ch+64]) -> A1 (free: last read was s3)
#pragma unroll
  for (int mi = 0; mi < 2; ++mi)
#pragma unroll
    for (int ni2 = 0; ni2 < 2; ++ni2) {
      int colb = 32 * wx + 16 * ni2 + l15;
      float ba = bde_s[colb], bb = bde_s[colb + 64];
#pragma unroll
      for (int reg = 0; reg < 4; ++reg) {
        float av = acc[mi][ni2][reg] + ba;
        float gv = acc[mi][ni2 + 2][reg] + bb;
        float ea = __expf(2.f * av);
        float th = 1.f - 2.f * __builtin_amdgcn_rcpf(ea + 1.f);
        float sg = __builtin_amdgcn_rcpf(1.f + __expf(-gv));
        A1[(32 * wy + 16 * mi + quad * 4 + reg) * 72 + colb] = (_Float16)(th * sg);
      }
    }

  // stage W_out (64x64) into B1 (free: last read was s3)
  if (!last && tid < 256) {
    int row = tid >> 2;
    const uint4* sb = (const uint4*)(wop_l + ((size_t)row * 64 + qo));
    *(uint4*)&B1[row * 72 + qo] = sb[0];
    *(uint4*)&B1[row * 72 + qo + 8] = sb[1];
  }
  __syncthreads();

  // z -> global ring slot
  {
    uint4 v0 = *(const uint4*)&A1[r2 * 72 + qo];
    uint4 v1 = *(const uint4*)&A1[r2 * 72 + qo + 8];
    uint4* dst = (uint4*)(zslot + ((size_t)(p0 + r2) * 64 + qo));
    dst[0] = v0; dst[1] = v1;
  }

  if (last) return;

  // phase 4: h_out = (Wout*z + b_out + h_in) * SQH   (h_in = A0 = h[t])
  f32x4 a4[2][2];
#pragma unroll
  for (int mi = 0; mi < 2; ++mi)
#pragma unroll
    for (int ni = 0; ni < 2; ++ni) { f32x4 z = {0.f, 0.f, 0.f, 0.f}; a4[mi][ni] = z; }
#pragma unroll
  for (int kc = 0; kc < 2; ++kc) {
    const int k0 = kc * 32 + quad * 8;
    half8 af[2], bfr[2];
#pragma unroll
    for (int mi = 0; mi < 2; ++mi)
      af[mi] = *(const half8*)&A1[(32 * wy + 16 * mi + l15) * 72 + k0];
#pragma unroll
    for (int ni = 0; ni < 2; ++ni)
      bfr[ni] = *(const half8*)&B1[(32 * wx + 16 * ni + l15) * 72 + k0];
#pragma unroll
    for (int mi = 0; mi < 2; ++mi)
#pragma unroll
      for (int ni = 0; ni < 2; ++ni)
        a4[mi][ni] = mfma16(af[mi], bfr[ni], a4[mi][ni]);
  }
#pragma unroll
  for (int mi = 0; mi < 2; ++mi)
#pragma unroll
    for (int ni = 0; ni < 2; ++ni) {
      int col = 32 * wx + 16 * ni + l15;
      int rowb = 32 * wy + 16 * mi + quad * 4;
      float bo = bout_l[col];
#pragma unroll
      for (int reg = 0; reg < 4; ++reg) {
        float hv = (float)A0[(rowb + reg) * 72 + col];   // per-thread-owned cell
        A0[(rowb + reg) * 72 + col] = (_Float16)((a4[mi][ni][reg] + bo + hv) * SQH);
      }
    }
  __syncthreads();
  {
    uint4 v0 = *(const uint4*)&A0[r2 * 72 + qo];
    uint4 v1 = *(const uint4*)&A0[r2 * 72 + qo + 8];
    uint4* dst = (uint4*)(hnext + ((size_t)(p0 + r2) * 64 + qo));
    dst[0] = v0; dst[1] = v1;
  }
}

// ---------------- deferred skip flush (512 threads, both n-halves) --------
// z tile staged ONCE in LDS, shared by both 128-col halves.
// mode 0: Abuf = acc   mode 1: Abuf += acc   mode 2: skr = relu((acc+Abuf)*q^19+bsk)
__global__ __launch_bounds__(512, 4) void flush_kernel(
    const _Float16* __restrict__ zbuf, const _Float16* __restrict__ wskp,
    _Float16* __restrict__ Abuf, const float* __restrict__ bsk,
    _Float16* __restrict__ skr, int l0, int g, int mode)
{
  __shared__ _Float16 As[128 * 72];
  __shared__ _Float16 Bs0[128 * 72];
  __shared__ _Float16 Bs1[128 * 72];
  const int tid = threadIdx.x;
  const int half = tid >> 8;
  _Float16* Bsh = half ? Bs1 : Bs0;
  const int tloc = tid & 255;
  const int lane = tloc & 63, w4 = tloc >> 6;
  const int wx = w4 & 1, wy = w4 >> 1;
  const int l15 = lane & 15, quad = lane >> 4;
  const int p0 = xswz(blockIdx.x, 512) * 128;
  const int n0 = half * 128;
  const int r = tloc >> 1, halfo = (tloc & 1) * 32;

  f32x4 acc[4][4];
#pragma unroll
  for (int mi = 0; mi < 4; ++mi)
#pragma unroll
    for (int ni = 0; ni < 4; ++ni) { f32x4 z = {0.f, 0.f, 0.f, 0.f}; acc[mi][ni] = z; }

#pragma unroll 1
  for (int j = 0; j < g; ++j) {
    const int lj = l0 + j;
    const _Float16* zsl = zbuf + (size_t)(lj & 7) * ((size_t)BT * 64);
    if (half == 0) {
      const uint4* sa = (const uint4*)(zsl + ((size_t)(p0 + r) * 64 + halfo));
#pragma unroll
      for (int jj = 0; jj < 4; ++jj) *(uint4*)&As[r * 72 + halfo + 8 * jj] = sa[jj];
    }
    const uint4* sb = (const uint4*)(wskp + ((size_t)(n0 + r) * 1280 + lj * 64 + halfo));
#pragma unroll
    for (int jj = 0; jj < 4; ++jj) *(uint4*)&Bsh[r * 72 + halfo + 8 * jj] = sb[jj];
    __syncthreads();
#pragma unroll
    for (int kc = 0; kc < 2; ++kc) {
      const int k0 = kc * 32 + quad * 8;
      half8 af[4], bfr[4];
#pragma unroll
      for (int mi = 0; mi < 4; ++mi)
        af[mi] = *(const half8*)&As[(64 * wy + 16 * mi + l15) * 72 + k0];
#pragma unroll
      for (int ni = 0; ni < 4; ++ni)
        bfr[ni] = *(const half8*)&Bsh[(64 * wx + 16 * ni + l15) * 72 + k0];
#pragma unroll
      for (int mi = 0; mi < 4; ++mi)
#pragma unroll
        for (int ni = 0; ni < 4; ++ni)
          acc[mi][ni] = mfma16(af[mi], bfr[ni], acc[mi][ni]);
    }
    __syncthreads();
  }
  const float Q19 = 0.0013810679320049757f;  // sqrt(0.5)^19
#pragma unroll
  for (int mi = 0; mi < 4; ++mi)
#pragma unroll
    for (int ni = 0; ni < 4; ++ni) {
      int col = n0 + 64 * wx + 16 * ni + l15;
      int rowb = 64 * wy + 16 * mi + quad * 4;
      size_t base = ((size_t)p0 + rowb) * 256 + col;
      if (mode == 2) {
        float bb = bsk[col];
#pragma unroll
        for (int reg = 0; reg < 4; ++reg) {
          float v = (acc[mi][ni][reg] + (float)Abuf[base + (size_t)256 * reg]) * Q19 + bb;
          skr[base + (size_t)256 * reg] = (_Float16)(v > 0.f ? v : 0.f);
        }
      } else if (mode == 1) {
#pragma unroll
        for (int reg = 0; reg < 4; ++reg) {
          size_t a = base + (size_t)256 * reg;
          Abuf[a] = (_Float16)((float)Abuf[a] + acc[mi][ni][reg]);
        }
      } else {
#pragma unroll
        for (int reg = 0; reg < 4; ++reg)
          Abuf[base + (size_t)256 * reg] = (_Float16)acc[mi][ni][reg];
      }
    }
}

// ---------------- generic 256x256 GEMM (last1 / last2) -------------------
// mode 0: dst f16 row-major (BT,256), relu.  mode 1: dst f32 (B,256,T), +bias,
// coalesced via LDS transpose.
__global__ __launch_bounds__(256, 4) void gemm256(
    const _Float16* __restrict__ Asrc, const _Float16* __restrict__ Bp,
    const float* __restrict__ bias, void* __restrict__ dst, int mode)
{
  __shared__ _Float16 smem[2 * 128 * 72];
  _Float16* As = smem;
  _Float16* Bs = smem + 128 * 72;
  const int tid = threadIdx.x;
  const int lane = tid & 63, w = tid >> 6;
  const int wx = w & 1, wy = w >> 1;
  const int l15 = lane & 15, quad = lane >> 4;
  const int p0 = xswz(blockIdx.x, 512) * 128;
  const int n0 = blockIdx.y * 128;
  const int r = tid >> 1, halfo = (tid & 1) * 32;

  f32x4 acc[4][4];
#pragma unroll
  for (int mi = 0; mi < 4; ++mi)
#pragma unroll
    for (int ni = 0; ni < 4; ++ni) { f32x4 z = {0.f, 0.f, 0.f, 0.f}; acc[mi][ni] = z; }

  for (int c4 = 0; c4 < 4; ++c4) {
    int k0g = c4 * 64;
    const uint4* sa = (const uint4*)(Asrc + ((size_t)(p0 + r) * 256 + k0g + halfo));
#pragma unroll
    for (int jj = 0; jj < 4; ++jj) *(uint4*)&As[r * 72 + halfo + 8 * jj] = sa[jj];
    const uint4* sb = (const uint4*)(Bp + ((size_t)(n0 + r) * 256 + k0g + halfo));
#pragma unroll
    for (int jj = 0; jj < 4; ++jj) *(uint4*)&Bs[r * 72 + halfo + 8 * jj] = sb[jj];
    __syncthreads();
#pragma unroll
    for (int kc = 0; kc < 2; ++kc) {
      const int k0 = kc * 32 + quad * 8;
      half8 af[4], bfr[4];
#pragma unroll
      for (int mi = 0; mi < 4; ++mi)
        af[mi] = *(const half8*)&As[(64 * wy + 16 * mi + l15) * 72 + k0];
#pragma unroll
      for (int ni = 0; ni < 4; ++ni)
        bfr[ni] = *(const half8*)&Bs[(64 * wx + 16 * ni + l15) * 72 + k0];
#pragma unroll
      for (int mi = 0; mi < 4; ++mi)
#pragma unroll
        for (int ni = 0; ni < 4; ++ni)
          acc[mi][ni] = mfma16(af[mi], bfr[ni], acc[mi][ni]);
    }
    __syncthreads();
  }
  if (mode == 0) {
#pragma unroll
    for (int mi = 0; mi < 4; ++mi)
#pragma unroll
      for (int ni = 0; ni < 4; ++ni) {
        int col = n0 + 64 * wx + 16 * ni + l15;
        int rowb = 64 * wy + 16 * mi + quad * 4;
        float bv = bias[col];
        _Float16* o = (_Float16*)dst;
#pragma unroll
        for (int reg = 0; reg < 4; ++reg) {
          float v = acc[mi][ni][reg] + bv;
          o[((size_t)(p0 + rowb + reg)) * 256 + col] = (_Float16)(v > 0.f ? v : 0.f);
        }
      }
  } else {
    // transposed coalesced store: two passes of 64 columns through LDS
    float* Ts = (float*)smem;       // 64 x 132 floats = 33792 B
    const int b = p0 >> 14, t0g = p0 & (T_LEN - 1);
    for (int pass = 0; pass < 2; ++pass) {
      if (wx == pass) {
#pragma unroll
        for (int mi = 0; mi < 4; ++mi)
#pragma unroll
          for (int ni = 0; ni < 4; ++ni) {
            int col_l = 16 * ni + l15;
            float bv = bias[n0 + 64 * pass + col_l];
            int tl = 64 * wy + 16 * mi + quad * 4;
#pragma unroll
            for (int reg = 0; reg < 4; ++reg)
              Ts[col_l * 132 + tl + reg] = acc[mi][ni][reg] + bv;
          }
      }
      __syncthreads();
      {
        int col_l = tid >> 2;
        int tq = (tid & 3) * 32;
        float* o = (float*)dst + ((size_t)b * 256 + n0 + 64 * pass + col_l) * T_LEN + t0g + tq;
#pragma unroll
        for (int j = 0; j < 8; ++j)
          *(float4*)(o + 4 * j) = *(const float4*)&Ts[col_l * 132 + tq + 4 * j];
      }
      __syncthreads();
    }
  }
}

extern "C" void kernel_launch(void* const* d_in, const int* in_sizes, int n_in,
                              void* d_out, int out_size, void* d_ws, size_t ws_size,
                              hipStream_t stream)
{
  const float* x     = (const float*)d_in[0];
  const float* c     = (const float*)d_in[1];
  const float* Wf    = (const float*)d_in[2];
  const float* bf    = (const float*)d_in[3];
  const float* Wdil  = (const float*)d_in[4];
  const float* bdil  = (const float*)d_in[5];
  const float* Wc    = (const float*)d_in[6];
  const float* bc    = (const float*)d_in[7];
  const float* Wskip = (const float*)d_in[8];
  const float* bskip = (const float*)d_in[9];
  const float* Wout  = (const float*)d_in[10];
  const float* bout  = (const float*)d_in[11];
  const float* Wl1   = (const float*)d_in[12];
  const float* bl1   = (const float*)d_in[13];
  const float* Wl2   = (const float*)d_in[14];
  const float* bl2   = (const float*)d_in[15];

  char* base = (char*)d_ws;
  // 8-slot z ring (64 MiB). Aliases: xt = slots 0-3 (consumed by first_conv
  // before layer 0 writes slot 0); skr = slots 4-7 (free after flush2);
  // y1 = slots 0-3 (free after flush3). Abuf (f16) lives in d_out, dead
  // before gemm256 #2 writes the final f32 output there.
  _Float16* zbuf = (_Float16*)base;
  _Float16* xt   = zbuf;
  _Float16* skr  = zbuf + (size_t)4 * BT * 64;
  _Float16* y1   = zbuf;
  _Float16* ctp  = (_Float16*)(base + 67108864);   // BT*96 f16 = 12.58 MB
  _Float16* hA   = (_Float16*)(base + 79691776);   // BT*64 f16 = 8.39 MB
  _Float16* hB   = (_Float16*)(base + 88080384);
  _Float16* wdp  = (_Float16*)(base + 96468992);
  _Float16* wcp  = wdp  + (size_t)20 * 3 * 128 * 64;
  _Float16* wop  = wcp  + (size_t)20 * 128 * 96;
  _Float16* wskp = wop  + (size_t)20 * 64 * 64;
  _Float16* wfp  = wskp + (size_t)256 * 1280;
  _Float16* wl1p = wfp  + (size_t)64 * 512;
  _Float16* wl2p = wl1p + (size_t)256 * 256;
  float*    bde  = (float*)(wl2p + (size_t)256 * 256);
  float*    bsk  = bde + 20 * 128;
  _Float16* Abuf = (_Float16*)d_out;               // f16 skip accumulator

  prep_pack<<<2048, 256, 0, stream>>>(Wf, Wdil, Wc, Wskip, Wout, Wl1, Wl2,
                                      bdil, bc, bskip,
                                      wdp, wcp, wop, wskp, wfp, wl1p, wl2p,
                                      bde, bsk);
  tr_x_kernel<<<4096, 256, 0, stream>>>(x, xt);
  tr_kernel<<<NB * (T_LEN / 32) * 3, 256, 0, stream>>>(c, ctp, 80, 96, 3);
  first_conv<<<512, 256, 0, stream>>>(xt, wfp, bf, hA);

  const _Float16* hin = hA;
  _Float16* hout = hB;
  for (int l = 0; l < NLAYERS; ++l) {
    int d = 1 << (l % 10);
    layer_kernel<<<512, 512, 0, stream>>>(
        hin, hout, ctp,
        wdp + (size_t)l * 3 * 128 * 64, wcp + (size_t)l * 128 * 96,
        wop + (size_t)l * 64 * 64, bde + l * 128, bout + l * 64,
        zbuf + (size_t)(l & 7) * BT * 64, d, (l == NLAYERS - 1) ? 1 : 0);
    _Float16* tmp = (_Float16*)hin; hin = hout; hout = tmp;
    if (l == 7)  flush_kernel<<<512, 512, 0, stream>>>(zbuf, wskp, Abuf, bsk, skr, 0, 8, 0);
    if (l == 15) flush_kernel<<<512, 512, 0, stream>>>(zbuf, wskp, Abuf, bsk, skr, 8, 8, 1);
    if (l == 19) flush_kernel<<<512, 512, 0, stream>>>(zbuf, wskp, Abuf, bsk, skr, 16, 4, 2);
  }
  gemm256<<<dim3(512, 2), 256, 0, stream>>>(skr, wl1p, bl1, (void*)y1, 0);
  gemm256<<<dim3(512, 2), 256, 0, stream>>>(y1, wl2p, bl2, d_out, 1);
}

// Round 8
// 617.080 us; speedup vs baseline: 4.5870x; 1.1531x over previous
//
#include <hip/hip_runtime.h>
#include <math.h>

// WaveNet (4,256,16384), 20 layers. Round 12. Post-mortem of rounds 9-11:
// the layer double-buffer (74KB LDS) halved occupancy to 2 blocks/CU vs
// round-0's single-buffer 37KB @ 4 blocks/CU (32 waves/CU) — TLP loss that
// ILP never repaid. RESTORED round-0 layer structure (single As/Bs, two
// barriers per K-stage, epilogue re-reads hprev from L2). Kept: XCD chunked
// swizzle, last-layer dead-phase-4 skip, vectorized tr_x, 512-thread
// single-z-stage flush.

#define T_LEN   16384
#define NB      4
#define BT      (NB * T_LEN)     // 65536
#define NLAYERS 20
#define SQH     0.70710678118654752440f

typedef _Float16 half8 __attribute__((ext_vector_type(8)));
typedef _Float16 half4 __attribute__((ext_vector_type(4)));
typedef float f32x4 __attribute__((ext_vector_type(4)));

__device__ inline f32x4 mfma16(half8 a, half8 b, f32x4 c) {
  return __builtin_amdgcn_mfma_f32_16x16x32_f16(a, b, c, 0, 0, 0);
}

// chunked XCD swizzle: physical block pb (XCD = pb%8 round-robin) -> logical
// lb such that consecutive logical blocks share an XCD chunk. nwg % 8 == 0.
__device__ __forceinline__ int xswz(int pb, int nwg) {
  return (pb & 7) * (nwg >> 3) + (pb >> 3);
}

// ---------------- weight packing (f16) ----------------
__global__ __launch_bounds__(256) void prep_pack(
    const float* __restrict__ Wf, const float* __restrict__ Wdil,
    const float* __restrict__ Wc, const float* __restrict__ Wskip,
    const float* __restrict__ Wout, const float* __restrict__ Wl1,
    const float* __restrict__ Wl2, const float* __restrict__ bdil,
    const float* __restrict__ bc, const float* __restrict__ bskip,
    _Float16* __restrict__ wdp, _Float16* __restrict__ wcp,
    _Float16* __restrict__ wop, _Float16* __restrict__ wskp,
    _Float16* __restrict__ wfp, _Float16* __restrict__ wl1p,
    _Float16* __restrict__ wl2p, float* __restrict__ bde,
    float* __restrict__ bsk)
{
  const float Q = 0.70710678118654752440f;
  const int WDP_E = 20 * 3 * 128 * 64;   // [l][tau][n][kc]
  const int WCP_E = 20 * 128 * 96;       // [l][n][kc pad96]
  const int WOP_E = 20 * 64 * 64;        // [l][n][kc]
  const int WSK_E = 256 * 1280;          // [n][l*64+kc], scale q^(1-l)
  const int WFP_E = 64 * 512;            // [n][tau*256+ci]
  const int WL_E  = 256 * 256;
  const int BDE_E = 20 * 128;
  const int BSK_E = 256;
  const int TOTAL = WDP_E + WCP_E + WOP_E + WSK_E + WFP_E + 2 * WL_E + BDE_E + BSK_E;
  for (int i = blockIdx.x * blockDim.x + threadIdx.x; i < TOTAL;
       i += gridDim.x * blockDim.x) {
    int j = i;
    if (j < WDP_E) {
      int l = j / (3 * 128 * 64); int r2 = j % (3 * 128 * 64);
      int tau = r2 / (128 * 64);  int r3 = r2 % (128 * 64);
      int n = r3 >> 6; int kc = r3 & 63;
      wdp[j] = (_Float16)Wdil[((l * 128 + n) * 64 + kc) * 3 + tau];
      continue;
    }
    j -= WDP_E;
    if (j < WCP_E) {
      int l = j / (128 * 96); int r2 = j % (128 * 96);
      int n = r2 / 96; int kc = r2 % 96;
      wcp[j] = (_Float16)(kc < 80 ? Wc[(l * 128 + n) * 80 + kc] : 0.f);
      continue;
    }
    j -= WCP_E;
    if (j < WOP_E) {
      int l = j >> 12; int r2 = j & 4095;
      int n = r2 >> 6; int kc = r2 & 63;
      wop[j] = (_Float16)Wout[(l * 64 + n) * 64 + kc];
      continue;
    }
    j -= WOP_E;
    if (j < WSK_E) {
      int n = j / 1280; int k = j % 1280;
      int l = k >> 6; int kc = k & 63;
      float f = (l == 0) ? 1.f : powf(Q, (float)(1 - l));
      wskp[j] = (_Float16)(Wskip[(l * 256 + n) * 64 + kc] * f);
      continue;
    }
    j -= WSK_E;
    if (j < WFP_E) {
      int n = j >> 9; int k = j & 511;
      int tau = k >> 8; int ci = k & 255;
      wfp[j] = (_Float16)Wf[(n * 256 + ci) * 2 + tau];
      continue;
    }
    j -= WFP_E;
    if (j < WL_E) { wl1p[j] = (_Float16)Wl1[j]; continue; }
    j -= WL_E;
    if (j < WL_E) { wl2p[j] = (_Float16)Wl2[j]; continue; }
    j -= WL_E;
    if (j < BDE_E) { bde[j] = bdil[j] + bc[j]; continue; }
    j -= BDE_E;
    {
      int n = j;
      float s = 0.f;
      for (int l = 0; l < NLAYERS; ++l) {
        float w = powf(Q, (float)(l == 0 ? 19 : 20 - l));
        s += bskip[l * 256 + n] * w;
      }
      bsk[n] = s;
    }
  }
}

// ------- x transpose, vectorized: (B,256,T) f32 -> (BT,256) f16 -----------
__global__ __launch_bounds__(256) void tr_x_kernel(
    const float* __restrict__ src, _Float16* __restrict__ dst)
{
  __shared__ float tile[32 * 132];
  const int lb = xswz(blockIdx.x, 4096);
  const int row_tile = lb >> 3, cb = lb & 7;
  const int bb = row_tile >> 7;
  const int t0 = (row_tile & 127) * 128;
  const int ch0 = cb * 32;
  {
    int ch = threadIdx.x >> 3, tq = (threadIdx.x & 7) * 16;
    const float4* s4 = (const float4*)(src + ((size_t)(bb * 256 + ch0 + ch)) * T_LEN + t0 + tq);
#pragma unroll
    for (int j = 0; j < 4; ++j)
      *(float4*)&tile[ch * 132 + tq + 4 * j] = s4[j];
  }
  __syncthreads();
  {
    int t = threadIdx.x >> 1, c16 = (threadIdx.x & 1) * 16;
    half8 h0, h1;
#pragma unroll
    for (int j = 0; j < 8; ++j) {
      h0[j] = (_Float16)tile[(c16 + j) * 132 + t];
      h1[j] = (_Float16)tile[(c16 + 8 + j) * 132 + t];
    }
    _Float16* o = dst + ((size_t)(bb * T_LEN + t0 + t)) * 256 + ch0 + c16;
    *(half8*)o = h0;
    *(half8*)(o + 8) = h1;
  }
}

// ---------------- transpose (B,C,T) f32 -> (BT,Cpad) f16 (c path) ---------
__global__ __launch_bounds__(256) void tr_kernel(
    const float* __restrict__ src, _Float16* __restrict__ dst, int C, int Cpad, int CB)
{
  __shared__ float tile[32 * 33];
  int lb = xswz(blockIdx.x, gridDim.x);
  int cb = lb % CB;
  int tb = (lb / CB) % (T_LEN / 32);
  int bb = lb / (CB * (T_LEN / 32));
  int t0 = tb * 32, ch0 = cb * 32;
  int tl = threadIdx.x & 31, cl = threadIdx.x >> 5;
#pragma unroll
  for (int i = 0; i < 4; ++i) {
    int ch = cl + 8 * i;
    float v = (ch0 + ch < C) ? src[((size_t)bb * C + ch0 + ch) * T_LEN + t0 + tl] : 0.f;
    tile[ch * 33 + tl] = v;
  }
  __syncthreads();
  int t = threadIdx.x >> 3;
  int c4 = (threadIdx.x & 7) * 4;
  half4 hv = {(_Float16)tile[(c4 + 0) * 33 + t], (_Float16)tile[(c4 + 1) * 33 + t],
              (_Float16)tile[(c4 + 2) * 33 + t], (_Float16)tile[(c4 + 3) * 33 + t]};
  *(half4*)&dst[((size_t)bb * T_LEN + t0 + t) * Cpad + ch0 + c4] = hv;
}

// ---------------- first conv: h0 = tanh(Wf*[x(t-1);x(t)] + bf), f16 out ----
__global__ __launch_bounds__(256, 4) void first_conv(
    const _Float16* __restrict__ xt, const _Float16* __restrict__ wfp,
    const float* __restrict__ bf, _Float16* __restrict__ h0)
{
  __shared__ _Float16 As[128 * 72];
  __shared__ _Float16 Bs[64 * 72];
  const int tid = threadIdx.x;
  const int lane = tid & 63, w = tid >> 6;
  const int wx = w & 1, wy = w >> 1;
  const int l15 = lane & 15, quad = lane >> 4;
  const int p0 = xswz(blockIdx.x, 512) * 128;
  const int b = p0 >> 14, t0 = p0 & (T_LEN - 1);
  const int r = tid >> 1, halfo = (tid & 1) * 32;

  f32x4 acc[4][2];
#pragma unroll
  for (int mi = 0; mi < 4; ++mi)
#pragma unroll
    for (int ni = 0; ni < 2; ++ni) { f32x4 z = {0.f, 0.f, 0.f, 0.f}; acc[mi][ni] = z; }

  for (int s = 0; s < 8; ++s) {
    int tau = s >> 2, ci0 = (s & 3) * 64;
    int ts = t0 + r - 1 + tau;
    if (ts >= 0) {
      const uint4* src = (const uint4*)(xt + ((size_t)(b * T_LEN + ts) * 256 + ci0 + halfo));
#pragma unroll
      for (int j = 0; j < 4; ++j) *(uint4*)&As[r * 72 + halfo + 8 * j] = src[j];
    } else {
      uint4 z = {0, 0, 0, 0};
#pragma unroll
      for (int j = 0; j < 4; ++j) *(uint4*)&As[r * 72 + halfo + 8 * j] = z;
    }
    if (tid < 128) {
      const uint4* s4 = (const uint4*)(wfp + ((size_t)r * 512 + tau * 256 + ci0 + halfo));
#pragma unroll
      for (int j = 0; j < 4; ++j) *(uint4*)&Bs[r * 72 + halfo + 8 * j] = s4[j];
    }
    __syncthreads();
#pragma unroll
    for (int kc = 0; kc < 2; ++kc) {
      const int k0 = kc * 32 + quad * 8;
      half8 af[4], bfr[2];
#pragma unroll
      for (int mi = 0; mi < 4; ++mi)
        af[mi] = *(const half8*)&As[(64 * wy + 16 * mi + l15) * 72 + k0];
#pragma unroll
      for (int ni = 0; ni < 2; ++ni)
        bfr[ni] = *(const half8*)&Bs[(32 * wx + 16 * ni + l15) * 72 + k0];
#pragma unroll
      for (int mi = 0; mi < 4; ++mi)
#pragma unroll
        for (int ni = 0; ni < 2; ++ni)
          acc[mi][ni] = mfma16(af[mi], bfr[ni], acc[mi][ni]);
    }
    __syncthreads();
  }
#pragma unroll
  for (int mi = 0; mi < 4; ++mi)
#pragma unroll
    for (int ni = 0; ni < 2; ++ni) {
      int col = 32 * wx + 16 * ni + l15;
      int rowb = 64 * wy + 16 * mi + quad * 4;
      float bo = bf[col];
      size_t base = ((size_t)p0 + rowb) * 64 + col;
#pragma unroll
      for (int reg = 0; reg < 4; ++reg) {
        float v = acc[mi][ni][reg] + bo;
        float e = __expf(2.f * v);
        h0[base + (size_t)64 * reg] = (_Float16)(1.f - 2.f * __builtin_amdgcn_rcpf(e + 1.f));
      }
    }
}

// ---------------- one residual layer: 512 threads, 8 waves (2x4) -----------
// Round-0 structure: single As/Bs (37KB LDS -> 4 blocks/CU, 32 waves/CU).
__global__ __launch_bounds__(512, 4) void layer_kernel(
    const _Float16* __restrict__ hprev, _Float16* __restrict__ hnext,
    const _Float16* __restrict__ ctp,
    const _Float16* __restrict__ wdp_l, const _Float16* __restrict__ wcp_l,
    const _Float16* __restrict__ wop_l,
    const float* __restrict__ bde_l, const float* __restrict__ bout_l,
    _Float16* __restrict__ zslot, int d, int last)
{
  __shared__ _Float16 As[128 * 72];   // A operand; becomes Zs after gate
  __shared__ _Float16 Bs[128 * 72];
  __shared__ float bde_s[128];

  const int tid = threadIdx.x;
  const int lane = tid & 63, w = tid >> 6;        // 8 waves
  const int wx = w & 1, wy = w >> 1;              // 2 (N) x 4 (M)
  const int l15 = lane & 15, quad = lane >> 4;
  const int p0 = xswz(blockIdx.x, 512) * 128;
  const int b = p0 >> 14, t0 = p0 & (T_LEN - 1);
  const int r2 = tid >> 2, qo = (tid & 3) * 16;   // staging: row, 16-elem chunk
  const int o8 = (tid & 3) * 8;                   // K=32 stage chunk

  if (tid < 128) bde_s[tid] = bde_l[tid];

  f32x4 acc[2][4];
#pragma unroll
  for (int mi = 0; mi < 2; ++mi)
#pragma unroll
    for (int ni = 0; ni < 4; ++ni) { f32x4 z = {0.f, 0.f, 0.f, 0.f}; acc[mi][ni] = z; }

  // K stages: h[t-2d], h[t-d], h[t] (64 each), cond[0:64], cond[64:96] (K=32)
  for (int s = 0; s < 5; ++s) {
    if (s < 3) {
      int ts = t0 + r2 - (2 - s) * d;
      if (ts >= 0) {
        const uint4* src = (const uint4*)(hprev + ((size_t)(b * T_LEN + ts) * 64 + qo));
        *(uint4*)&As[r2 * 72 + qo] = src[0];
        *(uint4*)&As[r2 * 72 + qo + 8] = src[1];
      } else {
        uint4 z4 = {0, 0, 0, 0};
        *(uint4*)&As[r2 * 72 + qo] = z4;
        *(uint4*)&As[r2 * 72 + qo + 8] = z4;
      }
      const uint4* sb = (const uint4*)(wdp_l + ((size_t)s * 8192 + r2 * 64 + qo));
      *(uint4*)&Bs[r2 * 72 + qo] = sb[0];
      *(uint4*)&Bs[r2 * 72 + qo + 8] = sb[1];
    } else if (s == 3) {
      const uint4* sa = (const uint4*)(ctp + ((size_t)(p0 + r2) * 96 + qo));
      *(uint4*)&As[r2 * 72 + qo] = sa[0];
      *(uint4*)&As[r2 * 72 + qo + 8] = sa[1];
      const uint4* sb = (const uint4*)(wcp_l + ((size_t)r2 * 96 + qo));
      *(uint4*)&Bs[r2 * 72 + qo] = sb[0];
      *(uint4*)&Bs[r2 * 72 + qo + 8] = sb[1];
    } else {  // s == 4: K=32 tail of cond
      *(uint4*)&As[r2 * 72 + o8] = *(const uint4*)(ctp + ((size_t)(p0 + r2) * 96 + 64 + o8));
      *(uint4*)&Bs[r2 * 72 + o8] = *(const uint4*)(wcp_l + ((size_t)r2 * 96 + 64 + o8));
    }
    __syncthreads();
    const int nkc = (s == 4) ? 1 : 2;
    for (int kc = 0; kc < nkc; ++kc) {
      const int k0 = kc * 32 + quad * 8;
      half8 af[2], bfr[4];
#pragma unroll
      for (int mi = 0; mi < 2; ++mi)
        af[mi] = *(const half8*)&As[(32 * wy + 16 * mi + l15) * 72 + k0];
#pragma unroll
      for (int ni = 0; ni < 4; ++ni) {
        int ncol = 32 * wx + 16 * (ni & 1) + 64 * (ni >> 1);  // ch and ch+64
        bfr[ni] = *(const half8*)&Bs[(ncol + l15) * 72 + k0];
      }
#pragma unroll
      for (int mi = 0; mi < 2; ++mi)
#pragma unroll
        for (int ni = 0; ni < 4; ++ni)
          acc[mi][ni] = mfma16(af[mi], bfr[ni], acc[mi][ni]);
    }
    __syncthreads();
  }

  // gate: z = tanh(y[ch]) * sigmoid(y[ch+64]) -> Zs (aliases As)
#pragma unroll
  for (int mi = 0; mi < 2; ++mi)
#pragma unroll
    for (int ni2 = 0; ni2 < 2; ++ni2) {
      int colb = 32 * wx + 16 * ni2 + l15;
      float ba = bde_s[colb], bb = bde_s[colb + 64];
#pragma unroll
      for (int reg = 0; reg < 4; ++reg) {
        float av = acc[mi][ni2][reg] + ba;
        float gv = acc[mi][ni2 + 2][reg] + bb;
        float ea = __expf(2.f * av);
        float th = 1.f - 2.f * __builtin_amdgcn_rcpf(ea + 1.f);
        float sg = __builtin_amdgcn_rcpf(1.f + __expf(-gv));
        As[(32 * wy + 16 * mi + quad * 4 + reg) * 72 + colb] = (_Float16)(th * sg);
      }
    }

  // stage W_out (64x64) into Bs (skip for the dead h of the last layer)
  if (!last && tid < 256) {
    int row = tid >> 2;
    const uint4* sb = (const uint4*)(wop_l + ((size_t)row * 64 + qo));
    *(uint4*)&Bs[row * 72 + qo] = sb[0];
    *(uint4*)&Bs[row * 72 + qo + 8] = sb[1];
  }
  __syncthreads();

  // z -> global ring slot
  {
    uint4 v0 = *(const uint4*)&As[r2 * 72 + qo];
    uint4 v1 = *(const uint4*)&As[r2 * 72 + qo + 8];
    uint4* dst = (uint4*)(zslot + ((size_t)(p0 + r2) * 64 + qo));
    dst[0] = v0; dst[1] = v1;
  }

  if (last) return;

  // phase 4: h_out = (Wout*z + b_out + h_in) * SQH  (h_in re-read from L2)
  f32x4 a4[2][2];
#pragma unroll
  for (int mi = 0; mi < 2; ++mi)
#pragma unroll
    for (int ni = 0; ni < 2; ++ni) { f32x4 z = {0.f, 0.f, 0.f, 0.f}; a4[mi][ni] = z; }
#pragma unroll
  for (int kc = 0; kc < 2; ++kc) {
    const int k0 = kc * 32 + quad * 8;
    half8 af[2], bfr[2];
#pragma unroll
    for (int mi = 0; mi < 2; ++mi)
      af[mi] = *(const half8*)&As[(32 * wy + 16 * mi + l15) * 72 + k0];
#pragma unroll
    for (int ni = 0; ni < 2; ++ni)
      bfr[ni] = *(const half8*)&Bs[(32 * wx + 16 * ni + l15) * 72 + k0];
#pragma unroll
    for (int mi = 0; mi < 2; ++mi)
#pragma unroll
      for (int ni = 0; ni < 2; ++ni)
        a4[mi][ni] = mfma16(af[mi], bfr[ni], a4[mi][ni]);
  }
#pragma unroll
  for (int mi = 0; mi < 2; ++mi)
#pragma unroll
    for (int ni = 0; ni < 2; ++ni) {
      int col = 32 * wx + 16 * ni + l15;
      int rowb = 32 * wy + 16 * mi + quad * 4;
      float bo = bout_l[col];
      size_t base = ((size_t)p0 + rowb) * 64 + col;
#pragma unroll
      for (int reg = 0; reg < 4; ++reg) {
        float hv = (float)hprev[base + (size_t)64 * reg];
        hnext[base + (size_t)64 * reg] = (_Float16)((a4[mi][ni][reg] + bo + hv) * SQH);
      }
    }
}

// ---------------- deferred skip flush (512 threads, both n-halves) --------
// z tile staged ONCE in LDS, shared by both 128-col halves.
// mode 0: Abuf = acc   mode 1: Abuf += acc   mode 2: skr = relu((acc+Abuf)*q^19+bsk)
__global__ __launch_bounds__(512, 4) void flush_kernel(
    const _Float16* __restrict__ zbuf, const _Float16* __restrict__ wskp,
    _Float16* __restrict__ Abuf, const float* __restrict__ bsk,
    _Float16* __restrict__ skr, int l0, int g, int mode)
{
  __shared__ _Float16 As[128 * 72];
  __shared__ _Float16 Bs0[128 * 72];
  __shared__ _Float16 Bs1[128 * 72];
  const int tid = threadIdx.x;
  const int half = tid >> 8;
  _Float16* Bsh = half ? Bs1 : Bs0;
  const int tloc = tid & 255;
  const int lane = tloc & 63, w4 = tloc >> 6;
  const int wx = w4 & 1, wy = w4 >> 1;
  const int l15 = lane & 15, quad = lane >> 4;
  const int p0 = xswz(blockIdx.x, 512) * 128;
  const int n0 = half * 128;
  const int r = tloc >> 1, halfo = (tloc & 1) * 32;

  f32x4 acc[4][4];
#pragma unroll
  for (int mi = 0; mi < 4; ++mi)
#pragma unroll
    for (int ni = 0; ni < 4; ++ni) { f32x4 z = {0.f, 0.f, 0.f, 0.f}; acc[mi][ni] = z; }

#pragma unroll 1
  for (int j = 0; j < g; ++j) {
    const int lj = l0 + j;
    const _Float16* zsl = zbuf + (size_t)(lj & 7) * ((size_t)BT * 64);
    if (half == 0) {
      const uint4* sa = (const uint4*)(zsl + ((size_t)(p0 + r) * 64 + halfo));
#pragma unroll
      for (int jj = 0; jj < 4; ++jj) *(uint4*)&As[r * 72 + halfo + 8 * jj] = sa[jj];
    }
    const uint4* sb = (const uint4*)(wskp + ((size_t)(n0 + r) * 1280 + lj * 64 + halfo));
#pragma unroll
    for (int jj = 0; jj < 4; ++jj) *(uint4*)&Bsh[r * 72 + halfo + 8 * jj] = sb[jj];
    __syncthreads();
#pragma unroll
    for (int kc = 0; kc < 2; ++kc) {
      const int k0 = kc * 32 + quad * 8;
      half8 af[4], bfr[4];
#pragma unroll
      for (int mi = 0; mi < 4; ++mi)
        af[mi] = *(const half8*)&As[(64 * wy + 16 * mi + l15) * 72 + k0];
#pragma unroll
      for (int ni = 0; ni < 4; ++ni)
        bfr[ni] = *(const half8*)&Bsh[(64 * wx + 16 * ni + l15) * 72 + k0];
#pragma unroll
      for (int mi = 0; mi < 4; ++mi)
#pragma unroll
        for (int ni = 0; ni < 4; ++ni)
          acc[mi][ni] = mfma16(af[mi], bfr[ni], acc[mi][ni]);
    }
    __syncthreads();
  }
  const float Q19 = 0.0013810679320049757f;  // sqrt(0.5)^19
#pragma unroll
  for (int mi = 0; mi < 4; ++mi)
#pragma unroll
    for (int ni = 0; ni < 4; ++ni) {
      int col = n0 + 64 * wx + 16 * ni + l15;
      int rowb = 64 * wy + 16 * mi + quad * 4;
      size_t base = ((size_t)p0 + rowb) * 256 + col;
      if (mode == 2) {
        float bb = bsk[col];
#pragma unroll
        for (int reg = 0; reg < 4; ++reg) {
          float v = (acc[mi][ni][reg] + (float)Abuf[base + (size_t)256 * reg]) * Q19 + bb;
          skr[base + (size_t)256 * reg] = (_Float16)(v > 0.f ? v : 0.f);
        }
      } else if (mode == 1) {
#pragma unroll
        for (int reg = 0; reg < 4; ++reg) {
          size_t a = base + (size_t)256 * reg;
          Abuf[a] = (_Float16)((float)Abuf[a] + acc[mi][ni][reg]);
        }
      } else {
#pragma unroll
        for (int reg = 0; reg < 4; ++reg)
          Abuf[base + (size_t)256 * reg] = (_Float16)acc[mi][ni][reg];
      }
    }
}

// ---------------- generic 256x256 GEMM (last1 / last2) -------------------
// mode 0: dst f16 row-major (BT,256), relu.  mode 1: dst f32 (B,256,T), +bias,
// coalesced via LDS transpose.
__global__ __launch_bounds__(256, 4) void gemm256(
    const _Float16* __restrict__ Asrc, const _Float16* __restrict__ Bp,
    const float* __restrict__ bias, void* __restrict__ dst, int mode)
{
  __shared__ _Float16 smem[2 * 128 * 72];
  _Float16* As = smem;
  _Float16* Bs = smem + 128 * 72;
  const int tid = threadIdx.x;
  const int lane = tid & 63, w = tid >> 6;
  const int wx = w & 1, wy = w >> 1;
  const int l15 = lane & 15, quad = lane >> 4;
  const int p0 = xswz(blockIdx.x, 512) * 128;
  const int n0 = blockIdx.y * 128;
  const int r = tid >> 1, halfo = (tid & 1) * 32;

  f32x4 acc[4][4];
#pragma unroll
  for (int mi = 0; mi < 4; ++mi)
#pragma unroll
    for (int ni = 0; ni < 4; ++ni) { f32x4 z = {0.f, 0.f, 0.f, 0.f}; acc[mi][ni] = z; }

  for (int c4 = 0; c4 < 4; ++c4) {
    int k0g = c4 * 64;
    const uint4* sa = (const uint4*)(Asrc + ((size_t)(p0 + r) * 256 + k0g + halfo));
#pragma unroll
    for (int jj = 0; jj < 4; ++jj) *(uint4*)&As[r * 72 + halfo + 8 * jj] = sa[jj];
    const uint4* sb = (const uint4*)(Bp + ((size_t)(n0 + r) * 256 + k0g + halfo));
#pragma unroll
    for (int jj = 0; jj < 4; ++jj) *(uint4*)&Bs[r * 72 + halfo + 8 * jj] = sb[jj];
    __syncthreads();
#pragma unroll
    for (int kc = 0; kc < 2; ++kc) {
      const int k0 = kc * 32 + quad * 8;
      half8 af[4], bfr[4];
#pragma unroll
      for (int mi = 0; mi < 4; ++mi)
        af[mi] = *(const half8*)&As[(64 * wy + 16 * mi + l15) * 72 + k0];
#pragma unroll
      for (int ni = 0; ni < 4; ++ni)
        bfr[ni] = *(const half8*)&Bs[(64 * wx + 16 * ni + l15) * 72 + k0];
#pragma unroll
      for (int mi = 0; mi < 4; ++mi)
#pragma unroll
        for (int ni = 0; ni < 4; ++ni)
          acc[mi][ni] = mfma16(af[mi], bfr[ni], acc[mi][ni]);
    }
    __syncthreads();
  }
  if (mode == 0) {
#pragma unroll
    for (int mi = 0; mi < 4; ++mi)
#pragma unroll
      for (int ni = 0; ni < 4; ++ni) {
        int col = n0 + 64 * wx + 16 * ni + l15;
        int rowb = 64 * wy + 16 * mi + quad * 4;
        float bv = bias[col];
        _Float16* o = (_Float16*)dst;
#pragma unroll
        for (int reg = 0; reg < 4; ++reg) {
          float v = acc[mi][ni][reg] + bv;
          o[((size_t)(p0 + rowb + reg)) * 256 + col] = (_Float16)(v > 0.f ? v : 0.f);
        }
      }
  } else {
    // transposed coalesced store: two passes of 64 columns through LDS
    float* Ts = (float*)smem;       // 64 x 132 floats = 33792 B
    const int b = p0 >> 14, t0g = p0 & (T_LEN - 1);
    for (int pass = 0; pass < 2; ++pass) {
      if (wx == pass) {
#pragma unroll
        for (int mi = 0; mi < 4; ++mi)
#pragma unroll
          for (int ni = 0; ni < 4; ++ni) {
            int col_l = 16 * ni + l15;
            float bv = bias[n0 + 64 * pass + col_l];
            int tl = 64 * wy + 16 * mi + quad * 4;
#pragma unroll
            for (int reg = 0; reg < 4; ++reg)
              Ts[col_l * 132 + tl + reg] = acc[mi][ni][reg] + bv;
          }
      }
      __syncthreads();
      {
        int col_l = tid >> 2;
        int tq = (tid & 3) * 32;
        float* o = (float*)dst + ((size_t)b * 256 + n0 + 64 * pass + col_l) * T_LEN + t0g + tq;
#pragma unroll
        for (int j = 0; j < 8; ++j)
          *(float4*)(o + 4 * j) = *(const float4*)&Ts[col_l * 132 + tq + 4 * j];
      }
      __syncthreads();
    }
  }
}

extern "C" void kernel_launch(void* const* d_in, const int* in_sizes, int n_in,
                              void* d_out, int out_size, void* d_ws, size_t ws_size,
                              hipStream_t stream)
{
  const float* x     = (const float*)d_in[0];
  const float* c     = (const float*)d_in[1];
  const float* Wf    = (const float*)d_in[2];
  const float* bf    = (const float*)d_in[3];
  const float* Wdil  = (const float*)d_in[4];
  const float* bdil  = (const float*)d_in[5];
  const float* Wc    = (const float*)d_in[6];
  const float* bc    = (const float*)d_in[7];
  const float* Wskip = (const float*)d_in[8];
  const float* bskip = (const float*)d_in[9];
  const float* Wout  = (const float*)d_in[10];
  const float* bout  = (const float*)d_in[11];
  const float* Wl1   = (const float*)d_in[12];
  const float* bl1   = (const float*)d_in[13];
  const float* Wl2   = (const float*)d_in[14];
  const float* bl2   = (const float*)d_in[15];

  char* base = (char*)d_ws;
  // 8-slot z ring (64 MiB). Aliases: xt = slots 0-3 (consumed by first_conv
  // before layer 0 writes slot 0); skr = slots 4-7 (free after flush2);
  // y1 = slots 0-3 (free after flush3). Abuf (f16) lives in d_out, dead
  // before gemm256 #2 writes the final f32 output there.
  _Float16* zbuf = (_Float16*)base;
  _Float16* xt   = zbuf;
  _Float16* skr  = zbuf + (size_t)4 * BT * 64;
  _Float16* y1   = zbuf;
  _Float16* ctp  = (_Float16*)(base + 67108864);   // BT*96 f16 = 12.58 MB
  _Float16* hA   = (_Float16*)(base + 79691776);   // BT*64 f16 = 8.39 MB
  _Float16* hB   = (_Float16*)(base + 88080384);
  _Float16* wdp  = (_Float16*)(base + 96468992);
  _Float16* wcp  = wdp  + (size_t)20 * 3 * 128 * 64;
  _Float16* wop  = wcp  + (size_t)20 * 128 * 96;
  _Float16* wskp = wop  + (size_t)20 * 64 * 64;
  _Float16* wfp  = wskp + (size_t)256 * 1280;
  _Float16* wl1p = wfp  + (size_t)64 * 512;
  _Float16* wl2p = wl1p + (size_t)256 * 256;
  float*    bde  = (float*)(wl2p + (size_t)256 * 256);
  float*    bsk  = bde + 20 * 128;
  _Float16* Abuf = (_Float16*)d_out;               // f16 skip accumulator

  prep_pack<<<2048, 256, 0, stream>>>(Wf, Wdil, Wc, Wskip, Wout, Wl1, Wl2,
                                      bdil, bc, bskip,
                                      wdp, wcp, wop, wskp, wfp, wl1p, wl2p,
                                      bde, bsk);
  tr_x_kernel<<<4096, 256, 0, stream>>>(x, xt);
  tr_kernel<<<NB * (T_LEN / 32) * 3, 256, 0, stream>>>(c, ctp, 80, 96, 3);
  first_conv<<<512, 256, 0, stream>>>(xt, wfp, bf, hA);

  const _Float16* hin = hA;
  _Float16* hout = hB;
  for (int l = 0; l < NLAYERS; ++l) {
    int d = 1 << (l % 10);
    layer_kernel<<<512, 512, 0, stream>>>(
        hin, hout, ctp,
        wdp + (size_t)l * 3 * 128 * 64, wcp + (size_t)l * 128 * 96,
        wop + (size_t)l * 64 * 64, bde + l * 128, bout + l * 64,
        zbuf + (size_t)(l & 7) * BT * 64, d, (l == NLAYERS - 1) ? 1 : 0);
    _Float16* tmp = (_Float16*)hin; hin = hout; hout = tmp;
    if (l == 7)  flush_kernel<<<512, 512, 0, stream>>>(zbuf, wskp, Abuf, bsk, skr, 0, 8, 0);
    if (l == 15) flush_kernel<<<512, 512, 0, stream>>>(zbuf, wskp, Abuf, bsk, skr, 8, 8, 1);
    if (l == 19) flush_kernel<<<512, 512, 0, stream>>>(zbuf, wskp, Abuf, bsk, skr, 16, 4, 2);
  }
  gemm256<<<dim3(512, 2), 256, 0, stream>>>(skr, wl1p, bl1, (void*)y1, 0);
  gemm256<<<dim3(512, 2), 256, 0, stream>>>(y1, wl2p, bl2, d_out, 1);
}